// Round 6
// baseline (708.419 us; speedup 1.0000x reference)
//
#include <hip/hip_runtime.h>
#include <hip/hip_bf16.h>

#define TWO_PI_F 6.2831853071795864769f

typedef __attribute__((ext_vector_type(8))) __bf16 bf16x8;
typedef __attribute__((ext_vector_type(4))) float f32x4;

__device__ __forceinline__ float bf2f_raw(unsigned short u) {
    return __uint_as_float(((unsigned int)u) << 16);
}
__device__ __forceinline__ unsigned short f2bf(float f) {
    unsigned int u = __float_as_uint(f);
    unsigned int r = (u + 0x7FFFu + ((u >> 16) & 1u)) >> 16;   // RNE
    return (unsigned short)r;
}
__device__ __forceinline__ float loadIn(const void* p, size_t i, bool f32) {
    return f32 ? ((const float*)p)[i] : bf2f_raw(((const unsigned short*)p)[i]);
}

// Fused BN affine + (leaky)relu applied to 8 packed bf16 during staging.
__device__ __forceinline__ uint4 bn_fuse8(uint4 v, const float* __restrict__ sc,
                                          const float* __restrict__ sh, int c0, float slope) {
    unsigned short us[8];
    *(uint4*)us = v;
#pragma unroll
    for (int k = 0; k < 8; ++k) {
        float f = bf2f_raw(us[k]) * sc[c0 + k] + sh[c0 + k];
        f = f > 0.f ? f : slope * f;
        us[k] = f2bf(f);
    }
    return *(const uint4*)us;
}

// ---------------- ws layout ----------------
static constexpr size_t OFF_WC0 = 0;          // cod_w0 fp32 3072
static constexpr size_t OFF_WG2 = 3072;       // gen_w2 fp32 6144 (legacy, unused)
static constexpr size_t OFF_P   = 9216;
static constexpr size_t OFF_CB0 = OFF_P + 0;
static constexpr size_t OFF_CG0 = OFF_P + 64;
static constexpr size_t OFF_CBE0= OFF_P + 128;
static constexpr size_t OFF_CB1 = OFF_P + 192;
static constexpr size_t OFF_CG1 = OFF_P + 320;
static constexpr size_t OFF_CBE1= OFF_P + 448;
static constexpr size_t OFF_CB2 = OFF_P + 576;
static constexpr size_t OFF_GB0 = OFF_P + 640;
static constexpr size_t OFF_GG0 = OFF_P + 896;
static constexpr size_t OFF_GBE0= OFF_P + 1152;
static constexpr size_t OFF_GB1 = OFF_P + 1408;
static constexpr size_t OFF_GG1 = OFF_P + 1536;
static constexpr size_t OFF_GBE1= OFF_P + 1664;
static constexpr size_t OFF_GB2 = OFF_P + 1792;
static constexpr size_t OFF_SSUM  = OFF_P + 2048;   // 576
static constexpr size_t OFF_SSQ   = OFF_SSUM + 576;
static constexpr size_t OFF_SCALE = OFF_SSUM + 1152;
static constexpr size_t OFF_SHIFT = OFF_SCALE + 576;
static constexpr size_t OFF_K12   = OFF_SHIFT + 576;
static constexpr size_t OFF_FLAG  = OFF_K12 + 1024;
static constexpr size_t FP32_END  = OFF_FLAG + 16;   // floats
// ushort regions:
static constexpr size_t UXT = 2 * FP32_END;            // X region: X_s2d (b,2,2,32,32,64) then X_t (b,32,32,256)
static constexpr size_t UYT = UXT + 16777216;          // Y region: Y_s2d head, then Y_t (b,64,64,128)
static constexpr size_t UZT = UYT + 8388608;           // Z_t (b,16,16,192)
static constexpr size_t UW0 = UYT + 33554432;          // deconv0 pack
static constexpr size_t UW1 = UW0 + 786432;            // deconv1 pack
static constexpr size_t UWC1 = UW1 + 524288;           // conv1 pack
static constexpr size_t UWC2 = UWC1 + 131072;          // conv2 pack
static constexpr size_t UW2 = UWC2 + 131072;           // deconv2 pack
static constexpr size_t WS_END_USHORT = UW2 + 32768;
static constexpr size_t WS_NEED_BYTES = WS_END_USHORT * 2;   // ~109.9 MB

// stat slots: L0:0(64) L1:64(128) G0:192(256) G1:448(128)

// ---------------- input dtype detection ----------------
__global__ void detect_kernel(const unsigned short* __restrict__ imgs, int* __restrict__ flag) {
    int t = threadIdx.x;  // 256
    unsigned short u = imgs[t];
    int e = (u >> 7) & 0xFF;
    unsigned long long b = __ballot(e >= 0xC0);
    __shared__ int cnt[4];
    if ((t & 63) == 0) cnt[t >> 6] = __popcll(b);
    __syncthreads();
    if (t == 0) flag[0] = (cnt[0] + cnt[1] + cnt[2] + cnt[3] >= 4) ? 1 : 0;
}

// ---------------- small param -> fp32 conversion ----------------
struct CvtJobs {
    const void* src[16];
    float* dst[16];
    int off[17];
};

__global__ void cvt_all_kernel(CvtJobs J, int total, const int* __restrict__ flg) {
    int i = blockIdx.x * 256 + threadIdx.x;
    if (i >= total) return;
    bool f32 = flg[0] != 0;
    int k = 0;
#pragma unroll
    for (int t = 0; t < 15; ++t) { if (i >= J.off[t + 1]) k = t + 1; }
    int r = i - J.off[k];
    J.dst[k][r] = loadIn(J.src[k], r, f32);
}

__global__ void zero_kernel(float* p, int n) {
    int i = blockIdx.x * 256 + threadIdx.x;
    if (i < n) p[i] = 0.f;
}

// ---------------- deconv weight packing ----------------
__global__ void pack_w2_kernel(const void* __restrict__ src, unsigned short* __restrict__ dst,
                               int ICreal, int ICP, int OC, const int* __restrict__ flg) {
    bool f32 = flg[0] != 0;
    int i = blockIdx.x * 256 + threadIdx.x;
    int total = 16 * OC * ICP;
    if (i >= total) return;
    int jj = i & 7;
    int lane = (i >> 3) & 63;
    int j = (i >> 9) & 3;
    int t3 = i >> 11;
    int NK = ICP / 32;
    int kc = t3 % NK;
    int t4 = t3 / NK;
    int NOCT = OC / 64;
    int oct = t4 % NOCT;
    int ktap = t4 / NOCT;
    int kq = lane >> 4, n = lane & 15;
    int ic = kc * 32 + kq * 8 + jj;
    int oc = oct * 64 + n * 4 + j;          // channel-interleaved
    unsigned short v = 0;
    if (ic < ICreal) v = f2bf(loadIn(src, ((size_t)(ic * OC + oc) << 4) + ktap, f32));
    dst[i] = v;
}

__global__ void pack_w2s_kernel(const void* __restrict__ src, unsigned short* __restrict__ dst,
                                int ICP, int OCreal, const int* __restrict__ flg) {
    bool f32 = flg[0] != 0;
    int i = blockIdx.x * 256 + threadIdx.x;
    int NK = ICP / 32;
    int total = 16 * NK * 512;
    if (i >= total) return;
    int jj = i & 7;
    int lane = (i >> 3) & 63;
    int t3 = i >> 9;
    int kc = t3 % NK;
    int ktap = t3 / NK;
    int kq = lane >> 4, n = lane & 15;
    int ic = kc * 32 + kq * 8 + jj;
    unsigned short v = 0;
    if (n < OCreal) v = f2bf(loadIn(src, ((size_t)(ic * OCreal + n) << 4) + ktap, f32));
    dst[i] = v;
}

__global__ void pack_wc_kernel(const void* __restrict__ src, unsigned short* __restrict__ dst,
                               int IC, int OC, const int* __restrict__ flg) {
    bool f32 = flg[0] != 0;
    int i = blockIdx.x * 256 + threadIdx.x;
    int total = 16 * OC * IC;
    if (i >= total) return;
    int jj = i & 7;
    int lane = (i >> 3) & 63;
    int j = (i >> 9) & 3;
    int t3 = i >> 11;
    int NK = IC / 32;
    int kc = t3 % NK;
    int t4 = t3 / NK;
    int NOCT = OC / 64;
    int oct = t4 % NOCT;
    int ktap = t4 / NOCT;
    int kq = lane >> 4, n = lane & 15;
    int ic = kc * 32 + kq * 8 + jj;
    int oc = oct * 64 + j * 16 + n;
    dst[i] = f2bf(loadIn(src, ((size_t)(oc * IC + ic) << 4) + ktap, f32));
}

// ---------------- tiny MLP ----------------
__global__ void mlp_kernel(const void* __restrict__ Zg,
                           const void* __restrict__ lW, const void* __restrict__ lb,
                           const void* __restrict__ l1W, const void* __restrict__ l1b,
                           const void* __restrict__ l2W, const void* __restrict__ l2b,
                           float* __restrict__ K12, const int* __restrict__ flg) {
    bool f32 = flg[0] != 0;
    int b = blockIdx.x;
    int t = threadIdx.x;  // 64
    __shared__ float xs[64];
    float acc = loadIn(lb, t, f32);
    for (int c = 0; c < 64; ++c)
        acc += loadIn(Zg, (size_t)(b * 64 + c) * 256, f32) * loadIn(lW, t * 64 + c, f32);
    xs[t] = fmaxf(acc, 0.f);
    __syncthreads();
    if (t < 16) {
        int p = t & 7;
        const void* Wp = (t < 8) ? l1W : l2W;
        const void* bp = (t < 8) ? l1b : l2b;
        float a = loadIn(bp, p, f32);
        for (int h = 0; h < 64; ++h) a += xs[h] * loadIn(Wp, p * 64 + h, f32);
        K12[b * 16 + t] = a;
    }
}

// ---------------- conv0: imgs -> X_s2d ----------------
__global__ void conv0_s2d_kernel(const void* __restrict__ imgs, const float* __restrict__ w,
                                 const float* __restrict__ bias, unsigned short* __restrict__ xs,
                                 const int* __restrict__ flg) {
    bool f32 = flg[0] != 0;
    int b = blockIdx.z;
    int tile = blockIdx.x;
    int Y0 = (tile >> 2) * 16, X0 = (tile & 3) * 16;
    __shared__ float vin[3 * 34 * 35];
    __shared__ float wl[64 * 49];
    for (int i = threadIdx.x; i < 3 * 34 * 34; i += 256) {
        int c = i % 34; int t = i / 34; int r = t % 34; int ic = t / 34;
        int iy = 2 * Y0 - 1 + r, ix = 2 * X0 - 1 + c;
        float v = 0.f;
        if (((unsigned)iy < 128u) & ((unsigned)ix < 128u))
            v = loadIn(imgs, ((size_t)(b * 3 + ic) * 128 + iy) * 128 + ix, f32);
        vin[(ic * 34 + r) * 35 + c] = v;
    }
    for (int i = threadIdx.x; i < 3072; i += 256) {
        int oc = i / 48, idx = i % 48;
        wl[oc * 49 + idx] = w[i];
    }
    __syncthreads();
    int q = threadIdx.x >> 2;
    int ocq = threadIdx.x & 3;
    int qy = q >> 3, qx = q & 7;
    float acc[4][16];
#pragma unroll
    for (int p = 0; p < 4; ++p)
#pragma unroll
        for (int o = 0; o < 16; ++o) acc[p][o] = 0.f;
    for (int ic = 0; ic < 3; ++ic) {
        float v[6][6];
#pragma unroll
        for (int r = 0; r < 6; ++r)
#pragma unroll
            for (int c = 0; c < 6; ++c)
                v[r][c] = vin[(ic * 34 + 4 * qy + r) * 35 + 4 * qx + c];
#pragma unroll
        for (int o = 0; o < 16; ++o) {
            const float* wo = wl + (ocq * 16 + o) * 49 + ic * 16;
#pragma unroll
            for (int ky = 0; ky < 4; ++ky)
#pragma unroll
                for (int kx = 0; kx < 4; ++kx) {
                    float wv = wo[ky * 4 + kx];
                    acc[0][o] = fmaf(v[ky][kx], wv, acc[0][o]);
                    acc[1][o] = fmaf(v[ky][kx + 2], wv, acc[1][o]);
                    acc[2][o] = fmaf(v[ky + 2][kx], wv, acc[2][o]);
                    acc[3][o] = fmaf(v[ky + 2][kx + 2], wv, acc[3][o]);
                }
        }
    }
    int j = (Y0 >> 1) + qy, i2 = (X0 >> 1) + qx;
#pragma unroll
    for (int p = 0; p < 4; ++p) {
        int dy = p >> 1, dx = p & 1;
        unsigned short tmp[16];
#pragma unroll
        for (int o = 0; o < 16; ++o) tmp[o] = f2bf(acc[p][o] + bias[ocq * 16 + o]);
        unsigned short* dst = xs + (((size_t)((b * 2 + dy) * 2 + dx) * 32 + j) * 32 + i2) * 64 + ocq * 16;
        *(uint4*)(dst) = *(const uint4*)(tmp);
        *(uint4*)(dst + 8) = *(const uint4*)(tmp + 8);
    }
}

// ---------------- conv1 (MFMA, fused L0 BN on load, fused L1 stats): X_s2d -> Y_s2d ----------------
__global__ void conv1_mfma_kernel(const unsigned short* __restrict__ xs,
                                  const unsigned short* __restrict__ wp,
                                  const float* __restrict__ bias,
                                  const float* __restrict__ sc, const float* __restrict__ sh,
                                  float* __restrict__ gsum, float* __restrict__ gsq,
                                  unsigned short* __restrict__ ys) {
    constexpr int STR = 72;
    __shared__ unsigned short lds[4 * 3 * 17 * STR];   // 29.4 KB
    __shared__ float cs[128], cq[128];
    int bid = blockIdx.x;
    int xt = bid & 1;
    int qp = (bid >> 1) & 15;
    int b = bid >> 5;
    int oy0 = qp * 2, x0 = xt * 16;
    for (int i = threadIdx.x; i < 1632; i += 256) {
        int icc = i & 7; int t = i >> 3;
        int col = t % 17; int rc = t / 17;
        int row = rc % 3; int pl = rc / 3;
        int py = pl >> 1, px = pl & 1;
        int j = oy0 - py + row;
        int ci = x0 - px + col;
        uint4 v = {0u, 0u, 0u, 0u};
        if (((unsigned)j < 32u) & ((unsigned)ci < 32u)) {
            v = *(const uint4*)(xs + ((size_t)((b * 4 + pl) * 32 + j) * 32 + ci) * 64 + icc * 8);
            v = bn_fuse8(v, sc, sh, icc * 8, 0.2f);
        }
        *(uint4*)(lds + ((pl * 3 + row) * 17 + col) * STR + icc * 8) = v;
    }
    if (threadIdx.x < 128) { cs[threadIdx.x] = 0.f; cq[threadIdx.x] = 0.f; }
    __syncthreads();

    int wv = threadIdx.x >> 6, lane = threadIdx.x & 63;
    int r = wv >> 1, oct = wv & 1;
    int m = lane & 15, kq = lane >> 4;
    f32x4 acc[4];
#pragma unroll
    for (int j = 0; j < 4; ++j) acc[j] = (f32x4){0.f, 0.f, 0.f, 0.f};

#pragma unroll
    for (int ky = 0; ky < 4; ++ky) {
        int py = (ky & 1) ^ 1;
        int lrow = r + (ky >> 1);
#pragma unroll
        for (int kx = 0; kx < 4; ++kx) {
            int px = (kx & 1) ^ 1;
            int pl = py * 2 + px;
            int lcol = m + (kx >> 1);
            const unsigned short* lp = lds + ((pl * 3 + lrow) * 17 + lcol) * STR + kq * 8;
            int ktap = ky * 4 + kx;
            const unsigned short* bb = wp + (size_t)(ktap * 2 + oct) * 4096;
#pragma unroll
            for (int kc = 0; kc < 2; ++kc) {
                bf16x8 a = *(const bf16x8*)(lp + kc * 32);
                const unsigned short* bk = bb + kc * 2048 + lane * 8;
                bf16x8 b0 = *(const bf16x8*)(bk);
                bf16x8 b1 = *(const bf16x8*)(bk + 512);
                bf16x8 b2 = *(const bf16x8*)(bk + 1024);
                bf16x8 b3 = *(const bf16x8*)(bk + 1536);
                acc[0] = __builtin_amdgcn_mfma_f32_16x16x32_bf16(a, b0, acc[0], 0, 0, 0);
                acc[1] = __builtin_amdgcn_mfma_f32_16x16x32_bf16(a, b1, acc[1], 0, 0, 0);
                acc[2] = __builtin_amdgcn_mfma_f32_16x16x32_bf16(a, b2, acc[2], 0, 0, 0);
                acc[3] = __builtin_amdgcn_mfma_f32_16x16x32_bf16(a, b3, acc[3], 0, 0, 0);
            }
        }
    }
    int oy = oy0 + r;
    int pyo = oy & 1, jo = oy >> 1;
    int n = m;
    float bv0 = bias[oct * 64 + n], bv1 = bias[oct * 64 + 16 + n];
    float bv2 = bias[oct * 64 + 32 + n], bv3 = bias[oct * 64 + 48 + n];
    float s0 = 0, s1 = 0, s2 = 0, s3 = 0, q0 = 0, q1 = 0, q2 = 0, q3 = 0;
#pragma unroll
    for (int reg = 0; reg < 4; ++reg) {
        int mm = kq * 4 + reg;
        int ox = x0 + mm;
        int pxo = ox & 1, io = ox >> 1;
        size_t base = (((size_t)((b * 2 + pyo) * 2 + pxo) * 16 + jo) * 16 + io) * 128 + oct * 64 + n;
        float v0 = acc[0][reg] + bv0, v1 = acc[1][reg] + bv1;
        float v2 = acc[2][reg] + bv2, v3 = acc[3][reg] + bv3;
        s0 += v0; q0 += v0 * v0; s1 += v1; q1 += v1 * v1;
        s2 += v2; q2 += v2 * v2; s3 += v3; q3 += v3 * v3;
        ys[base]      = f2bf(v0);
        ys[base + 16] = f2bf(v1);
        ys[base + 32] = f2bf(v2);
        ys[base + 48] = f2bf(v3);
    }
    atomicAdd(&cs[oct * 64 + n], s0);      atomicAdd(&cq[oct * 64 + n], q0);
    atomicAdd(&cs[oct * 64 + 16 + n], s1); atomicAdd(&cq[oct * 64 + 16 + n], q1);
    atomicAdd(&cs[oct * 64 + 32 + n], s2); atomicAdd(&cq[oct * 64 + 32 + n], q2);
    atomicAdd(&cs[oct * 64 + 48 + n], s3); atomicAdd(&cq[oct * 64 + 48 + n], q3);
    __syncthreads();
    if (threadIdx.x < 128) {
        atomicAdd(&gsum[64 + threadIdx.x], cs[threadIdx.x]);
        atomicAdd(&gsq[64 + threadIdx.x], cq[threadIdx.x]);
    }
}

// ---------------- conv2 (MFMA, fused L1 BN on load) + tanh: Y_s2d -> Z_t[0:64) ----------------
__global__ void conv2_mfma_kernel(const unsigned short* __restrict__ ys,
                                  const unsigned short* __restrict__ wp,
                                  const float* __restrict__ bias,
                                  const float* __restrict__ sc, const float* __restrict__ sh,
                                  unsigned short* __restrict__ zt) {
    constexpr int STR = 136;
    __shared__ unsigned short lds[4 * 3 * 17 * STR];   // 55.5 KB
    int bid = blockIdx.x;
    int qp = bid & 7;
    int b = bid >> 3;
    int oy0 = qp * 2;
    for (int i = threadIdx.x; i < 3264; i += 256) {
        int icc = i & 15; int t = i >> 4;
        int col = t % 17; int rc = t / 17;
        int row = rc % 3; int pl = rc / 3;
        int py = pl >> 1, px = pl & 1;
        int j = oy0 - py + row;
        int ci = col - px;
        uint4 v = {0u, 0u, 0u, 0u};
        if (((unsigned)j < 16u) & ((unsigned)ci < 16u)) {
            v = *(const uint4*)(ys + ((size_t)((b * 4 + pl) * 16 + j) * 16 + ci) * 128 + icc * 8);
            v = bn_fuse8(v, sc, sh, icc * 8, 0.2f);
        }
        *(uint4*)(lds + ((pl * 3 + row) * 17 + col) * STR + icc * 8) = v;
    }
    __syncthreads();

    int wv = threadIdx.x >> 6, lane = threadIdx.x & 63;
    int r = wv >> 1, jh = wv & 1;
    int m = lane & 15, kq = lane >> 4;
    f32x4 acc[2];
    acc[0] = (f32x4){0.f, 0.f, 0.f, 0.f};
    acc[1] = acc[0];
#pragma unroll
    for (int ky = 0; ky < 4; ++ky) {
        int py = (ky & 1) ^ 1;
        int lrow = r + (ky >> 1);
#pragma unroll
        for (int kx = 0; kx < 4; ++kx) {
            int px = (kx & 1) ^ 1;
            int pl = py * 2 + px;
            int lcol = m + (kx >> 1);
            const unsigned short* lp = lds + ((pl * 3 + lrow) * 17 + lcol) * STR + kq * 8;
            int ktap = ky * 4 + kx;
            const unsigned short* bb = wp + (size_t)ktap * 8192;
#pragma unroll
            for (int kc = 0; kc < 4; ++kc) {
                bf16x8 a = *(const bf16x8*)(lp + kc * 32);
                const unsigned short* bk = bb + kc * 2048 + (jh * 2) * 512 + lane * 8;
                bf16x8 b0 = *(const bf16x8*)(bk);
                bf16x8 b1 = *(const bf16x8*)(bk + 512);
                acc[0] = __builtin_amdgcn_mfma_f32_16x16x32_bf16(a, b0, acc[0], 0, 0, 0);
                acc[1] = __builtin_amdgcn_mfma_f32_16x16x32_bf16(a, b1, acc[1], 0, 0, 0);
            }
        }
    }
    int oy = oy0 + r;
    int n = m;
    float bv0 = bias[(jh * 2) * 16 + n], bv1 = bias[(jh * 2 + 1) * 16 + n];
#pragma unroll
    for (int reg = 0; reg < 4; ++reg) {
        int x = kq * 4 + reg;
        size_t base = ((size_t)(b * 16 + oy) * 16 + x) * 192 + (jh * 2) * 16 + n;
        zt[base]      = f2bf(tanhf(acc[0][reg] + bv0));
        zt[base + 16] = f2bf(tanhf(acc[1][reg] + bv1));
    }
}

// ---------------- assemble Z_t[...][64:192): Zl, Zg, wave, and pad channels ----------------
__global__ void assemble_z(const void* __restrict__ Zl, const void* __restrict__ Zg,
                           const void* __restrict__ phi, const float* __restrict__ K12,
                           unsigned short* __restrict__ zt, const int* __restrict__ flg) {
    bool f32 = flg[0] != 0;
    int i = blockIdx.x * 256 + threadIdx.x;
    const int TOT = 64 * 128 * 256;
    if (i >= TOT) return;
    int pos = i & 255;
    int t = i >> 8;
    int c128 = t % 128;
    int b = t / 128;
    float val;
    if (c128 < 32) {
        val = loadIn(Zl, ((size_t)(b * 32 + c128) << 8) + pos, f32);
    } else if (c128 < 96) {
        val = loadIn(Zg, ((size_t)(b * 64 + (c128 - 32)) << 8) + pos, f32);
    } else if (c128 < 104) {
        int p = c128 - 96;
        int y = pos >> 4, x = pos & 15;
        float k1 = K12[b * 16 + p];
        float k2 = K12[b * 16 + 8 + p];
        val = sinf(k1 * (float)y + k2 * (float)x + loadIn(phi, b * 8 + p, f32) * TWO_PI_F);
    } else {
        val = 0.f;      // pad channels 168..192 of Z_t
    }
    zt[((size_t)(b * 256 + pos)) * 192 + 64 + c128] = f2bf(val);
}

// ---------------- MFMA transposed-conv v7: QR=2, oct slowest, fused BN-in + fused stats-out ----------------
// __launch_bounds__(256, 2): the min-waves bound only sets the ALLOCATOR BUDGET (256 regs);
// actual occupancy follows the real allocation (~100 regs -> 4-5 waves/SIMD, LDS allows 4 blk/CU).
// Round-5 regression root cause: (256,4) squeezed alloc to 64 VGPR with ~80-90 live values ->
// L2-resident scratch spill in the MFMA loop (invisible in FETCH/WRITE, MfmaUtil 28->17).
template <int ICP, int Q, int OC, int QR, bool BN, bool ST>
__global__ __launch_bounds__(256, 2)
void deconv_mfma2_kernel(const unsigned short* __restrict__ in_t,
                         const unsigned short* __restrict__ wp2,
                         const float* __restrict__ bias,
                         const float* __restrict__ sc, const float* __restrict__ sh,
                         float* __restrict__ gsum, float* __restrict__ gsq, int statoff,
                         unsigned short* __restrict__ out_t) {
    constexpr int NOCT = OC / 64;
    constexpr int NK = ICP / 32;
    constexpr int XT = Q / 16;
    constexpr int NQB = Q / QR;
    constexpr int ROWS = QR + 2;
    constexpr int STRIDE = ICP + 8;
    constexpr int NTILES = XT * NQB * 64;
    __shared__ unsigned short lds[ROWS * 18 * STRIDE];
    __shared__ float sstat[64], qstat[64];

    int bid = blockIdx.x;
    int oct = bid / NTILES;          // slowest dim
    bid -= oct * NTILES;
    int xt = bid % XT;
    int t2 = bid / XT;
    int qp = t2 % NQB;
    int b = t2 / NQB;
    int qy0 = qp * QR;
    int x0 = xt * 16;

    constexpr int P8 = ICP / 8;
    constexpr int E8 = ROWS * 18 * P8;
    for (int i = threadIdx.x; i < E8; i += 256) {
        int icc = i % P8;
        int rc = i / P8;
        int row = rc / 18, col = rc % 18;
        int y = qy0 - 1 + row, x = x0 - 1 + col;
        uint4 val = {0u, 0u, 0u, 0u};
        if (((unsigned)y < (unsigned)Q) & ((unsigned)x < (unsigned)Q)) {
            val = *(const uint4*)(in_t + (size_t)((b * Q + y) * Q + x) * ICP + icc * 8);
            if (BN) val = bn_fuse8(val, sc, sh, icc * 8, 0.f);
        }
        *(uint4*)(lds + rc * STRIDE + icc * 8) = val;
    }
    if (ST && threadIdx.x < 64) { sstat[threadIdx.x] = 0.f; qstat[threadIdx.x] = 0.f; }
    __syncthreads();

    int wv = threadIdx.x >> 6, lane = threadIdx.x & 63;
    int dy = wv >> 1, dx = wv & 1;
    int m = lane & 15, kq = lane >> 4;

    f32x4 acc[QR][4];
#pragma unroll
    for (int q = 0; q < QR; ++q)
#pragma unroll
        for (int j = 0; j < 4; ++j) acc[q][j] = (f32x4){0.f, 0.f, 0.f, 0.f};

#pragma unroll
    for (int t = 0; t < 4; ++t) {
        int rr = t >> 1, cc = t & 1;
        int ktap = ((3 - dy) - 2 * rr) * 4 + ((3 - dx) - 2 * cc);
        int col = m + dx + cc;
        int row0 = dy + rr;
        const unsigned short* bbase = wp2 + (size_t)((ktap * NOCT + oct) * NK) * 2048;
#pragma unroll
        for (int kc = 0; kc < NK; ++kc) {
            bf16x8 a[QR];
#pragma unroll
            for (int q = 0; q < QR; ++q)
                a[q] = *(const bf16x8*)(lds + ((row0 + q) * 18 + col) * STRIDE + kc * 32 + kq * 8);
            bf16x8 b0 = *(const bf16x8*)(bbase + (kc * 4 + 0) * 512 + lane * 8);
            bf16x8 b1 = *(const bf16x8*)(bbase + (kc * 4 + 1) * 512 + lane * 8);
            bf16x8 b2 = *(const bf16x8*)(bbase + (kc * 4 + 2) * 512 + lane * 8);
            bf16x8 b3 = *(const bf16x8*)(bbase + (kc * 4 + 3) * 512 + lane * 8);
#pragma unroll
            for (int q = 0; q < QR; ++q) {
                acc[q][0] = __builtin_amdgcn_mfma_f32_16x16x32_bf16(a[q], b0, acc[q][0], 0, 0, 0);
                acc[q][1] = __builtin_amdgcn_mfma_f32_16x16x32_bf16(a[q], b1, acc[q][1], 0, 0, 0);
                acc[q][2] = __builtin_amdgcn_mfma_f32_16x16x32_bf16(a[q], b2, acc[q][2], 0, 0, 0);
                acc[q][3] = __builtin_amdgcn_mfma_f32_16x16x32_bf16(a[q], b3, acc[q][3], 0, 0, 0);
            }
        }
    }
    // Epilogue: lane n holds channels oct*64 + 4n + j -> one contiguous ushort4 per (qyl,reg).
    int n = m;
    const float4 bv = *(const float4*)(bias + oct * 64 + 4 * n);
    float s0 = 0, s1 = 0, s2 = 0, s3 = 0, q0 = 0, q1 = 0, q2 = 0, q3 = 0;
#pragma unroll
    for (int qyl = 0; qyl < QR; ++qyl) {
        int oy = 2 * (qy0 + qyl) + dy;
#pragma unroll
        for (int reg = 0; reg < 4; ++reg) {
            int mm = kq * 4 + reg;
            int ox = 2 * (x0 + mm) + dx;
            size_t base = ((size_t)((b * 2 * Q + oy) * (2 * Q) + ox)) * OC + oct * 64 + 4 * n;
            float v0 = acc[qyl][0][reg] + bv.x;
            float v1 = acc[qyl][1][reg] + bv.y;
            float v2 = acc[qyl][2][reg] + bv.z;
            float v3 = acc[qyl][3][reg] + bv.w;
            if (ST) {
                s0 += v0; q0 += v0 * v0; s1 += v1; q1 += v1 * v1;
                s2 += v2; q2 += v2 * v2; s3 += v3; q3 += v3 * v3;
            }
            ushort4 tv;
            tv.x = f2bf(v0); tv.y = f2bf(v1); tv.z = f2bf(v2); tv.w = f2bf(v3);
            *(ushort4*)(out_t + base) = tv;
        }
    }
    if (ST) {
        atomicAdd(&sstat[4 * n + 0], s0); atomicAdd(&qstat[4 * n + 0], q0);
        atomicAdd(&sstat[4 * n + 1], s1); atomicAdd(&qstat[4 * n + 1], q1);
        atomicAdd(&sstat[4 * n + 2], s2); atomicAdd(&qstat[4 * n + 2], q2);
        atomicAdd(&sstat[4 * n + 3], s3); atomicAdd(&qstat[4 * n + 3], q3);
        __syncthreads();
        if (threadIdx.x < 64) {
            atomicAdd(&gsum[statoff + oct * 64 + threadIdx.x], sstat[threadIdx.x]);
            atomicAdd(&gsq[statoff + oct * 64 + threadIdx.x], qstat[threadIdx.x]);
        }
    }
}

// ---------------- deconv2 (MFMA, fused G1 BN+relu on load, OC=3 pad 16) + tanh -> fp32 NCHW ----------------
__global__ void deconv2_mfma_kernel(const unsigned short* __restrict__ yt,
                                    const unsigned short* __restrict__ wp,
                                    const float* __restrict__ bias,
                                    const float* __restrict__ sc, const float* __restrict__ sh,
                                    float* __restrict__ outp) {
    constexpr int Q = 64, ICP = 128, NK = 4, STRIDE = 136;
    __shared__ unsigned short lds[4 * 18 * STRIDE];   // 19.6 KB
    int bid = blockIdx.x;
    int xt = bid & 3;
    int t2 = bid >> 2;
    int qp = t2 & 31;
    int b = t2 >> 5;
    int qy0 = qp * 2, x0 = xt * 16;

    for (int i = threadIdx.x; i < 4 * 18 * 16; i += 256) {
        int icc = i & 15;
        int rc = i >> 4;
        int row = rc / 18, col = rc % 18;
        int y = qy0 - 1 + row, x = x0 - 1 + col;
        uint4 v = {0u, 0u, 0u, 0u};
        if (((unsigned)y < (unsigned)Q) & ((unsigned)x < (unsigned)Q)) {
            v = *(const uint4*)(yt + (size_t)((b * Q + y) * Q + x) * ICP + icc * 8);
            v = bn_fuse8(v, sc, sh, icc * 8, 0.f);
        }
        *(uint4*)(lds + rc * STRIDE + icc * 8) = v;
    }
    __syncthreads();

    int wv = threadIdx.x >> 6, lane = threadIdx.x & 63;
    int dy = wv >> 1, dx = wv & 1;
    int m = lane & 15, kq = lane >> 4;
    f32x4 acc0 = {0.f, 0.f, 0.f, 0.f}, acc1 = acc0;

#pragma unroll
    for (int t = 0; t < 4; ++t) {
        int rr = t >> 1, cc = t & 1;
        int ktap = ((3 - dy) - 2 * rr) * 4 + ((3 - dx) - 2 * cc);
        int col = m + dx + cc;
        int row0 = dy + rr;
        const unsigned short* bb = wp + (size_t)(ktap * NK) * 512;
#pragma unroll
        for (int kc = 0; kc < NK; ++kc) {
            bf16x8 a0 = *(const bf16x8*)(lds + (row0 * 18 + col) * STRIDE + kc * 32 + kq * 8);
            bf16x8 a1 = *(const bf16x8*)(lds + ((row0 + 1) * 18 + col) * STRIDE + kc * 32 + kq * 8);
            bf16x8 b0 = *(const bf16x8*)(bb + kc * 512 + lane * 8);
            acc0 = __builtin_amdgcn_mfma_f32_16x16x32_bf16(a0, b0, acc0, 0, 0, 0);
            acc1 = __builtin_amdgcn_mfma_f32_16x16x32_bf16(a1, b0, acc1, 0, 0, 0);
        }
    }
    int n = m;
    if (n < 3) {
        float bv = bias[n];
#pragma unroll
        for (int reg = 0; reg < 4; ++reg) {
            int mm = kq * 4 + reg;
            int ox = 2 * (x0 + mm) + dx;
            int oy0_ = 2 * qy0 + dy;
            size_t ob = (size_t)(b * 3 + n) * 16384;
            outp[ob + (size_t)oy0_ * 128 + ox]       = tanhf(acc0[reg] + bv);
            outp[ob + (size_t)(oy0_ + 2) * 128 + ox] = tanhf(acc1[reg] + bv);
        }
    }
}

// ---------------- channel-last BN stat reduction (only used for conv0 output) ----------------
template <int C>
__global__ void stat_reduce_t(const unsigned short* __restrict__ x, int total4,
                              float* __restrict__ ssum, float* __restrict__ ssq, int statoff) {
    __shared__ float ls[C], lq[C];
    for (int c = threadIdx.x; c < C; c += 256) { ls[c] = 0.f; lq[c] = 0.f; }
    __syncthreads();
    int i0 = blockIdx.x * 256 + threadIdx.x;
    int stride = gridDim.x * 256;
    int c0 = (i0 << 2) & (C - 1);
    float s0 = 0, s1 = 0, s2 = 0, s3 = 0, q0 = 0, q1 = 0, q2 = 0, q3 = 0;
    for (int i = i0; i < total4; i += stride) {
        ushort4 v = *(const ushort4*)(x + ((size_t)i << 2));
        float f0 = bf2f_raw(v.x), f1 = bf2f_raw(v.y), f2 = bf2f_raw(v.z), f3 = bf2f_raw(v.w);
        s0 += f0; s1 += f1; s2 += f2; s3 += f3;
        q0 += f0 * f0; q1 += f1 * f1; q2 += f2 * f2; q3 += f3 * f3;
    }
    atomicAdd(&ls[c0], s0); atomicAdd(&ls[c0 + 1], s1); atomicAdd(&ls[c0 + 2], s2); atomicAdd(&ls[c0 + 3], s3);
    atomicAdd(&lq[c0], q0); atomicAdd(&lq[c0 + 1], q1); atomicAdd(&lq[c0 + 2], q2); atomicAdd(&lq[c0 + 3], q3);
    __syncthreads();
    for (int c = threadIdx.x; c < C; c += 256) {
        atomicAdd(&ssum[statoff + c], ls[c]);
        atomicAdd(&ssq[statoff + c], lq[c]);
    }
}

// ---------------- BN finalize ----------------
__global__ void bn_fin_kernel(const float* __restrict__ ssum, const float* __restrict__ ssq,
                              const float* __restrict__ g, const float* __restrict__ be,
                              float* __restrict__ scale, float* __restrict__ shift,
                              int statoff, int C, float invN) {
    int c = threadIdx.x;
    if (c >= C) return;
    float m = ssum[statoff + c] * invN;
    float v = ssq[statoff + c] * invN - m * m;
    v = fmaxf(v, 0.f);
    float sc = g[c] * rsqrtf(v + 1e-5f);
    scale[statoff + c] = sc;
    shift[statoff + c] = be[c] - m * sc;
}

extern "C" void kernel_launch(void* const* d_in, const int* in_sizes, int n_in,
                              void* d_out, int out_size, void* d_ws, size_t ws_size,
                              hipStream_t stream) {
    if (ws_size < WS_NEED_BYTES) {
        hipMemsetAsync(d_out, 0, (size_t)out_size * 4, stream);
        return;
    }

    float* W = (float*)d_ws;
    unsigned short* U = (unsigned short*)d_ws;
    int* FLG = (int*)(W + OFF_FLAG);

    detect_kernel<<<1, 256, 0, stream>>>((const unsigned short*)d_in[2], FLG);

    CvtJobs J;
    const int srcIdx[16] = {10, 28, 11, 12, 13, 15, 16, 17, 19, 21, 22, 23, 25, 26, 27, 29};
    const int cnt[16]    = {3072, 6144, 64, 64, 64, 128, 128, 128, 64, 256, 256, 256, 128, 128, 128, 3};
    float* dsts[16] = {W + OFF_WC0, W + OFF_WG2,
                       W + OFF_CB0, W + OFF_CG0, W + OFF_CBE0, W + OFF_CB1, W + OFF_CG1, W + OFF_CBE1,
                       W + OFF_CB2, W + OFF_GB0, W + OFF_GG0, W + OFF_GBE0, W + OFF_GB1, W + OFF_GG1,
                       W + OFF_GBE1, W + OFF_GB2};
    int off = 0;
    for (int k = 0; k < 16; ++k) {
        J.src[k] = d_in[srcIdx[k]];
        J.dst[k] = dsts[k];
        J.off[k] = off;
        off += cnt[k];
    }
    J.off[16] = off;
    cvt_all_kernel<<<(off + 255) / 256, 256, 0, stream>>>(J, off, FLG);

    zero_kernel<<<5, 256, 0, stream>>>(W + OFF_SSUM, 1152);

    // weight packs
    pack_w2_kernel<<<3072, 256, 0, stream>>>(d_in[20], U + UW0, 168, 192, 256, FLG);
    pack_w2_kernel<<<2048, 256, 0, stream>>>(d_in[24], U + UW1, 256, 256, 128, FLG);
    pack_wc_kernel<<<512, 256, 0, stream>>>(d_in[14], U + UWC1, 64, 128, FLG);
    pack_wc_kernel<<<512, 256, 0, stream>>>(d_in[18], U + UWC2, 128, 64, FLG);
    pack_w2s_kernel<<<128, 256, 0, stream>>>(d_in[28], U + UW2, 128, 3, FLG);

    mlp_kernel<<<64, 64, 0, stream>>>(d_in[1], d_in[4], d_in[5], d_in[6], d_in[7],
                                      d_in[8], d_in[9], W + OFF_K12, FLG);

    // ---- conv0 -> X_s2d (raw) ----
    conv0_s2d_kernel<<<dim3(16, 1, 64), 256, 0, stream>>>(d_in[2], W + OFF_WC0, W + OFF_CB0,
                                                          U + UXT, FLG);
    stat_reduce_t<64><<<1024, 256, 0, stream>>>(U + UXT, 4194304, W + OFF_SSUM, W + OFF_SSQ, 0);
    bn_fin_kernel<<<1, 256, 0, stream>>>(W + OFF_SSUM, W + OFF_SSQ, W + OFF_CG0, W + OFF_CBE0,
                                         W + OFF_SCALE, W + OFF_SHIFT, 0, 64, 1.f / 262144.f);

    // ---- conv1 (MFMA, fused L0 BN, fused L1 stats) -> Y_s2d ----
    conv1_mfma_kernel<<<2048, 256, 0, stream>>>(U + UXT, U + UWC1, W + OFF_CB1,
                                                W + OFF_SCALE + 0, W + OFF_SHIFT + 0,
                                                W + OFF_SSUM, W + OFF_SSQ, U + UYT);
    bn_fin_kernel<<<1, 256, 0, stream>>>(W + OFF_SSUM, W + OFF_SSQ, W + OFF_CG1, W + OFF_CBE1,
                                         W + OFF_SCALE, W + OFF_SHIFT, 64, 128, 1.f / 65536.f);

    // ---- conv2 (MFMA, fused L1 BN) + tanh -> Z_t[0:64) ----
    conv2_mfma_kernel<<<512, 256, 0, stream>>>(U + UYT, U + UWC2, W + OFF_CB2,
                                               W + OFF_SCALE + 64, W + OFF_SHIFT + 64, U + UZT);

    // ---- Z_t[64:192) incl. pad zeroing ----
    assemble_z<<<8192, 256, 0, stream>>>(d_in[0], d_in[1], d_in[3], W + OFF_K12, U + UZT, FLG);

    // ---- gen deconv0 (MFMA, fused G0 stats): Z_t -> X_t(32,32,256) ----  grid = 4 oct * 512 tiles
    deconv_mfma2_kernel<192, 16, 256, 2, false, true><<<2048, 256, 0, stream>>>(
        U + UZT, U + UW0, W + OFF_GB0, nullptr, nullptr,
        W + OFF_SSUM, W + OFF_SSQ, 192, U + UXT);
    bn_fin_kernel<<<1, 256, 0, stream>>>(W + OFF_SSUM, W + OFF_SSQ, W + OFF_GG0, W + OFF_GBE0,
                                         W + OFF_SCALE, W + OFF_SHIFT, 192, 256, 1.f / 65536.f);

    // ---- gen deconv1 (MFMA, fused G0 BN, fused G1 stats): X_t -> Y_t(64,64,128) ----  grid = 2 oct * 2048 tiles
    deconv_mfma2_kernel<256, 32, 128, 2, true, true><<<4096, 256, 0, stream>>>(
        U + UXT, U + UW1, W + OFF_GB1, W + OFF_SCALE + 192, W + OFF_SHIFT + 192,
        W + OFF_SSUM, W + OFF_SSQ, 448, U + UYT);
    bn_fin_kernel<<<1, 256, 0, stream>>>(W + OFF_SSUM, W + OFF_SSQ, W + OFF_GG1, W + OFF_GBE1,
                                         W + OFF_SCALE, W + OFF_SHIFT, 448, 128, 1.f / 262144.f);

    // ---- gen deconv2 (MFMA, fused G1 BN) + tanh -> d_out fp32 ----
    deconv2_mfma_kernel<<<8192, 256, 0, stream>>>(U + UYT, U + UW2, W + OFF_GB2,
                                                  W + OFF_SCALE + 448, W + OFF_SHIFT + 448,
                                                  (float*)d_out);
}

// Round 7
// 628.073 us; speedup vs baseline: 1.1279x; 1.1279x over previous
//
#include <hip/hip_runtime.h>
#include <hip/hip_bf16.h>

#define TWO_PI_F 6.2831853071795864769f

typedef __attribute__((ext_vector_type(8))) __bf16 bf16x8;
typedef __attribute__((ext_vector_type(4))) float f32x4;

// 8-way replicated stat buffers: per-address atomic chains drop 8x.
#define NREP 8

__device__ __forceinline__ float bf2f_raw(unsigned short u) {
    return __uint_as_float(((unsigned int)u) << 16);
}
__device__ __forceinline__ unsigned short f2bf(float f) {
    unsigned int u = __float_as_uint(f);
    unsigned int r = (u + 0x7FFFu + ((u >> 16) & 1u)) >> 16;   // RNE
    return (unsigned short)r;
}
__device__ __forceinline__ float loadIn(const void* p, size_t i, bool f32) {
    return f32 ? ((const float*)p)[i] : bf2f_raw(((const unsigned short*)p)[i]);
}

// Fused BN affine + (leaky)relu applied to 8 packed bf16 during staging.
__device__ __forceinline__ uint4 bn_fuse8(uint4 v, const float* __restrict__ sc,
                                          const float* __restrict__ sh, int c0, float slope) {
    unsigned short us[8];
    *(uint4*)us = v;
#pragma unroll
    for (int k = 0; k < 8; ++k) {
        float f = bf2f_raw(us[k]) * sc[c0 + k] + sh[c0 + k];
        f = f > 0.f ? f : slope * f;
        us[k] = f2bf(f);
    }
    return *(const uint4*)us;
}

// ---------------- ws layout ----------------
static constexpr size_t OFF_WC0 = 0;          // cod_w0 fp32 3072
static constexpr size_t OFF_WG2 = 3072;       // gen_w2 fp32 6144 (legacy, unused)
static constexpr size_t OFF_P   = 9216;
static constexpr size_t OFF_CB0 = OFF_P + 0;
static constexpr size_t OFF_CG0 = OFF_P + 64;
static constexpr size_t OFF_CBE0= OFF_P + 128;
static constexpr size_t OFF_CB1 = OFF_P + 192;
static constexpr size_t OFF_CG1 = OFF_P + 320;
static constexpr size_t OFF_CBE1= OFF_P + 448;
static constexpr size_t OFF_CB2 = OFF_P + 576;
static constexpr size_t OFF_GB0 = OFF_P + 640;
static constexpr size_t OFF_GG0 = OFF_P + 896;
static constexpr size_t OFF_GBE0= OFF_P + 1152;
static constexpr size_t OFF_GB1 = OFF_P + 1408;
static constexpr size_t OFF_GG1 = OFF_P + 1536;
static constexpr size_t OFF_GBE1= OFF_P + 1664;
static constexpr size_t OFF_GB2 = OFF_P + 1792;
static constexpr size_t OFF_SSUM  = OFF_P + 2048;              // NREP x 576
static constexpr size_t OFF_SSQ   = OFF_SSUM + NREP * 576;     // NREP x 576
static constexpr size_t OFF_SCALE = OFF_SSQ + NREP * 576;
static constexpr size_t OFF_SHIFT = OFF_SCALE + 576;
static constexpr size_t OFF_K12   = OFF_SHIFT + 576;
static constexpr size_t OFF_FLAG  = OFF_K12 + 1024;
static constexpr size_t FP32_END  = OFF_FLAG + 16;   // floats
// ushort regions:
static constexpr size_t UXT = 2 * FP32_END;            // X region: X_s2d (b,2,2,32,32,64) then X_t (b,32,32,256)
static constexpr size_t UYT = UXT + 16777216;          // Y region: Y_s2d head, then Y_t (b,64,64,128)
static constexpr size_t UZT = UYT + 8388608;           // Z_t (b,16,16,192)
static constexpr size_t UW0 = UYT + 33554432;          // deconv0 pack
static constexpr size_t UW1 = UW0 + 786432;            // deconv1 pack
static constexpr size_t UWC1 = UW1 + 524288;           // conv1 pack
static constexpr size_t UWC2 = UWC1 + 131072;          // conv2 pack
static constexpr size_t UW2 = UWC2 + 131072;           // deconv2 pack
static constexpr size_t WS_END_USHORT = UW2 + 32768;
static constexpr size_t WS_NEED_BYTES = WS_END_USHORT * 2;   // ~110 MB

// stat slots: L0:0(64) L1:64(128) G0:192(256) G1:448(128)

// ---------------- input dtype detection ----------------
__global__ void detect_kernel(const unsigned short* __restrict__ imgs, int* __restrict__ flag) {
    int t = threadIdx.x;  // 256
    unsigned short u = imgs[t];
    int e = (u >> 7) & 0xFF;
    unsigned long long b = __ballot(e >= 0xC0);
    __shared__ int cnt[4];
    if ((t & 63) == 0) cnt[t >> 6] = __popcll(b);
    __syncthreads();
    if (t == 0) flag[0] = (cnt[0] + cnt[1] + cnt[2] + cnt[3] >= 4) ? 1 : 0;
}

// ---------------- small param -> fp32 conversion ----------------
struct CvtJobs {
    const void* src[16];
    float* dst[16];
    int off[17];
};

__global__ void cvt_all_kernel(CvtJobs J, int total, const int* __restrict__ flg) {
    int i = blockIdx.x * 256 + threadIdx.x;
    if (i >= total) return;
    bool f32 = flg[0] != 0;
    int k = 0;
#pragma unroll
    for (int t = 0; t < 15; ++t) { if (i >= J.off[t + 1]) k = t + 1; }
    int r = i - J.off[k];
    J.dst[k][r] = loadIn(J.src[k], r, f32);
}

__global__ void zero_kernel(float* p, int n) {
    int i = blockIdx.x * 256 + threadIdx.x;
    if (i < n) p[i] = 0.f;
}

// ---------------- deconv weight packing ----------------
__global__ void pack_w2_kernel(const void* __restrict__ src, unsigned short* __restrict__ dst,
                               int ICreal, int ICP, int OC, const int* __restrict__ flg) {
    bool f32 = flg[0] != 0;
    int i = blockIdx.x * 256 + threadIdx.x;
    int total = 16 * OC * ICP;
    if (i >= total) return;
    int jj = i & 7;
    int lane = (i >> 3) & 63;
    int j = (i >> 9) & 3;
    int t3 = i >> 11;
    int NK = ICP / 32;
    int kc = t3 % NK;
    int t4 = t3 / NK;
    int NOCT = OC / 64;
    int oct = t4 % NOCT;
    int ktap = t4 / NOCT;
    int kq = lane >> 4, n = lane & 15;
    int ic = kc * 32 + kq * 8 + jj;
    int oc = oct * 64 + n * 4 + j;          // channel-interleaved
    unsigned short v = 0;
    if (ic < ICreal) v = f2bf(loadIn(src, ((size_t)(ic * OC + oc) << 4) + ktap, f32));
    dst[i] = v;
}

__global__ void pack_w2s_kernel(const void* __restrict__ src, unsigned short* __restrict__ dst,
                                int ICP, int OCreal, const int* __restrict__ flg) {
    bool f32 = flg[0] != 0;
    int i = blockIdx.x * 256 + threadIdx.x;
    int NK = ICP / 32;
    int total = 16 * NK * 512;
    if (i >= total) return;
    int jj = i & 7;
    int lane = (i >> 3) & 63;
    int t3 = i >> 9;
    int kc = t3 % NK;
    int ktap = t3 / NK;
    int kq = lane >> 4, n = lane & 15;
    int ic = kc * 32 + kq * 8 + jj;
    unsigned short v = 0;
    if (n < OCreal) v = f2bf(loadIn(src, ((size_t)(ic * OCreal + n) << 4) + ktap, f32));
    dst[i] = v;
}

__global__ void pack_wc_kernel(const void* __restrict__ src, unsigned short* __restrict__ dst,
                               int IC, int OC, const int* __restrict__ flg) {
    bool f32 = flg[0] != 0;
    int i = blockIdx.x * 256 + threadIdx.x;
    int total = 16 * OC * IC;
    if (i >= total) return;
    int jj = i & 7;
    int lane = (i >> 3) & 63;
    int j = (i >> 9) & 3;
    int t3 = i >> 11;
    int NK = IC / 32;
    int kc = t3 % NK;
    int t4 = t3 / NK;
    int NOCT = OC / 64;
    int oct = t4 % NOCT;
    int ktap = t4 / NOCT;
    int kq = lane >> 4, n = lane & 15;
    int ic = kc * 32 + kq * 8 + jj;
    int oc = oct * 64 + j * 16 + n;
    dst[i] = f2bf(loadIn(src, ((size_t)(oc * IC + ic) << 4) + ktap, f32));
}

// ---------------- tiny MLP ----------------
__global__ void mlp_kernel(const void* __restrict__ Zg,
                           const void* __restrict__ lW, const void* __restrict__ lb,
                           const void* __restrict__ l1W, const void* __restrict__ l1b,
                           const void* __restrict__ l2W, const void* __restrict__ l2b,
                           float* __restrict__ K12, const int* __restrict__ flg) {
    bool f32 = flg[0] != 0;
    int b = blockIdx.x;
    int t = threadIdx.x;  // 64
    __shared__ float xs[64];
    float acc = loadIn(lb, t, f32);
    for (int c = 0; c < 64; ++c)
        acc += loadIn(Zg, (size_t)(b * 64 + c) * 256, f32) * loadIn(lW, t * 64 + c, f32);
    xs[t] = fmaxf(acc, 0.f);
    __syncthreads();
    if (t < 16) {
        int p = t & 7;
        const void* Wp = (t < 8) ? l1W : l2W;
        const void* bp = (t < 8) ? l1b : l2b;
        float a = loadIn(bp, p, f32);
        for (int h = 0; h < 64; ++h) a += xs[h] * loadIn(Wp, p * 64 + h, f32);
        K12[b * 16 + t] = a;
    }
}

// ---------------- conv0: imgs -> X_s2d ----------------
__global__ void conv0_s2d_kernel(const void* __restrict__ imgs, const float* __restrict__ w,
                                 const float* __restrict__ bias, unsigned short* __restrict__ xs,
                                 const int* __restrict__ flg) {
    bool f32 = flg[0] != 0;
    int b = blockIdx.z;
    int tile = blockIdx.x;
    int Y0 = (tile >> 2) * 16, X0 = (tile & 3) * 16;
    __shared__ float vin[3 * 34 * 35];
    __shared__ float wl[64 * 49];
    for (int i = threadIdx.x; i < 3 * 34 * 34; i += 256) {
        int c = i % 34; int t = i / 34; int r = t % 34; int ic = t / 34;
        int iy = 2 * Y0 - 1 + r, ix = 2 * X0 - 1 + c;
        float v = 0.f;
        if (((unsigned)iy < 128u) & ((unsigned)ix < 128u))
            v = loadIn(imgs, ((size_t)(b * 3 + ic) * 128 + iy) * 128 + ix, f32);
        vin[(ic * 34 + r) * 35 + c] = v;
    }
    for (int i = threadIdx.x; i < 3072; i += 256) {
        int oc = i / 48, idx = i % 48;
        wl[oc * 49 + idx] = w[i];
    }
    __syncthreads();
    int q = threadIdx.x >> 2;
    int ocq = threadIdx.x & 3;
    int qy = q >> 3, qx = q & 7;
    float acc[4][16];
#pragma unroll
    for (int p = 0; p < 4; ++p)
#pragma unroll
        for (int o = 0; o < 16; ++o) acc[p][o] = 0.f;
    for (int ic = 0; ic < 3; ++ic) {
        float v[6][6];
#pragma unroll
        for (int r = 0; r < 6; ++r)
#pragma unroll
            for (int c = 0; c < 6; ++c)
                v[r][c] = vin[(ic * 34 + 4 * qy + r) * 35 + 4 * qx + c];
#pragma unroll
        for (int o = 0; o < 16; ++o) {
            const float* wo = wl + (ocq * 16 + o) * 49 + ic * 16;
#pragma unroll
            for (int ky = 0; ky < 4; ++ky)
#pragma unroll
                for (int kx = 0; kx < 4; ++kx) {
                    float wv = wo[ky * 4 + kx];
                    acc[0][o] = fmaf(v[ky][kx], wv, acc[0][o]);
                    acc[1][o] = fmaf(v[ky][kx + 2], wv, acc[1][o]);
                    acc[2][o] = fmaf(v[ky + 2][kx], wv, acc[2][o]);
                    acc[3][o] = fmaf(v[ky + 2][kx + 2], wv, acc[3][o]);
                }
        }
    }
    int j = (Y0 >> 1) + qy, i2 = (X0 >> 1) + qx;
#pragma unroll
    for (int p = 0; p < 4; ++p) {
        int dy = p >> 1, dx = p & 1;
        unsigned short tmp[16];
#pragma unroll
        for (int o = 0; o < 16; ++o) tmp[o] = f2bf(acc[p][o] + bias[ocq * 16 + o]);
        unsigned short* dst = xs + (((size_t)((b * 2 + dy) * 2 + dx) * 32 + j) * 32 + i2) * 64 + ocq * 16;
        *(uint4*)(dst) = *(const uint4*)(tmp);
        *(uint4*)(dst + 8) = *(const uint4*)(tmp + 8);
    }
}

// ---------------- conv1 (MFMA, fused L0 BN on load, fused L1 stats w/ replicas): X_s2d -> Y_s2d ----------------
__global__ void conv1_mfma_kernel(const unsigned short* __restrict__ xs,
                                  const unsigned short* __restrict__ wp,
                                  const float* __restrict__ bias,
                                  const float* __restrict__ sc, const float* __restrict__ sh,
                                  float* __restrict__ gsum, float* __restrict__ gsq,
                                  unsigned short* __restrict__ ys) {
    constexpr int STR = 72;
    __shared__ unsigned short lds[4 * 3 * 17 * STR];   // 29.4 KB
    __shared__ float cs[128], cq[128];
    int bid = blockIdx.x;
    int slot = (bid & (NREP - 1)) * 576;
    int xt = bid & 1;
    int qp = (bid >> 1) & 15;
    int b = bid >> 5;
    int oy0 = qp * 2, x0 = xt * 16;
    for (int i = threadIdx.x; i < 1632; i += 256) {
        int icc = i & 7; int t = i >> 3;
        int col = t % 17; int rc = t / 17;
        int row = rc % 3; int pl = rc / 3;
        int py = pl >> 1, px = pl & 1;
        int j = oy0 - py + row;
        int ci = x0 - px + col;
        uint4 v = {0u, 0u, 0u, 0u};
        if (((unsigned)j < 32u) & ((unsigned)ci < 32u)) {
            v = *(const uint4*)(xs + ((size_t)((b * 4 + pl) * 32 + j) * 32 + ci) * 64 + icc * 8);
            v = bn_fuse8(v, sc, sh, icc * 8, 0.2f);
        }
        *(uint4*)(lds + ((pl * 3 + row) * 17 + col) * STR + icc * 8) = v;
    }
    if (threadIdx.x < 128) { cs[threadIdx.x] = 0.f; cq[threadIdx.x] = 0.f; }
    __syncthreads();

    int wv = threadIdx.x >> 6, lane = threadIdx.x & 63;
    int r = wv >> 1, oct = wv & 1;
    int m = lane & 15, kq = lane >> 4;
    f32x4 acc[4];
#pragma unroll
    for (int j = 0; j < 4; ++j) acc[j] = (f32x4){0.f, 0.f, 0.f, 0.f};

#pragma unroll
    for (int ky = 0; ky < 4; ++ky) {
        int py = (ky & 1) ^ 1;
        int lrow = r + (ky >> 1);
#pragma unroll
        for (int kx = 0; kx < 4; ++kx) {
            int px = (kx & 1) ^ 1;
            int pl = py * 2 + px;
            int lcol = m + (kx >> 1);
            const unsigned short* lp = lds + ((pl * 3 + lrow) * 17 + lcol) * STR + kq * 8;
            int ktap = ky * 4 + kx;
            const unsigned short* bb = wp + (size_t)(ktap * 2 + oct) * 4096;
#pragma unroll
            for (int kc = 0; kc < 2; ++kc) {
                bf16x8 a = *(const bf16x8*)(lp + kc * 32);
                const unsigned short* bk = bb + kc * 2048 + lane * 8;
                bf16x8 b0 = *(const bf16x8*)(bk);
                bf16x8 b1 = *(const bf16x8*)(bk + 512);
                bf16x8 b2 = *(const bf16x8*)(bk + 1024);
                bf16x8 b3 = *(const bf16x8*)(bk + 1536);
                acc[0] = __builtin_amdgcn_mfma_f32_16x16x32_bf16(a, b0, acc[0], 0, 0, 0);
                acc[1] = __builtin_amdgcn_mfma_f32_16x16x32_bf16(a, b1, acc[1], 0, 0, 0);
                acc[2] = __builtin_amdgcn_mfma_f32_16x16x32_bf16(a, b2, acc[2], 0, 0, 0);
                acc[3] = __builtin_amdgcn_mfma_f32_16x16x32_bf16(a, b3, acc[3], 0, 0, 0);
            }
        }
    }
    int oy = oy0 + r;
    int pyo = oy & 1, jo = oy >> 1;
    int n = m;
    float bv0 = bias[oct * 64 + n], bv1 = bias[oct * 64 + 16 + n];
    float bv2 = bias[oct * 64 + 32 + n], bv3 = bias[oct * 64 + 48 + n];
    float s0 = 0, s1 = 0, s2 = 0, s3 = 0, q0 = 0, q1 = 0, q2 = 0, q3 = 0;
#pragma unroll
    for (int reg = 0; reg < 4; ++reg) {
        int mm = kq * 4 + reg;
        int ox = x0 + mm;
        int pxo = ox & 1, io = ox >> 1;
        size_t base = (((size_t)((b * 2 + pyo) * 2 + pxo) * 16 + jo) * 16 + io) * 128 + oct * 64 + n;
        float v0 = acc[0][reg] + bv0, v1 = acc[1][reg] + bv1;
        float v2 = acc[2][reg] + bv2, v3 = acc[3][reg] + bv3;
        s0 += v0; q0 += v0 * v0; s1 += v1; q1 += v1 * v1;
        s2 += v2; q2 += v2 * v2; s3 += v3; q3 += v3 * v3;
        ys[base]      = f2bf(v0);
        ys[base + 16] = f2bf(v1);
        ys[base + 32] = f2bf(v2);
        ys[base + 48] = f2bf(v3);
    }
    atomicAdd(&cs[oct * 64 + n], s0);      atomicAdd(&cq[oct * 64 + n], q0);
    atomicAdd(&cs[oct * 64 + 16 + n], s1); atomicAdd(&cq[oct * 64 + 16 + n], q1);
    atomicAdd(&cs[oct * 64 + 32 + n], s2); atomicAdd(&cq[oct * 64 + 32 + n], q2);
    atomicAdd(&cs[oct * 64 + 48 + n], s3); atomicAdd(&cq[oct * 64 + 48 + n], q3);
    __syncthreads();
    if (threadIdx.x < 128) {
        atomicAdd(&gsum[slot + 64 + threadIdx.x], cs[threadIdx.x]);
        atomicAdd(&gsq[slot + 64 + threadIdx.x], cq[threadIdx.x]);
    }
}

// ---------------- conv2 (MFMA, fused L1 BN on load) + tanh: Y_s2d -> Z_t[0:64) ----------------
__global__ void conv2_mfma_kernel(const unsigned short* __restrict__ ys,
                                  const unsigned short* __restrict__ wp,
                                  const float* __restrict__ bias,
                                  const float* __restrict__ sc, const float* __restrict__ sh,
                                  unsigned short* __restrict__ zt) {
    constexpr int STR = 136;
    __shared__ unsigned short lds[4 * 3 * 17 * STR];   // 55.5 KB
    int bid = blockIdx.x;
    int qp = bid & 7;
    int b = bid >> 3;
    int oy0 = qp * 2;
    for (int i = threadIdx.x; i < 3264; i += 256) {
        int icc = i & 15; int t = i >> 4;
        int col = t % 17; int rc = t / 17;
        int row = rc % 3; int pl = rc / 3;
        int py = pl >> 1, px = pl & 1;
        int j = oy0 - py + row;
        int ci = col - px;
        uint4 v = {0u, 0u, 0u, 0u};
        if (((unsigned)j < 16u) & ((unsigned)ci < 16u)) {
            v = *(const uint4*)(ys + ((size_t)((b * 4 + pl) * 16 + j) * 16 + ci) * 128 + icc * 8);
            v = bn_fuse8(v, sc, sh, icc * 8, 0.2f);
        }
        *(uint4*)(lds + ((pl * 3 + row) * 17 + col) * STR + icc * 8) = v;
    }
    __syncthreads();

    int wv = threadIdx.x >> 6, lane = threadIdx.x & 63;
    int r = wv >> 1, jh = wv & 1;
    int m = lane & 15, kq = lane >> 4;
    f32x4 acc[2];
    acc[0] = (f32x4){0.f, 0.f, 0.f, 0.f};
    acc[1] = acc[0];
#pragma unroll
    for (int ky = 0; ky < 4; ++ky) {
        int py = (ky & 1) ^ 1;
        int lrow = r + (ky >> 1);
#pragma unroll
        for (int kx = 0; kx < 4; ++kx) {
            int px = (kx & 1) ^ 1;
            int pl = py * 2 + px;
            int lcol = m + (kx >> 1);
            const unsigned short* lp = lds + ((pl * 3 + lrow) * 17 + lcol) * STR + kq * 8;
            int ktap = ky * 4 + kx;
            const unsigned short* bb = wp + (size_t)ktap * 8192;
#pragma unroll
            for (int kc = 0; kc < 4; ++kc) {
                bf16x8 a = *(const bf16x8*)(lp + kc * 32);
                const unsigned short* bk = bb + kc * 2048 + (jh * 2) * 512 + lane * 8;
                bf16x8 b0 = *(const bf16x8*)(bk);
                bf16x8 b1 = *(const bf16x8*)(bk + 512);
                acc[0] = __builtin_amdgcn_mfma_f32_16x16x32_bf16(a, b0, acc[0], 0, 0, 0);
                acc[1] = __builtin_amdgcn_mfma_f32_16x16x32_bf16(a, b1, acc[1], 0, 0, 0);
            }
        }
    }
    int oy = oy0 + r;
    int n = m;
    float bv0 = bias[(jh * 2) * 16 + n], bv1 = bias[(jh * 2 + 1) * 16 + n];
#pragma unroll
    for (int reg = 0; reg < 4; ++reg) {
        int x = kq * 4 + reg;
        size_t base = ((size_t)(b * 16 + oy) * 16 + x) * 192 + (jh * 2) * 16 + n;
        zt[base]      = f2bf(tanhf(acc[0][reg] + bv0));
        zt[base + 16] = f2bf(tanhf(acc[1][reg] + bv1));
    }
}

// ---------------- assemble Z_t[...][64:192): Zl, Zg, wave, and pad channels ----------------
__global__ void assemble_z(const void* __restrict__ Zl, const void* __restrict__ Zg,
                           const void* __restrict__ phi, const float* __restrict__ K12,
                           unsigned short* __restrict__ zt, const int* __restrict__ flg) {
    bool f32 = flg[0] != 0;
    int i = blockIdx.x * 256 + threadIdx.x;
    const int TOT = 64 * 128 * 256;
    if (i >= TOT) return;
    int pos = i & 255;
    int t = i >> 8;
    int c128 = t % 128;
    int b = t / 128;
    float val;
    if (c128 < 32) {
        val = loadIn(Zl, ((size_t)(b * 32 + c128) << 8) + pos, f32);
    } else if (c128 < 96) {
        val = loadIn(Zg, ((size_t)(b * 64 + (c128 - 32)) << 8) + pos, f32);
    } else if (c128 < 104) {
        int p = c128 - 96;
        int y = pos >> 4, x = pos & 15;
        float k1 = K12[b * 16 + p];
        float k2 = K12[b * 16 + 8 + p];
        val = sinf(k1 * (float)y + k2 * (float)x + loadIn(phi, b * 8 + p, f32) * TWO_PI_F);
    } else {
        val = 0.f;      // pad channels 168..192 of Z_t
    }
    zt[((size_t)(b * 256 + pos)) * 192 + 64 + c128] = f2bf(val);
}

// ---------------- MFMA transposed-conv v8: QR=2, oct slowest, fused BN-in + replicated stats-out ----------------
template <int ICP, int Q, int OC, int QR, bool BN, bool ST>
__global__ __launch_bounds__(256, 2)
void deconv_mfma2_kernel(const unsigned short* __restrict__ in_t,
                         const unsigned short* __restrict__ wp2,
                         const float* __restrict__ bias,
                         const float* __restrict__ sc, const float* __restrict__ sh,
                         float* __restrict__ gsum, float* __restrict__ gsq, int statoff,
                         unsigned short* __restrict__ out_t) {
    constexpr int NOCT = OC / 64;
    constexpr int NK = ICP / 32;
    constexpr int XT = Q / 16;
    constexpr int NQB = Q / QR;
    constexpr int ROWS = QR + 2;
    constexpr int STRIDE = ICP + 8;
    constexpr int NTILES = XT * NQB * 64;
    __shared__ unsigned short lds[ROWS * 18 * STRIDE];
    __shared__ float sstat[64], qstat[64];

    int bid = blockIdx.x;
    int slot = (bid & (NREP - 1)) * 576;
    int oct = bid / NTILES;          // slowest dim
    bid -= oct * NTILES;
    int xt = bid % XT;
    int t2 = bid / XT;
    int qp = t2 % NQB;
    int b = t2 / NQB;
    int qy0 = qp * QR;
    int x0 = xt * 16;

    constexpr int P8 = ICP / 8;
    constexpr int E8 = ROWS * 18 * P8;
    for (int i = threadIdx.x; i < E8; i += 256) {
        int icc = i % P8;
        int rc = i / P8;
        int row = rc / 18, col = rc % 18;
        int y = qy0 - 1 + row, x = x0 - 1 + col;
        uint4 val = {0u, 0u, 0u, 0u};
        if (((unsigned)y < (unsigned)Q) & ((unsigned)x < (unsigned)Q)) {
            val = *(const uint4*)(in_t + (size_t)((b * Q + y) * Q + x) * ICP + icc * 8);
            if (BN) val = bn_fuse8(val, sc, sh, icc * 8, 0.f);
        }
        *(uint4*)(lds + rc * STRIDE + icc * 8) = val;
    }
    if (ST && threadIdx.x < 64) { sstat[threadIdx.x] = 0.f; qstat[threadIdx.x] = 0.f; }
    __syncthreads();

    int wv = threadIdx.x >> 6, lane = threadIdx.x & 63;
    int dy = wv >> 1, dx = wv & 1;
    int m = lane & 15, kq = lane >> 4;

    f32x4 acc[QR][4];
#pragma unroll
    for (int q = 0; q < QR; ++q)
#pragma unroll
        for (int j = 0; j < 4; ++j) acc[q][j] = (f32x4){0.f, 0.f, 0.f, 0.f};

#pragma unroll
    for (int t = 0; t < 4; ++t) {
        int rr = t >> 1, cc = t & 1;
        int ktap = ((3 - dy) - 2 * rr) * 4 + ((3 - dx) - 2 * cc);
        int col = m + dx + cc;
        int row0 = dy + rr;
        const unsigned short* bbase = wp2 + (size_t)((ktap * NOCT + oct) * NK) * 2048;
#pragma unroll
        for (int kc = 0; kc < NK; ++kc) {
            bf16x8 a[QR];
#pragma unroll
            for (int q = 0; q < QR; ++q)
                a[q] = *(const bf16x8*)(lds + ((row0 + q) * 18 + col) * STRIDE + kc * 32 + kq * 8);
            bf16x8 b0 = *(const bf16x8*)(bbase + (kc * 4 + 0) * 512 + lane * 8);
            bf16x8 b1 = *(const bf16x8*)(bbase + (kc * 4 + 1) * 512 + lane * 8);
            bf16x8 b2 = *(const bf16x8*)(bbase + (kc * 4 + 2) * 512 + lane * 8);
            bf16x8 b3 = *(const bf16x8*)(bbase + (kc * 4 + 3) * 512 + lane * 8);
#pragma unroll
            for (int q = 0; q < QR; ++q) {
                acc[q][0] = __builtin_amdgcn_mfma_f32_16x16x32_bf16(a[q], b0, acc[q][0], 0, 0, 0);
                acc[q][1] = __builtin_amdgcn_mfma_f32_16x16x32_bf16(a[q], b1, acc[q][1], 0, 0, 0);
                acc[q][2] = __builtin_amdgcn_mfma_f32_16x16x32_bf16(a[q], b2, acc[q][2], 0, 0, 0);
                acc[q][3] = __builtin_amdgcn_mfma_f32_16x16x32_bf16(a[q], b3, acc[q][3], 0, 0, 0);
            }
        }
    }
    // Epilogue: lane n holds channels oct*64 + 4n + j -> one contiguous ushort4 per (qyl,reg).
    int n = m;
    const float4 bv = *(const float4*)(bias + oct * 64 + 4 * n);
    float s0 = 0, s1 = 0, s2 = 0, s3 = 0, q0 = 0, q1 = 0, q2 = 0, q3 = 0;
#pragma unroll
    for (int qyl = 0; qyl < QR; ++qyl) {
        int oy = 2 * (qy0 + qyl) + dy;
#pragma unroll
        for (int reg = 0; reg < 4; ++reg) {
            int mm = kq * 4 + reg;
            int ox = 2 * (x0 + mm) + dx;
            size_t base = ((size_t)((b * 2 * Q + oy) * (2 * Q) + ox)) * OC + oct * 64 + 4 * n;
            float v0 = acc[qyl][0][reg] + bv.x;
            float v1 = acc[qyl][1][reg] + bv.y;
            float v2 = acc[qyl][2][reg] + bv.z;
            float v3 = acc[qyl][3][reg] + bv.w;
            if (ST) {
                s0 += v0; q0 += v0 * v0; s1 += v1; q1 += v1 * v1;
                s2 += v2; q2 += v2 * v2; s3 += v3; q3 += v3 * v3;
            }
            ushort4 tv;
            tv.x = f2bf(v0); tv.y = f2bf(v1); tv.z = f2bf(v2); tv.w = f2bf(v3);
            *(ushort4*)(out_t + base) = tv;
        }
    }
    if (ST) {
        atomicAdd(&sstat[4 * n + 0], s0); atomicAdd(&qstat[4 * n + 0], q0);
        atomicAdd(&sstat[4 * n + 1], s1); atomicAdd(&qstat[4 * n + 1], q1);
        atomicAdd(&sstat[4 * n + 2], s2); atomicAdd(&qstat[4 * n + 2], q2);
        atomicAdd(&sstat[4 * n + 3], s3); atomicAdd(&qstat[4 * n + 3], q3);
        __syncthreads();
        if (threadIdx.x < 64) {
            atomicAdd(&gsum[slot + statoff + oct * 64 + threadIdx.x], sstat[threadIdx.x]);
            atomicAdd(&gsq[slot + statoff + oct * 64 + threadIdx.x], qstat[threadIdx.x]);
        }
    }
}

// ---------------- deconv2 (MFMA, fused G1 BN+relu on load, OC=3 pad 16) + tanh -> fp32 NCHW ----------------
__global__ void deconv2_mfma_kernel(const unsigned short* __restrict__ yt,
                                    const unsigned short* __restrict__ wp,
                                    const float* __restrict__ bias,
                                    const float* __restrict__ sc, const float* __restrict__ sh,
                                    float* __restrict__ outp) {
    constexpr int Q = 64, ICP = 128, NK = 4, STRIDE = 136;
    __shared__ unsigned short lds[4 * 18 * STRIDE];   // 19.6 KB
    int bid = blockIdx.x;
    int xt = bid & 3;
    int t2 = bid >> 2;
    int qp = t2 & 31;
    int b = t2 >> 5;
    int qy0 = qp * 2, x0 = xt * 16;

    for (int i = threadIdx.x; i < 4 * 18 * 16; i += 256) {
        int icc = i & 15;
        int rc = i >> 4;
        int row = rc / 18, col = rc % 18;
        int y = qy0 - 1 + row, x = x0 - 1 + col;
        uint4 v = {0u, 0u, 0u, 0u};
        if (((unsigned)y < (unsigned)Q) & ((unsigned)x < (unsigned)Q)) {
            v = *(const uint4*)(yt + (size_t)((b * Q + y) * Q + x) * ICP + icc * 8);
            v = bn_fuse8(v, sc, sh, icc * 8, 0.f);
        }
        *(uint4*)(lds + rc * STRIDE + icc * 8) = v;
    }
    __syncthreads();

    int wv = threadIdx.x >> 6, lane = threadIdx.x & 63;
    int dy = wv >> 1, dx = wv & 1;
    int m = lane & 15, kq = lane >> 4;
    f32x4 acc0 = {0.f, 0.f, 0.f, 0.f}, acc1 = acc0;

#pragma unroll
    for (int t = 0; t < 4; ++t) {
        int rr = t >> 1, cc = t & 1;
        int ktap = ((3 - dy) - 2 * rr) * 4 + ((3 - dx) - 2 * cc);
        int col = m + dx + cc;
        int row0 = dy + rr;
        const unsigned short* bb = wp + (size_t)(ktap * NK) * 512;
#pragma unroll
        for (int kc = 0; kc < NK; ++kc) {
            bf16x8 a0 = *(const bf16x8*)(lds + (row0 * 18 + col) * STRIDE + kc * 32 + kq * 8);
            bf16x8 a1 = *(const bf16x8*)(lds + ((row0 + 1) * 18 + col) * STRIDE + kc * 32 + kq * 8);
            bf16x8 b0 = *(const bf16x8*)(bb + kc * 512 + lane * 8);
            acc0 = __builtin_amdgcn_mfma_f32_16x16x32_bf16(a0, b0, acc0, 0, 0, 0);
            acc1 = __builtin_amdgcn_mfma_f32_16x16x32_bf16(a1, b0, acc1, 0, 0, 0);
        }
    }
    int n = m;
    if (n < 3) {
        float bv = bias[n];
#pragma unroll
        for (int reg = 0; reg < 4; ++reg) {
            int mm = kq * 4 + reg;
            int ox = 2 * (x0 + mm) + dx;
            int oy0_ = 2 * qy0 + dy;
            size_t ob = (size_t)(b * 3 + n) * 16384;
            outp[ob + (size_t)oy0_ * 128 + ox]       = tanhf(acc0[reg] + bv);
            outp[ob + (size_t)(oy0_ + 2) * 128 + ox] = tanhf(acc1[reg] + bv);
        }
    }
}

// ---------------- channel-last BN stat reduction (only used for conv0 output; writes replica 0) ----------------
template <int C>
__global__ void stat_reduce_t(const unsigned short* __restrict__ x, int total4,
                              float* __restrict__ ssum, float* __restrict__ ssq, int statoff) {
    __shared__ float ls[C], lq[C];
    for (int c = threadIdx.x; c < C; c += 256) { ls[c] = 0.f; lq[c] = 0.f; }
    __syncthreads();
    int i0 = blockIdx.x * 256 + threadIdx.x;
    int stride = gridDim.x * 256;
    int c0 = (i0 << 2) & (C - 1);
    float s0 = 0, s1 = 0, s2 = 0, s3 = 0, q0 = 0, q1 = 0, q2 = 0, q3 = 0;
    for (int i = i0; i < total4; i += stride) {
        ushort4 v = *(const ushort4*)(x + ((size_t)i << 2));
        float f0 = bf2f_raw(v.x), f1 = bf2f_raw(v.y), f2 = bf2f_raw(v.z), f3 = bf2f_raw(v.w);
        s0 += f0; s1 += f1; s2 += f2; s3 += f3;
        q0 += f0 * f0; q1 += f1 * f1; q2 += f2 * f2; q3 += f3 * f3;
    }
    atomicAdd(&ls[c0], s0); atomicAdd(&ls[c0 + 1], s1); atomicAdd(&ls[c0 + 2], s2); atomicAdd(&ls[c0 + 3], s3);
    atomicAdd(&lq[c0], q0); atomicAdd(&lq[c0 + 1], q1); atomicAdd(&lq[c0 + 2], q2); atomicAdd(&lq[c0 + 3], q3);
    __syncthreads();
    int slot = (blockIdx.x & (NREP - 1)) * 576;
    for (int c = threadIdx.x; c < C; c += 256) {
        atomicAdd(&ssum[slot + statoff + c], ls[c]);
        atomicAdd(&ssq[slot + statoff + c], lq[c]);
    }
}

// ---------------- BN finalize (sums NREP replicas) ----------------
__global__ void bn_fin_kernel(const float* __restrict__ ssum, const float* __restrict__ ssq,
                              const float* __restrict__ g, const float* __restrict__ be,
                              float* __restrict__ scale, float* __restrict__ shift,
                              int statoff, int C, float invN) {
    int c = threadIdx.x;
    if (c >= C) return;
    float s = 0.f, q = 0.f;
#pragma unroll
    for (int r = 0; r < NREP; ++r) {
        s += ssum[r * 576 + statoff + c];
        q += ssq[r * 576 + statoff + c];
    }
    float m = s * invN;
    float v = q * invN - m * m;
    v = fmaxf(v, 0.f);
    float sc = g[c] * rsqrtf(v + 1e-5f);
    scale[statoff + c] = sc;
    shift[statoff + c] = be[c] - m * sc;
}

extern "C" void kernel_launch(void* const* d_in, const int* in_sizes, int n_in,
                              void* d_out, int out_size, void* d_ws, size_t ws_size,
                              hipStream_t stream) {
    if (ws_size < WS_NEED_BYTES) {
        hipMemsetAsync(d_out, 0, (size_t)out_size * 4, stream);
        return;
    }

    float* W = (float*)d_ws;
    unsigned short* U = (unsigned short*)d_ws;
    int* FLG = (int*)(W + OFF_FLAG);

    detect_kernel<<<1, 256, 0, stream>>>((const unsigned short*)d_in[2], FLG);

    CvtJobs J;
    const int srcIdx[16] = {10, 28, 11, 12, 13, 15, 16, 17, 19, 21, 22, 23, 25, 26, 27, 29};
    const int cnt[16]    = {3072, 6144, 64, 64, 64, 128, 128, 128, 64, 256, 256, 256, 128, 128, 128, 3};
    float* dsts[16] = {W + OFF_WC0, W + OFF_WG2,
                       W + OFF_CB0, W + OFF_CG0, W + OFF_CBE0, W + OFF_CB1, W + OFF_CG1, W + OFF_CBE1,
                       W + OFF_CB2, W + OFF_GB0, W + OFF_GG0, W + OFF_GBE0, W + OFF_GB1, W + OFF_GG1,
                       W + OFF_GBE1, W + OFF_GB2};
    int off = 0;
    for (int k = 0; k < 16; ++k) {
        J.src[k] = d_in[srcIdx[k]];
        J.dst[k] = dsts[k];
        J.off[k] = off;
        off += cnt[k];
    }
    J.off[16] = off;
    cvt_all_kernel<<<(off + 255) / 256, 256, 0, stream>>>(J, off, FLG);

    zero_kernel<<<36, 256, 0, stream>>>(W + OFF_SSUM, 2 * NREP * 576);

    // weight packs
    pack_w2_kernel<<<3072, 256, 0, stream>>>(d_in[20], U + UW0, 168, 192, 256, FLG);
    pack_w2_kernel<<<2048, 256, 0, stream>>>(d_in[24], U + UW1, 256, 256, 128, FLG);
    pack_wc_kernel<<<512, 256, 0, stream>>>(d_in[14], U + UWC1, 64, 128, FLG);
    pack_wc_kernel<<<512, 256, 0, stream>>>(d_in[18], U + UWC2, 128, 64, FLG);
    pack_w2s_kernel<<<128, 256, 0, stream>>>(d_in[28], U + UW2, 128, 3, FLG);

    mlp_kernel<<<64, 64, 0, stream>>>(d_in[1], d_in[4], d_in[5], d_in[6], d_in[7],
                                      d_in[8], d_in[9], W + OFF_K12, FLG);

    // ---- conv0 -> X_s2d (raw) ----
    conv0_s2d_kernel<<<dim3(16, 1, 64), 256, 0, stream>>>(d_in[2], W + OFF_WC0, W + OFF_CB0,
                                                          U + UXT, FLG);
    stat_reduce_t<64><<<1024, 256, 0, stream>>>(U + UXT, 4194304, W + OFF_SSUM, W + OFF_SSQ, 0);
    bn_fin_kernel<<<1, 256, 0, stream>>>(W + OFF_SSUM, W + OFF_SSQ, W + OFF_CG0, W + OFF_CBE0,
                                         W + OFF_SCALE, W + OFF_SHIFT, 0, 64, 1.f / 262144.f);

    // ---- conv1 (MFMA, fused L0 BN, fused L1 stats w/ replicas) -> Y_s2d ----
    conv1_mfma_kernel<<<2048, 256, 0, stream>>>(U + UXT, U + UWC1, W + OFF_CB1,
                                                W + OFF_SCALE + 0, W + OFF_SHIFT + 0,
                                                W + OFF_SSUM, W + OFF_SSQ, U + UYT);
    bn_fin_kernel<<<1, 256, 0, stream>>>(W + OFF_SSUM, W + OFF_SSQ, W + OFF_CG1, W + OFF_CBE1,
                                         W + OFF_SCALE, W + OFF_SHIFT, 64, 128, 1.f / 65536.f);

    // ---- conv2 (MFMA, fused L1 BN) + tanh -> Z_t[0:64) ----
    conv2_mfma_kernel<<<512, 256, 0, stream>>>(U + UYT, U + UWC2, W + OFF_CB2,
                                               W + OFF_SCALE + 64, W + OFF_SHIFT + 64, U + UZT);

    // ---- Z_t[64:192) incl. pad zeroing ----
    assemble_z<<<8192, 256, 0, stream>>>(d_in[0], d_in[1], d_in[3], W + OFF_K12, U + UZT, FLG);

    // ---- gen deconv0 (MFMA, fused G0 stats w/ replicas): Z_t -> X_t(32,32,256) ----
    deconv_mfma2_kernel<192, 16, 256, 2, false, true><<<2048, 256, 0, stream>>>(
        U + UZT, U + UW0, W + OFF_GB0, nullptr, nullptr,
        W + OFF_SSUM, W + OFF_SSQ, 192, U + UXT);
    bn_fin_kernel<<<1, 256, 0, stream>>>(W + OFF_SSUM, W + OFF_SSQ, W + OFF_GG0, W + OFF_GBE0,
                                         W + OFF_SCALE, W + OFF_SHIFT, 192, 256, 1.f / 65536.f);

    // ---- gen deconv1 (MFMA, fused G0 BN, fused G1 stats w/ replicas): X_t -> Y_t(64,64,128) ----
    deconv_mfma2_kernel<256, 32, 128, 2, true, true><<<4096, 256, 0, stream>>>(
        U + UXT, U + UW1, W + OFF_GB1, W + OFF_SCALE + 192, W + OFF_SHIFT + 192,
        W + OFF_SSUM, W + OFF_SSQ, 448, U + UYT);
    bn_fin_kernel<<<1, 256, 0, stream>>>(W + OFF_SSUM, W + OFF_SSQ, W + OFF_GG1, W + OFF_GBE1,
                                         W + OFF_SCALE, W + OFF_SHIFT, 448, 128, 1.f / 262144.f);

    // ---- gen deconv2 (MFMA, fused G1 BN) + tanh -> d_out fp32 ----
    deconv2_mfma_kernel<<<8192, 256, 0, stream>>>(U + UYT, U + UW2, W + OFF_GB2,
                                                  W + OFF_SCALE + 448, W + OFF_SHIFT + 448,
                                                  (float*)d_out);
}

// Round 9
// 608.628 us; speedup vs baseline: 1.1640x; 1.0319x over previous
//
#include <hip/hip_runtime.h>
#include <hip/hip_bf16.h>

#define TWO_PI_F 6.2831853071795864769f

typedef __attribute__((ext_vector_type(8))) __bf16 bf16x8;
typedef __attribute__((ext_vector_type(4))) float f32x4;

// 32-way replicated stat buffers: per-address global atomic chains drop 32x.
#define NREP 32

__device__ __forceinline__ float bf2f_raw(unsigned short u) {
    return __uint_as_float(((unsigned int)u) << 16);
}
__device__ __forceinline__ unsigned short f2bf(float f) {
    unsigned int u = __float_as_uint(f);
    unsigned int r = (u + 0x7FFFu + ((u >> 16) & 1u)) >> 16;   // RNE
    return (unsigned short)r;
}
__device__ __forceinline__ float loadIn(const void* p, size_t i, bool f32) {
    return f32 ? ((const float*)p)[i] : bf2f_raw(((const unsigned short*)p)[i]);
}

// Fused BN affine + (leaky)relu applied to 8 packed bf16 during staging.
__device__ __forceinline__ uint4 bn_fuse8(uint4 v, const float* __restrict__ sc,
                                          const float* __restrict__ sh, int c0, float slope) {
    unsigned short us[8];
    *(uint4*)us = v;
#pragma unroll
    for (int k = 0; k < 8; ++k) {
        float f = bf2f_raw(us[k]) * sc[c0 + k] + sh[c0 + k];
        f = f > 0.f ? f : slope * f;
        us[k] = f2bf(f);
    }
    return *(const uint4*)us;
}

// Reduce val across the 4 kq-groups of a wave (lanes differing in bits 4,5).
__device__ __forceinline__ float kq_reduce(float v) {
    v += __shfl_xor(v, 16, 64);
    v += __shfl_xor(v, 32, 64);
    return v;
}

// ---------------- ws layout ----------------
static constexpr size_t OFF_WC0 = 0;          // cod_w0 fp32 3072
static constexpr size_t OFF_WG2 = 3072;       // gen_w2 fp32 6144 (legacy, unused)
static constexpr size_t OFF_P   = 9216;
static constexpr size_t OFF_CB0 = OFF_P + 0;
static constexpr size_t OFF_CG0 = OFF_P + 64;
static constexpr size_t OFF_CBE0= OFF_P + 128;
static constexpr size_t OFF_CB1 = OFF_P + 192;
static constexpr size_t OFF_CG1 = OFF_P + 320;
static constexpr size_t OFF_CBE1= OFF_P + 448;
static constexpr size_t OFF_CB2 = OFF_P + 576;
static constexpr size_t OFF_GB0 = OFF_P + 640;
static constexpr size_t OFF_GG0 = OFF_P + 896;
static constexpr size_t OFF_GBE0= OFF_P + 1152;
static constexpr size_t OFF_GB1 = OFF_P + 1408;
static constexpr size_t OFF_GG1 = OFF_P + 1536;
static constexpr size_t OFF_GBE1= OFF_P + 1664;
static constexpr size_t OFF_GB2 = OFF_P + 1792;
static constexpr size_t OFF_SSUM  = OFF_P + 2048;              // NREP x 576
static constexpr size_t OFF_SSQ   = OFF_SSUM + NREP * 576;     // NREP x 576
static constexpr size_t OFF_SCALE = OFF_SSQ + NREP * 576;
static constexpr size_t OFF_SHIFT = OFF_SCALE + 576;
static constexpr size_t OFF_K12   = OFF_SHIFT + 576;
static constexpr size_t OFF_FLAG  = OFF_K12 + 1024;
static constexpr size_t FP32_END  = OFF_FLAG + 16;   // floats
// ushort regions:
static constexpr size_t UXT = 2 * FP32_END;            // X region: X_s2d (b,2,2,32,32,64) then X_t (b,32,32,256)
static constexpr size_t UYT = UXT + 16777216;          // Y region: Y_s2d head, then Y_t (b,64,64,128)
static constexpr size_t UZT = UYT + 8388608;           // Z_t (b,16,16,192)
static constexpr size_t UW0 = UYT + 33554432;          // deconv0 pack
static constexpr size_t UW1 = UW0 + 786432;            // deconv1 pack
static constexpr size_t UWC1 = UW1 + 524288;           // conv1 pack
static constexpr size_t UWC2 = UWC1 + 131072;          // conv2 pack
static constexpr size_t UW2 = UWC2 + 131072;           // deconv2 pack
static constexpr size_t WS_END_USHORT = UW2 + 32768;
static constexpr size_t WS_NEED_BYTES = WS_END_USHORT * 2;   // ~110 MB

// stat slots: L0:0(64) L1:64(128) G0:192(256) G1:448(128)

// ---------------- input dtype detection ----------------
__global__ void detect_kernel(const unsigned short* __restrict__ imgs, int* __restrict__ flag) {
    int t = threadIdx.x;  // 256
    unsigned short u = imgs[t];
    int e = (u >> 7) & 0xFF;
    unsigned long long b = __ballot(e >= 0xC0);
    __shared__ int cnt[4];
    if ((t & 63) == 0) cnt[t >> 6] = __popcll(b);
    __syncthreads();
    if (t == 0) flag[0] = (cnt[0] + cnt[1] + cnt[2] + cnt[3] >= 4) ? 1 : 0;
}

// ---------------- small param -> fp32 conversion ----------------
struct CvtJobs {
    const void* src[16];
    float* dst[16];
    int off[17];
};

__global__ void cvt_all_kernel(CvtJobs J, int total, const int* __restrict__ flg) {
    int i = blockIdx.x * 256 + threadIdx.x;
    if (i >= total) return;
    bool f32 = flg[0] != 0;
    int k = 0;
#pragma unroll
    for (int t = 0; t < 15; ++t) { if (i >= J.off[t + 1]) k = t + 1; }
    int r = i - J.off[k];
    J.dst[k][r] = loadIn(J.src[k], r, f32);
}

__global__ void zero_kernel(float* p, int n) {
    int i = blockIdx.x * 256 + threadIdx.x;
    if (i < n) p[i] = 0.f;
}

// ---------------- deconv weight packing ----------------
__global__ void pack_w2_kernel(const void* __restrict__ src, unsigned short* __restrict__ dst,
                               int ICreal, int ICP, int OC, const int* __restrict__ flg) {
    bool f32 = flg[0] != 0;
    int i = blockIdx.x * 256 + threadIdx.x;
    int total = 16 * OC * ICP;
    if (i >= total) return;
    int jj = i & 7;
    int lane = (i >> 3) & 63;
    int j = (i >> 9) & 3;
    int t3 = i >> 11;
    int NK = ICP / 32;
    int kc = t3 % NK;
    int t4 = t3 / NK;
    int NOCT = OC / 64;
    int oct = t4 % NOCT;
    int ktap = t4 / NOCT;
    int kq = lane >> 4, n = lane & 15;
    int ic = kc * 32 + kq * 8 + jj;
    int oc = oct * 64 + n * 4 + j;          // channel-interleaved
    unsigned short v = 0;
    if (ic < ICreal) v = f2bf(loadIn(src, ((size_t)(ic * OC + oc) << 4) + ktap, f32));
    dst[i] = v;
}

__global__ void pack_w2s_kernel(const void* __restrict__ src, unsigned short* __restrict__ dst,
                                int ICP, int OCreal, const int* __restrict__ flg) {
    bool f32 = flg[0] != 0;
    int i = blockIdx.x * 256 + threadIdx.x;
    int NK = ICP / 32;
    int total = 16 * NK * 512;
    if (i >= total) return;
    int jj = i & 7;
    int lane = (i >> 3) & 63;
    int t3 = i >> 9;
    int kc = t3 % NK;
    int ktap = t3 / NK;
    int kq = lane >> 4, n = lane & 15;
    int ic = kc * 32 + kq * 8 + jj;
    unsigned short v = 0;
    if (n < OCreal) v = f2bf(loadIn(src, ((size_t)(ic * OCreal + n) << 4) + ktap, f32));
    dst[i] = v;
}

__global__ void pack_wc_kernel(const void* __restrict__ src, unsigned short* __restrict__ dst,
                               int IC, int OC, const int* __restrict__ flg) {
    bool f32 = flg[0] != 0;
    int i = blockIdx.x * 256 + threadIdx.x;
    int total = 16 * OC * IC;
    if (i >= total) return;
    int jj = i & 7;
    int lane = (i >> 3) & 63;
    int j = (i >> 9) & 3;
    int t3 = i >> 11;
    int NK = IC / 32;
    int kc = t3 % NK;
    int t4 = t3 / NK;
    int NOCT = OC / 64;
    int oct = t4 % NOCT;
    int ktap = t4 / NOCT;
    int kq = lane >> 4, n = lane & 15;
    int ic = kc * 32 + kq * 8 + jj;
    int oc = oct * 64 + j * 16 + n;
    dst[i] = f2bf(loadIn(src, ((size_t)(oc * IC + ic) << 4) + ktap, f32));
}

// ---------------- tiny MLP ----------------
__global__ void mlp_kernel(const void* __restrict__ Zg,
                           const void* __restrict__ lW, const void* __restrict__ lb,
                           const void* __restrict__ l1W, const void* __restrict__ l1b,
                           const void* __restrict__ l2W, const void* __restrict__ l2b,
                           float* __restrict__ K12, const int* __restrict__ flg) {
    bool f32 = flg[0] != 0;
    int b = blockIdx.x;
    int t = threadIdx.x;  // 64
    __shared__ float xs[64];
    float acc = loadIn(lb, t, f32);
    for (int c = 0; c < 64; ++c)
        acc += loadIn(Zg, (size_t)(b * 64 + c) * 256, f32) * loadIn(lW, t * 64 + c, f32);
    xs[t] = fmaxf(acc, 0.f);
    __syncthreads();
    if (t < 16) {
        int p = t & 7;
        const void* Wp = (t < 8) ? l1W : l2W;
        const void* bp = (t < 8) ? l1b : l2b;
        float a = loadIn(bp, p, f32);
        for (int h = 0; h < 64; ++h) a += xs[h] * loadIn(Wp, p * 64 + h, f32);
        K12[b * 16 + t] = a;
    }
}

// ---------------- conv0: imgs -> X_s2d ----------------
__global__ void conv0_s2d_kernel(const void* __restrict__ imgs, const float* __restrict__ w,
                                 const float* __restrict__ bias, unsigned short* __restrict__ xs,
                                 const int* __restrict__ flg) {
    bool f32 = flg[0] != 0;
    int b = blockIdx.z;
    int tile = blockIdx.x;
    int Y0 = (tile >> 2) * 16, X0 = (tile & 3) * 16;
    __shared__ float vin[3 * 34 * 35];
    __shared__ float wl[64 * 49];
    for (int i = threadIdx.x; i < 3 * 34 * 34; i += 256) {
        int c = i % 34; int t = i / 34; int r = t % 34; int ic = t / 34;
        int iy = 2 * Y0 - 1 + r, ix = 2 * X0 - 1 + c;
        float v = 0.f;
        if (((unsigned)iy < 128u) & ((unsigned)ix < 128u))
            v = loadIn(imgs, ((size_t)(b * 3 + ic) * 128 + iy) * 128 + ix, f32);
        vin[(ic * 34 + r) * 35 + c] = v;
    }
    for (int i = threadIdx.x; i < 3072; i += 256) {
        int oc = i / 48, idx = i % 48;
        wl[oc * 49 + idx] = w[i];
    }
    __syncthreads();
    int q = threadIdx.x >> 2;
    int ocq = threadIdx.x & 3;
    int qy = q >> 3, qx = q & 7;
    float acc[4][16];
#pragma unroll
    for (int p = 0; p < 4; ++p)
#pragma unroll
        for (int o = 0; o < 16; ++o) acc[p][o] = 0.f;
    for (int ic = 0; ic < 3; ++ic) {
        float v[6][6];
#pragma unroll
        for (int r = 0; r < 6; ++r)
#pragma unroll
            for (int c = 0; c < 6; ++c)
                v[r][c] = vin[(ic * 34 + 4 * qy + r) * 35 + 4 * qx + c];
#pragma unroll
        for (int o = 0; o < 16; ++o) {
            const float* wo = wl + (ocq * 16 + o) * 49 + ic * 16;
#pragma unroll
            for (int ky = 0; ky < 4; ++ky)
#pragma unroll
                for (int kx = 0; kx < 4; ++kx) {
                    float wv = wo[ky * 4 + kx];
                    acc[0][o] = fmaf(v[ky][kx], wv, acc[0][o]);
                    acc[1][o] = fmaf(v[ky][kx + 2], wv, acc[1][o]);
                    acc[2][o] = fmaf(v[ky + 2][kx], wv, acc[2][o]);
                    acc[3][o] = fmaf(v[ky + 2][kx + 2], wv, acc[3][o]);
                }
        }
    }
    int j = (Y0 >> 1) + qy, i2 = (X0 >> 1) + qx;
#pragma unroll
    for (int p = 0; p < 4; ++p) {
        int dy = p >> 1, dx = p & 1;
        unsigned short tmp[16];
#pragma unroll
        for (int o = 0; o < 16; ++o) tmp[o] = f2bf(acc[p][o] + bias[ocq * 16 + o]);
        unsigned short* dst = xs + (((size_t)((b * 2 + dy) * 2 + dx) * 32 + j) * 32 + i2) * 64 + ocq * 16;
        *(uint4*)(dst) = *(const uint4*)(tmp);
        *(uint4*)(dst + 8) = *(const uint4*)(tmp + 8);
    }
}

// ---------------- conv1 (MFMA, fused L0 BN on load, fused L1 stats, atomic-free in-block reduce) ----------------
__global__ void conv1_mfma_kernel(const unsigned short* __restrict__ xs,
                                  const unsigned short* __restrict__ wp,
                                  const float* __restrict__ bias,
                                  const float* __restrict__ sc, const float* __restrict__ sh,
                                  float* __restrict__ gsum, float* __restrict__ gsq,
                                  unsigned short* __restrict__ ys) {
    constexpr int STR = 72;
    __shared__ unsigned short lds[4 * 3 * 17 * STR];   // 29.4 KB
    __shared__ float ws[4][64], wq[4][64];
    int bid = blockIdx.x;
    int slot = (bid & (NREP - 1)) * 576;
    int xt = bid & 1;
    int qp = (bid >> 1) & 15;
    int b = bid >> 5;
    int oy0 = qp * 2, x0 = xt * 16;
    for (int i = threadIdx.x; i < 1632; i += 256) {
        int icc = i & 7; int t = i >> 3;
        int col = t % 17; int rc = t / 17;
        int row = rc % 3; int pl = rc / 3;
        int py = pl >> 1, px = pl & 1;
        int j = oy0 - py + row;
        int ci = x0 - px + col;
        uint4 v = {0u, 0u, 0u, 0u};
        if (((unsigned)j < 32u) & ((unsigned)ci < 32u)) {
            v = *(const uint4*)(xs + ((size_t)((b * 4 + pl) * 32 + j) * 32 + ci) * 64 + icc * 8);
            v = bn_fuse8(v, sc, sh, icc * 8, 0.2f);
        }
        *(uint4*)(lds + ((pl * 3 + row) * 17 + col) * STR + icc * 8) = v;
    }
    __syncthreads();

    int wv = threadIdx.x >> 6, lane = threadIdx.x & 63;
    int r = wv >> 1, oct = wv & 1;
    int m = lane & 15, kq = lane >> 4;
    f32x4 acc[4];
#pragma unroll
    for (int j = 0; j < 4; ++j) acc[j] = (f32x4){0.f, 0.f, 0.f, 0.f};

#pragma unroll
    for (int ky = 0; ky < 4; ++ky) {
        int py = (ky & 1) ^ 1;
        int lrow = r + (ky >> 1);
#pragma unroll
        for (int kx = 0; kx < 4; ++kx) {
            int px = (kx & 1) ^ 1;
            int pl = py * 2 + px;
            int lcol = m + (kx >> 1);
            const unsigned short* lp = lds + ((pl * 3 + lrow) * 17 + lcol) * STR + kq * 8;
            int ktap = ky * 4 + kx;
            const unsigned short* bb = wp + (size_t)(ktap * 2 + oct) * 4096;
#pragma unroll
            for (int kc = 0; kc < 2; ++kc) {
                bf16x8 a = *(const bf16x8*)(lp + kc * 32);
                const unsigned short* bk = bb + kc * 2048 + lane * 8;
                bf16x8 b0 = *(const bf16x8*)(bk);
                bf16x8 b1 = *(const bf16x8*)(bk + 512);
                bf16x8 b2 = *(const bf16x8*)(bk + 1024);
                bf16x8 b3 = *(const bf16x8*)(bk + 1536);
                acc[0] = __builtin_amdgcn_mfma_f32_16x16x32_bf16(a, b0, acc[0], 0, 0, 0);
                acc[1] = __builtin_amdgcn_mfma_f32_16x16x32_bf16(a, b1, acc[1], 0, 0, 0);
                acc[2] = __builtin_amdgcn_mfma_f32_16x16x32_bf16(a, b2, acc[2], 0, 0, 0);
                acc[3] = __builtin_amdgcn_mfma_f32_16x16x32_bf16(a, b3, acc[3], 0, 0, 0);
            }
        }
    }
    int oy = oy0 + r;
    int pyo = oy & 1, jo = oy >> 1;
    int n = m;
    float bv0 = bias[oct * 64 + n], bv1 = bias[oct * 64 + 16 + n];
    float bv2 = bias[oct * 64 + 32 + n], bv3 = bias[oct * 64 + 48 + n];
    float s0 = 0, s1 = 0, s2 = 0, s3 = 0, q0 = 0, q1 = 0, q2 = 0, q3 = 0;
#pragma unroll
    for (int reg = 0; reg < 4; ++reg) {
        int mm = kq * 4 + reg;
        int ox = x0 + mm;
        int pxo = ox & 1, io = ox >> 1;
        size_t base = (((size_t)((b * 2 + pyo) * 2 + pxo) * 16 + jo) * 16 + io) * 128 + oct * 64 + n;
        float v0 = acc[0][reg] + bv0, v1 = acc[1][reg] + bv1;
        float v2 = acc[2][reg] + bv2, v3 = acc[3][reg] + bv3;
        s0 += v0; q0 += v0 * v0; s1 += v1; q1 += v1 * v1;
        s2 += v2; q2 += v2 * v2; s3 += v3; q3 += v3 * v3;
        ys[base]      = f2bf(v0);
        ys[base + 16] = f2bf(v1);
        ys[base + 32] = f2bf(v2);
        ys[base + 48] = f2bf(v3);
    }
    // wave-level kq reduction (no atomics)
    s0 = kq_reduce(s0); q0 = kq_reduce(q0);
    s1 = kq_reduce(s1); q1 = kq_reduce(q1);
    s2 = kq_reduce(s2); q2 = kq_reduce(q2);
    s3 = kq_reduce(s3); q3 = kq_reduce(q3);
    if (lane < 16) {
        ws[wv][0 * 16 + n] = s0; wq[wv][0 * 16 + n] = q0;
        ws[wv][1 * 16 + n] = s1; wq[wv][1 * 16 + n] = q1;
        ws[wv][2 * 16 + n] = s2; wq[wv][2 * 16 + n] = q2;
        ws[wv][3 * 16 + n] = s3; wq[wv][3 * 16 + n] = q3;
    }
    __syncthreads();
    if (threadIdx.x < 128) {
        int c = threadIdx.x;
        int o = c >> 6, rr = c & 63;          // waves {o, o+2} cover oct o
        float s = ws[o][rr] + ws[o + 2][rr];
        float q = wq[o][rr] + wq[o + 2][rr];
        atomicAdd(&gsum[slot + 64 + c], s);
        atomicAdd(&gsq[slot + 64 + c], q);
    }
}

// ---------------- conv2 (MFMA, fused L1 BN on load) + tanh: Y_s2d -> Z_t[0:64) ----------------
__global__ void conv2_mfma_kernel(const unsigned short* __restrict__ ys,
                                  const unsigned short* __restrict__ wp,
                                  const float* __restrict__ bias,
                                  const float* __restrict__ sc, const float* __restrict__ sh,
                                  unsigned short* __restrict__ zt) {
    constexpr int STR = 136;
    __shared__ unsigned short lds[4 * 3 * 17 * STR];   // 55.5 KB
    int bid = blockIdx.x;
    int qp = bid & 7;
    int b = bid >> 3;
    int oy0 = qp * 2;
    for (int i = threadIdx.x; i < 3264; i += 256) {
        int icc = i & 15; int t = i >> 4;
        int col = t % 17; int rc = t / 17;
        int row = rc % 3; int pl = rc / 3;
        int py = pl >> 1, px = pl & 1;
        int j = oy0 - py + row;
        int ci = col - px;
        uint4 v = {0u, 0u, 0u, 0u};
        if (((unsigned)j < 16u) & ((unsigned)ci < 16u)) {
            v = *(const uint4*)(ys + ((size_t)((b * 4 + pl) * 16 + j) * 16 + ci) * 128 + icc * 8);
            v = bn_fuse8(v, sc, sh, icc * 8, 0.2f);
        }
        *(uint4*)(lds + ((pl * 3 + row) * 17 + col) * STR + icc * 8) = v;
    }
    __syncthreads();

    int wv = threadIdx.x >> 6, lane = threadIdx.x & 63;
    int r = wv >> 1, jh = wv & 1;
    int m = lane & 15, kq = lane >> 4;
    f32x4 acc[2];
    acc[0] = (f32x4){0.f, 0.f, 0.f, 0.f};
    acc[1] = acc[0];
#pragma unroll
    for (int ky = 0; ky < 4; ++ky) {
        int py = (ky & 1) ^ 1;
        int lrow = r + (ky >> 1);
#pragma unroll
        for (int kx = 0; kx < 4; ++kx) {
            int px = (kx & 1) ^ 1;
            int pl = py * 2 + px;
            int lcol = m + (kx >> 1);
            const unsigned short* lp = lds + ((pl * 3 + lrow) * 17 + lcol) * STR + kq * 8;
            int ktap = ky * 4 + kx;
            const unsigned short* bb = wp + (size_t)ktap * 8192;
#pragma unroll
            for (int kc = 0; kc < 4; ++kc) {
                bf16x8 a = *(const bf16x8*)(lp + kc * 32);
                const unsigned short* bk = bb + kc * 2048 + (jh * 2) * 512 + lane * 8;
                bf16x8 b0 = *(const bf16x8*)(bk);
                bf16x8 b1 = *(const bf16x8*)(bk + 512);
                acc[0] = __builtin_amdgcn_mfma_f32_16x16x32_bf16(a, b0, acc[0], 0, 0, 0);
                acc[1] = __builtin_amdgcn_mfma_f32_16x16x32_bf16(a, b1, acc[1], 0, 0, 0);
            }
        }
    }
    int oy = oy0 + r;
    int n = m;
    float bv0 = bias[(jh * 2) * 16 + n], bv1 = bias[(jh * 2 + 1) * 16 + n];
#pragma unroll
    for (int reg = 0; reg < 4; ++reg) {
        int x = kq * 4 + reg;
        size_t base = ((size_t)(b * 16 + oy) * 16 + x) * 192 + (jh * 2) * 16 + n;
        zt[base]      = f2bf(tanhf(acc[0][reg] + bv0));
        zt[base + 16] = f2bf(tanhf(acc[1][reg] + bv1));
    }
}

// ---------------- assemble Z_t[...][64:192): Zl, Zg, wave, and pad channels ----------------
__global__ void assemble_z(const void* __restrict__ Zl, const void* __restrict__ Zg,
                           const void* __restrict__ phi, const float* __restrict__ K12,
                           unsigned short* __restrict__ zt, const int* __restrict__ flg) {
    bool f32 = flg[0] != 0;
    int i = blockIdx.x * 256 + threadIdx.x;
    const int TOT = 64 * 128 * 256;
    if (i >= TOT) return;
    int pos = i & 255;
    int t = i >> 8;
    int c128 = t % 128;
    int b = t / 128;
    float val;
    if (c128 < 32) {
        val = loadIn(Zl, ((size_t)(b * 32 + c128) << 8) + pos, f32);
    } else if (c128 < 96) {
        val = loadIn(Zg, ((size_t)(b * 64 + (c128 - 32)) << 8) + pos, f32);
    } else if (c128 < 104) {
        int p = c128 - 96;
        int y = pos >> 4, x = pos & 15;
        float k1 = K12[b * 16 + p];
        float k2 = K12[b * 16 + 8 + p];
        val = sinf(k1 * (float)y + k2 * (float)x + loadIn(phi, b * 8 + p, f32) * TWO_PI_F);
    } else {
        val = 0.f;      // pad channels 168..192 of Z_t
    }
    zt[((size_t)(b * 256 + pos)) * 192 + 64 + c128] = f2bf(val);
}

// ---------------- MFMA transposed-conv v9: QR=2, oct slowest, fused BN-in +
// atomic-free in-block stat reduce + 32x-replicated global stats ----------------
template <int ICP, int Q, int OC, int QR, bool BN, bool ST>
__global__ __launch_bounds__(256, 2)
void deconv_mfma2_kernel(const unsigned short* __restrict__ in_t,
                         const unsigned short* __restrict__ wp2,
                         const float* __restrict__ bias,
                         const float* __restrict__ sc, const float* __restrict__ sh,
                         float* __restrict__ gsum, float* __restrict__ gsq, int statoff,
                         unsigned short* __restrict__ out_t) {
    constexpr int NOCT = OC / 64;
    constexpr int NK = ICP / 32;
    constexpr int XT = Q / 16;
    constexpr int NQB = Q / QR;
    constexpr int ROWS = QR + 2;
    constexpr int STRIDE = ICP + 8;
    constexpr int NTILES = XT * NQB * 64;
    __shared__ unsigned short lds[ROWS * 18 * STRIDE];
    __shared__ float ws[4][64], wq[4][64];

    int bid = blockIdx.x;
    int slot = (bid & (NREP - 1)) * 576;
    int oct = bid / NTILES;          // slowest dim
    bid -= oct * NTILES;
    int xt = bid % XT;
    int t2 = bid / XT;
    int qp = t2 % NQB;
    int b = t2 / NQB;
    int qy0 = qp * QR;
    int x0 = xt * 16;

    constexpr int P8 = ICP / 8;
    constexpr int E8 = ROWS * 18 * P8;
    for (int i = threadIdx.x; i < E8; i += 256) {
        int icc = i % P8;
        int rc = i / P8;
        int row = rc / 18, col = rc % 18;
        int y = qy0 - 1 + row, x = x0 - 1 + col;
        uint4 val = {0u, 0u, 0u, 0u};
        if (((unsigned)y < (unsigned)Q) & ((unsigned)x < (unsigned)Q)) {
            val = *(const uint4*)(in_t + (size_t)((b * Q + y) * Q + x) * ICP + icc * 8);
            if (BN) val = bn_fuse8(val, sc, sh, icc * 8, 0.f);
        }
        *(uint4*)(lds + rc * STRIDE + icc * 8) = val;
    }
    __syncthreads();

    int wv = threadIdx.x >> 6, lane = threadIdx.x & 63;
    int dy = wv >> 1, dx = wv & 1;
    int m = lane & 15, kq = lane >> 4;

    f32x4 acc[QR][4];
#pragma unroll
    for (int q = 0; q < QR; ++q)
#pragma unroll
        for (int j = 0; j < 4; ++j) acc[q][j] = (f32x4){0.f, 0.f, 0.f, 0.f};

#pragma unroll
    for (int t = 0; t < 4; ++t) {
        int rr = t >> 1, cc = t & 1;
        int ktap = ((3 - dy) - 2 * rr) * 4 + ((3 - dx) - 2 * cc);
        int col = m + dx + cc;
        int row0 = dy + rr;
        const unsigned short* bbase = wp2 + (size_t)((ktap * NOCT + oct) * NK) * 2048;
#pragma unroll
        for (int kc = 0; kc < NK; ++kc) {
            bf16x8 a[QR];
#pragma unroll
            for (int q = 0; q < QR; ++q)
                a[q] = *(const bf16x8*)(lds + ((row0 + q) * 18 + col) * STRIDE + kc * 32 + kq * 8);
            bf16x8 b0 = *(const bf16x8*)(bbase + (kc * 4 + 0) * 512 + lane * 8);
            bf16x8 b1 = *(const bf16x8*)(bbase + (kc * 4 + 1) * 512 + lane * 8);
            bf16x8 b2 = *(const bf16x8*)(bbase + (kc * 4 + 2) * 512 + lane * 8);
            bf16x8 b3 = *(const bf16x8*)(bbase + (kc * 4 + 3) * 512 + lane * 8);
#pragma unroll
            for (int q = 0; q < QR; ++q) {
                acc[q][0] = __builtin_amdgcn_mfma_f32_16x16x32_bf16(a[q], b0, acc[q][0], 0, 0, 0);
                acc[q][1] = __builtin_amdgcn_mfma_f32_16x16x32_bf16(a[q], b1, acc[q][1], 0, 0, 0);
                acc[q][2] = __builtin_amdgcn_mfma_f32_16x16x32_bf16(a[q], b2, acc[q][2], 0, 0, 0);
                acc[q][3] = __builtin_amdgcn_mfma_f32_16x16x32_bf16(a[q], b3, acc[q][3], 0, 0, 0);
            }
        }
    }
    // Epilogue: lane n holds channels oct*64 + 4n + j -> one contiguous ushort4 per (qyl,reg).
    int n = m;
    const float4 bv = *(const float4*)(bias + oct * 64 + 4 * n);
    float s0 = 0, s1 = 0, s2 = 0, s3 = 0, q0 = 0, q1 = 0, q2 = 0, q3 = 0;
#pragma unroll
    for (int qyl = 0; qyl < QR; ++qyl) {
        int oy = 2 * (qy0 + qyl) + dy;
#pragma unroll
        for (int reg = 0; reg < 4; ++reg) {
            int mm = kq * 4 + reg;
            int ox = 2 * (x0 + mm) + dx;
            size_t base = ((size_t)((b * 2 * Q + oy) * (2 * Q) + ox)) * OC + oct * 64 + 4 * n;
            float v0 = acc[qyl][0][reg] + bv.x;
            float v1 = acc[qyl][1][reg] + bv.y;
            float v2 = acc[qyl][2][reg] + bv.z;
            float v3 = acc[qyl][3][reg] + bv.w;
            if (ST) {
                s0 += v0; q0 += v0 * v0; s1 += v1; q1 += v1 * v1;
                s2 += v2; q2 += v2 * v2; s3 += v3; q3 += v3 * v3;
            }
            ushort4 tv;
            tv.x = f2bf(v0); tv.y = f2bf(v1); tv.z = f2bf(v2); tv.w = f2bf(v3);
            *(ushort4*)(out_t + base) = tv;
        }
    }
    if (ST) {
        // wave-level kq reduction (no LDS atomics)
        s0 = kq_reduce(s0); q0 = kq_reduce(q0);
        s1 = kq_reduce(s1); q1 = kq_reduce(q1);
        s2 = kq_reduce(s2); q2 = kq_reduce(q2);
        s3 = kq_reduce(s3); q3 = kq_reduce(q3);
        if (lane < 16) {
            ws[wv][4 * n + 0] = s0; wq[wv][4 * n + 0] = q0;
            ws[wv][4 * n + 1] = s1; wq[wv][4 * n + 1] = q1;
            ws[wv][4 * n + 2] = s2; wq[wv][4 * n + 2] = q2;
            ws[wv][4 * n + 3] = s3; wq[wv][4 * n + 3] = q3;
        }
        __syncthreads();
        if (threadIdx.x < 64) {
            int c = threadIdx.x;
            float s = ws[0][c] + ws[1][c] + ws[2][c] + ws[3][c];
            float q = wq[0][c] + wq[1][c] + wq[2][c] + wq[3][c];
            atomicAdd(&gsum[slot + statoff + oct * 64 + c], s);
            atomicAdd(&gsq[slot + statoff + oct * 64 + c], q);
        }
    }
}

// ---------------- deconv2 (MFMA, fused G1 BN+relu on load, OC=3 pad 16) + tanh -> fp32 NCHW ----------------
__global__ void deconv2_mfma_kernel(const unsigned short* __restrict__ yt,
                                    const unsigned short* __restrict__ wp,
                                    const float* __restrict__ bias,
                                    const float* __restrict__ sc, const float* __restrict__ sh,
                                    float* __restrict__ outp) {
    constexpr int Q = 64, ICP = 128, NK = 4, STRIDE = 136;
    __shared__ unsigned short lds[4 * 18 * STRIDE];   // 19.6 KB
    int bid = blockIdx.x;
    int xt = bid & 3;
    int t2 = bid >> 2;
    int qp = t2 & 31;
    int b = t2 >> 5;
    int qy0 = qp * 2, x0 = xt * 16;

    for (int i = threadIdx.x; i < 4 * 18 * 16; i += 256) {
        int icc = i & 15;
        int rc = i >> 4;
        int row = rc / 18, col = rc % 18;
        int y = qy0 - 1 + row, x = x0 - 1 + col;
        uint4 v = {0u, 0u, 0u, 0u};
        if (((unsigned)y < (unsigned)Q) & ((unsigned)x < (unsigned)Q)) {
            v = *(const uint4*)(yt + (size_t)((b * Q + y) * Q + x) * ICP + icc * 8);
            v = bn_fuse8(v, sc, sh, icc * 8, 0.f);
        }
        *(uint4*)(lds + rc * STRIDE + icc * 8) = v;
    }
    __syncthreads();

    int wv = threadIdx.x >> 6, lane = threadIdx.x & 63;
    int dy = wv >> 1, dx = wv & 1;
    int m = lane & 15, kq = lane >> 4;
    f32x4 acc0 = {0.f, 0.f, 0.f, 0.f}, acc1 = acc0;

#pragma unroll
    for (int t = 0; t < 4; ++t) {
        int rr = t >> 1, cc = t & 1;
        int ktap = ((3 - dy) - 2 * rr) * 4 + ((3 - dx) - 2 * cc);
        int col = m + dx + cc;
        int row0 = dy + rr;
        const unsigned short* bb = wp + (size_t)(ktap * NK) * 512;
#pragma unroll
        for (int kc = 0; kc < NK; ++kc) {
            bf16x8 a0 = *(const bf16x8*)(lds + (row0 * 18 + col) * STRIDE + kc * 32 + kq * 8);
            bf16x8 a1 = *(const bf16x8*)(lds + ((row0 + 1) * 18 + col) * STRIDE + kc * 32 + kq * 8);
            bf16x8 b0 = *(const bf16x8*)(bb + kc * 512 + lane * 8);
            acc0 = __builtin_amdgcn_mfma_f32_16x16x32_bf16(a0, b0, acc0, 0, 0, 0);
            acc1 = __builtin_amdgcn_mfma_f32_16x16x32_bf16(a1, b0, acc1, 0, 0, 0);
        }
    }
    int n = m;
    if (n < 3) {
        float bv = bias[n];
#pragma unroll
        for (int reg = 0; reg < 4; ++reg) {
            int mm = kq * 4 + reg;
            int ox = 2 * (x0 + mm) + dx;
            int oy0_ = 2 * qy0 + dy;
            size_t ob = (size_t)(b * 3 + n) * 16384;
            outp[ob + (size_t)oy0_ * 128 + ox]       = tanhf(acc0[reg] + bv);
            outp[ob + (size_t)(oy0_ + 2) * 128 + ox] = tanhf(acc1[reg] + bv);
        }
    }
}

// ---------------- channel-last BN stat reduction (only used for conv0 output) ----------------
template <int C>
__global__ void stat_reduce_t(const unsigned short* __restrict__ x, int total4,
                              float* __restrict__ ssum, float* __restrict__ ssq, int statoff) {
    __shared__ float ls[C], lq[C];
    for (int c = threadIdx.x; c < C; c += 256) { ls[c] = 0.f; lq[c] = 0.f; }
    __syncthreads();
    int i0 = blockIdx.x * 256 + threadIdx.x;
    int stride = gridDim.x * 256;
    int c0 = (i0 << 2) & (C - 1);
    float s0 = 0, s1 = 0, s2 = 0, s3 = 0, q0 = 0, q1 = 0, q2 = 0, q3 = 0;
    for (int i = i0; i < total4; i += stride) {
        ushort4 v = *(const ushort4*)(x + ((size_t)i << 2));
        float f0 = bf2f_raw(v.x), f1 = bf2f_raw(v.y), f2 = bf2f_raw(v.z), f3 = bf2f_raw(v.w);
        s0 += f0; s1 += f1; s2 += f2; s3 += f3;
        q0 += f0 * f0; q1 += f1 * f1; q2 += f2 * f2; q3 += f3 * f3;
    }
    atomicAdd(&ls[c0], s0); atomicAdd(&ls[c0 + 1], s1); atomicAdd(&ls[c0 + 2], s2); atomicAdd(&ls[c0 + 3], s3);
    atomicAdd(&lq[c0], q0); atomicAdd(&lq[c0 + 1], q1); atomicAdd(&lq[c0 + 2], q2); atomicAdd(&lq[c0 + 3], q3);
    __syncthreads();
    int slot = (blockIdx.x & (NREP - 1)) * 576;
    for (int c = threadIdx.x; c < C; c += 256) {
        atomicAdd(&ssum[slot + statoff + c], ls[c]);
        atomicAdd(&ssq[slot + statoff + c], lq[c]);
    }
}

// ---------------- BN finalize (sums NREP replicas) ----------------
__global__ void bn_fin_kernel(const float* __restrict__ ssum, const float* __restrict__ ssq,
                              const float* __restrict__ g, const float* __restrict__ be,
                              float* __restrict__ scale, float* __restrict__ shift,
                              int statoff, int C, float invN) {
    int c = threadIdx.x;
    if (c >= C) return;
    float s = 0.f, q = 0.f;
#pragma unroll
    for (int r = 0; r < NREP; ++r) {
        s += ssum[r * 576 + statoff + c];
        q += ssq[r * 576 + statoff + c];
    }
    float m = s * invN;
    float v = q * invN - m * m;
    v = fmaxf(v, 0.f);
    float sc = g[c] * rsqrtf(v + 1e-5f);
    scale[statoff + c] = sc;
    shift[statoff + c] = be[c] - m * sc;
}

extern "C" void kernel_launch(void* const* d_in, const int* in_sizes, int n_in,
                              void* d_out, int out_size, void* d_ws, size_t ws_size,
                              hipStream_t stream) {
    if (ws_size < WS_NEED_BYTES) {
        hipMemsetAsync(d_out, 0, (size_t)out_size * 4, stream);
        return;
    }

    float* W = (float*)d_ws;
    unsigned short* U = (unsigned short*)d_ws;
    int* FLG = (int*)(W + OFF_FLAG);

    detect_kernel<<<1, 256, 0, stream>>>((const unsigned short*)d_in[2], FLG);

    CvtJobs J;
    const int srcIdx[16] = {10, 28, 11, 12, 13, 15, 16, 17, 19, 21, 22, 23, 25, 26, 27, 29};
    const int cnt[16]    = {3072, 6144, 64, 64, 64, 128, 128, 128, 64, 256, 256, 256, 128, 128, 128, 3};
    float* dsts[16] = {W + OFF_WC0, W + OFF_WG2,
                       W + OFF_CB0, W + OFF_CG0, W + OFF_CBE0, W + OFF_CB1, W + OFF_CG1, W + OFF_CBE1,
                       W + OFF_CB2, W + OFF_GB0, W + OFF_GG0, W + OFF_GBE0, W + OFF_GB1, W + OFF_GG1,
                       W + OFF_GBE1, W + OFF_GB2};
    int off = 0;
    for (int k = 0; k < 16; ++k) {
        J.src[k] = d_in[srcIdx[k]];
        J.dst[k] = dsts[k];
        J.off[k] = off;
        off += cnt[k];
    }
    J.off[16] = off;
    cvt_all_kernel<<<(off + 255) / 256, 256, 0, stream>>>(J, off, FLG);

    zero_kernel<<<(2 * NREP * 576 + 255) / 256, 256, 0, stream>>>(W + OFF_SSUM, 2 * NREP * 576);

    // weight packs
    pack_w2_kernel<<<3072, 256, 0, stream>>>(d_in[20], U + UW0, 168, 192, 256, FLG);
    pack_w2_kernel<<<2048, 256, 0, stream>>>(d_in[24], U + UW1, 256, 256, 128, FLG);
    pack_wc_kernel<<<512, 256, 0, stream>>>(d_in[14], U + UWC1, 64, 128, FLG);
    pack_wc_kernel<<<512, 256, 0, stream>>>(d_in[18], U + UWC2, 128, 64, FLG);
    pack_w2s_kernel<<<128, 256, 0, stream>>>(d_in[28], U + UW2, 128, 3, FLG);

    mlp_kernel<<<64, 64, 0, stream>>>(d_in[1], d_in[4], d_in[5], d_in[6], d_in[7],
                                      d_in[8], d_in[9], W + OFF_K12, FLG);

    // ---- conv0 -> X_s2d (raw) ----
    conv0_s2d_kernel<<<dim3(16, 1, 64), 256, 0, stream>>>(d_in[2], W + OFF_WC0, W + OFF_CB0,
                                                          U + UXT, FLG);
    stat_reduce_t<64><<<1024, 256, 0, stream>>>(U + UXT, 4194304, W + OFF_SSUM, W + OFF_SSQ, 0);
    bn_fin_kernel<<<1, 256, 0, stream>>>(W + OFF_SSUM, W + OFF_SSQ, W + OFF_CG0, W + OFF_CBE0,
                                         W + OFF_SCALE, W + OFF_SHIFT, 0, 64, 1.f / 262144.f);

    // ---- conv1 (MFMA, fused L0 BN, fused L1 stats) -> Y_s2d ----
    conv1_mfma_kernel<<<2048, 256, 0, stream>>>(U + UXT, U + UWC1, W + OFF_CB1,
                                                W + OFF_SCALE + 0, W + OFF_SHIFT + 0,
                                                W + OFF_SSUM, W + OFF_SSQ, U + UYT);
    bn_fin_kernel<<<1, 256, 0, stream>>>(W + OFF_SSUM, W + OFF_SSQ, W + OFF_CG1, W + OFF_CBE1,
                                         W + OFF_SCALE, W + OFF_SHIFT, 64, 128, 1.f / 65536.f);

    // ---- conv2 (MFMA, fused L1 BN) + tanh -> Z_t[0:64) ----
    conv2_mfma_kernel<<<512, 256, 0, stream>>>(U + UYT, U + UWC2, W + OFF_CB2,
                                               W + OFF_SCALE + 64, W + OFF_SHIFT + 64, U + UZT);

    // ---- Z_t[64:192) incl. pad zeroing ----
    assemble_z<<<8192, 256, 0, stream>>>(d_in[0], d_in[1], d_in[3], W + OFF_K12, U + UZT, FLG);

    // ---- gen deconv0 (MFMA, fused G0 stats): Z_t -> X_t(32,32,256) ----
    deconv_mfma2_kernel<192, 16, 256, 2, false, true><<<2048, 256, 0, stream>>>(
        U + UZT, U + UW0, W + OFF_GB0, nullptr, nullptr,
        W + OFF_SSUM, W + OFF_SSQ, 192, U + UXT);
    bn_fin_kernel<<<1, 256, 0, stream>>>(W + OFF_SSUM, W + OFF_SSQ, W + OFF_GG0, W + OFF_GBE0,
                                         W + OFF_SCALE, W + OFF_SHIFT, 192, 256, 1.f / 65536.f);

    // ---- gen deconv1 (MFMA, fused G0 BN, fused G1 stats): X_t -> Y_t(64,64,128) ----
    deconv_mfma2_kernel<256, 32, 128, 2, true, true><<<4096, 256, 0, stream>>>(
        U + UXT, U + UW1, W + OFF_GB1, W + OFF_SCALE + 192, W + OFF_SHIFT + 192,
        W + OFF_SSUM, W + OFF_SSQ, 448, U + UYT);
    bn_fin_kernel<<<1, 256, 0, stream>>>(W + OFF_SSUM, W + OFF_SSQ, W + OFF_GG1, W + OFF_GBE1,
                                         W + OFF_SCALE, W + OFF_SHIFT, 448, 128, 1.f / 262144.f);

    // ---- gen deconv2 (MFMA, fused G1 BN) + tanh -> d_out fp32 ----
    deconv2_mfma_kernel<<<8192, 256, 0, stream>>>(U + UYT, U + UW2, W + OFF_GB2,
                                                  W + OFF_SCALE + 448, W + OFF_SHIFT + 448,
                                                  (float*)d_out);
}

// Round 10
// 602.356 us; speedup vs baseline: 1.1761x; 1.0104x over previous
//
#include <hip/hip_runtime.h>
#include <hip/hip_bf16.h>

#define TWO_PI_F 6.2831853071795864769f

typedef __attribute__((ext_vector_type(8))) __bf16 bf16x8;
typedef __attribute__((ext_vector_type(4))) float f32x4;

// 32-way replicated stat buffers: per-address global atomic chains drop 32x.
#define NREP 32

__device__ __forceinline__ float bf2f_raw(unsigned short u) {
    return __uint_as_float(((unsigned int)u) << 16);
}
__device__ __forceinline__ unsigned short f2bf(float f) {
    unsigned int u = __float_as_uint(f);
    unsigned int r = (u + 0x7FFFu + ((u >> 16) & 1u)) >> 16;   // RNE
    return (unsigned short)r;
}
__device__ __forceinline__ float loadIn(const void* p, size_t i, bool f32) {
    return f32 ? ((const float*)p)[i] : bf2f_raw(((const unsigned short*)p)[i]);
}

// Fused BN affine + (leaky)relu applied to 8 packed bf16 during staging.
__device__ __forceinline__ uint4 bn_fuse8(uint4 v, const float* __restrict__ sc,
                                          const float* __restrict__ sh, int c0, float slope) {
    unsigned short us[8];
    *(uint4*)us = v;
#pragma unroll
    for (int k = 0; k < 8; ++k) {
        float f = bf2f_raw(us[k]) * sc[c0 + k] + sh[c0 + k];
        f = f > 0.f ? f : slope * f;
        us[k] = f2bf(f);
    }
    return *(const uint4*)us;
}

// Reduce val across the 4 kq-groups of a wave (lanes differing in bits 4,5).
__device__ __forceinline__ float kq_reduce(float v) {
    v += __shfl_xor(v, 16, 64);
    v += __shfl_xor(v, 32, 64);
    return v;
}

// ---------------- ws layout ----------------
static constexpr size_t OFF_WC0 = 0;          // cod_w0 fp32 3072
static constexpr size_t OFF_WG2 = 3072;       // gen_w2 fp32 6144 (legacy, unused)
static constexpr size_t OFF_P   = 9216;
static constexpr size_t OFF_CB0 = OFF_P + 0;
static constexpr size_t OFF_CG0 = OFF_P + 64;
static constexpr size_t OFF_CBE0= OFF_P + 128;
static constexpr size_t OFF_CB1 = OFF_P + 192;
static constexpr size_t OFF_CG1 = OFF_P + 320;
static constexpr size_t OFF_CBE1= OFF_P + 448;
static constexpr size_t OFF_CB2 = OFF_P + 576;
static constexpr size_t OFF_GB0 = OFF_P + 640;
static constexpr size_t OFF_GG0 = OFF_P + 896;
static constexpr size_t OFF_GBE0= OFF_P + 1152;
static constexpr size_t OFF_GB1 = OFF_P + 1408;
static constexpr size_t OFF_GG1 = OFF_P + 1536;
static constexpr size_t OFF_GBE1= OFF_P + 1664;
static constexpr size_t OFF_GB2 = OFF_P + 1792;
static constexpr size_t OFF_SSUM  = OFF_P + 2048;              // NREP x 576
static constexpr size_t OFF_SSQ   = OFF_SSUM + NREP * 576;     // NREP x 576
static constexpr size_t OFF_SCALE = OFF_SSQ + NREP * 576;
static constexpr size_t OFF_SHIFT = OFF_SCALE + 576;
static constexpr size_t OFF_K12   = OFF_SHIFT + 576;
static constexpr size_t OFF_FLAG  = OFF_K12 + 1024;
static constexpr size_t FP32_END  = OFF_FLAG + 16;   // floats
// ushort regions:
static constexpr size_t UXT = 2 * FP32_END;            // X region: X_s2d (b,2,2,32,32,64) then X_t (b,32,32,256)
static constexpr size_t UYT = UXT + 16777216;          // Y region: Y_s2d head, then Y_t (b,64,64,128)
static constexpr size_t UZT = UYT + 8388608;           // Z_t (b,16,16,192)
static constexpr size_t UW0 = UYT + 33554432;          // deconv0 pack
static constexpr size_t UW1 = UW0 + 786432;            // deconv1 pack
static constexpr size_t UWC1 = UW1 + 524288;           // conv1 pack
static constexpr size_t UWC2 = UWC1 + 131072;          // conv2 pack
static constexpr size_t UW2 = UWC2 + 131072;           // deconv2 pack
static constexpr size_t WS_END_USHORT = UW2 + 32768;
static constexpr size_t WS_NEED_BYTES = WS_END_USHORT * 2;   // ~110 MB

// stat slots: L0:0(64) L1:64(128) G0:192(256) G1:448(128)

// ---------------- input dtype detection ----------------
__global__ void detect_kernel(const unsigned short* __restrict__ imgs, int* __restrict__ flag) {
    int t = threadIdx.x;  // 256
    unsigned short u = imgs[t];
    int e = (u >> 7) & 0xFF;
    unsigned long long b = __ballot(e >= 0xC0);
    __shared__ int cnt[4];
    if ((t & 63) == 0) cnt[t >> 6] = __popcll(b);
    __syncthreads();
    if (t == 0) flag[0] = (cnt[0] + cnt[1] + cnt[2] + cnt[3] >= 4) ? 1 : 0;
}

// ---------------- small param -> fp32 conversion ----------------
struct CvtJobs {
    const void* src[16];
    float* dst[16];
    int off[17];
};

__global__ void cvt_all_kernel(CvtJobs J, int total, const int* __restrict__ flg) {
    int i = blockIdx.x * 256 + threadIdx.x;
    if (i >= total) return;
    bool f32 = flg[0] != 0;
    int k = 0;
#pragma unroll
    for (int t = 0; t < 15; ++t) { if (i >= J.off[t + 1]) k = t + 1; }
    int r = i - J.off[k];
    J.dst[k][r] = loadIn(J.src[k], r, f32);
}

__global__ void zero_kernel(float* p, int n) {
    int i = blockIdx.x * 256 + threadIdx.x;
    if (i < n) p[i] = 0.f;
}

// ---------------- deconv weight packing ----------------
__global__ void pack_w2_kernel(const void* __restrict__ src, unsigned short* __restrict__ dst,
                               int ICreal, int ICP, int OC, const int* __restrict__ flg) {
    bool f32 = flg[0] != 0;
    int i = blockIdx.x * 256 + threadIdx.x;
    int total = 16 * OC * ICP;
    if (i >= total) return;
    int jj = i & 7;
    int lane = (i >> 3) & 63;
    int j = (i >> 9) & 3;
    int t3 = i >> 11;
    int NK = ICP / 32;
    int kc = t3 % NK;
    int t4 = t3 / NK;
    int NOCT = OC / 64;
    int oct = t4 % NOCT;
    int ktap = t4 / NOCT;
    int kq = lane >> 4, n = lane & 15;
    int ic = kc * 32 + kq * 8 + jj;
    int oc = oct * 64 + n * 4 + j;          // channel-interleaved
    unsigned short v = 0;
    if (ic < ICreal) v = f2bf(loadIn(src, ((size_t)(ic * OC + oc) << 4) + ktap, f32));
    dst[i] = v;
}

__global__ void pack_w2s_kernel(const void* __restrict__ src, unsigned short* __restrict__ dst,
                                int ICP, int OCreal, const int* __restrict__ flg) {
    bool f32 = flg[0] != 0;
    int i = blockIdx.x * 256 + threadIdx.x;
    int NK = ICP / 32;
    int total = 16 * NK * 512;
    if (i >= total) return;
    int jj = i & 7;
    int lane = (i >> 3) & 63;
    int t3 = i >> 9;
    int kc = t3 % NK;
    int ktap = t3 / NK;
    int kq = lane >> 4, n = lane & 15;
    int ic = kc * 32 + kq * 8 + jj;
    unsigned short v = 0;
    if (n < OCreal) v = f2bf(loadIn(src, ((size_t)(ic * OCreal + n) << 4) + ktap, f32));
    dst[i] = v;
}

__global__ void pack_wc_kernel(const void* __restrict__ src, unsigned short* __restrict__ dst,
                               int IC, int OC, const int* __restrict__ flg) {
    bool f32 = flg[0] != 0;
    int i = blockIdx.x * 256 + threadIdx.x;
    int total = 16 * OC * IC;
    if (i >= total) return;
    int jj = i & 7;
    int lane = (i >> 3) & 63;
    int j = (i >> 9) & 3;
    int t3 = i >> 11;
    int NK = IC / 32;
    int kc = t3 % NK;
    int t4 = t3 / NK;
    int NOCT = OC / 64;
    int oct = t4 % NOCT;
    int ktap = t4 / NOCT;
    int kq = lane >> 4, n = lane & 15;
    int ic = kc * 32 + kq * 8 + jj;
    int oc = oct * 64 + j * 16 + n;
    dst[i] = f2bf(loadIn(src, ((size_t)(oc * IC + ic) << 4) + ktap, f32));
}

// ---------------- tiny MLP ----------------
__global__ void mlp_kernel(const void* __restrict__ Zg,
                           const void* __restrict__ lW, const void* __restrict__ lb,
                           const void* __restrict__ l1W, const void* __restrict__ l1b,
                           const void* __restrict__ l2W, const void* __restrict__ l2b,
                           float* __restrict__ K12, const int* __restrict__ flg) {
    bool f32 = flg[0] != 0;
    int b = blockIdx.x;
    int t = threadIdx.x;  // 64
    __shared__ float xs[64];
    float acc = loadIn(lb, t, f32);
    for (int c = 0; c < 64; ++c)
        acc += loadIn(Zg, (size_t)(b * 64 + c) * 256, f32) * loadIn(lW, t * 64 + c, f32);
    xs[t] = fmaxf(acc, 0.f);
    __syncthreads();
    if (t < 16) {
        int p = t & 7;
        const void* Wp = (t < 8) ? l1W : l2W;
        const void* bp = (t < 8) ? l1b : l2b;
        float a = loadIn(bp, p, f32);
        for (int h = 0; h < 64; ++h) a += xs[h] * loadIn(Wp, p * 64 + h, f32);
        K12[b * 16 + t] = a;
    }
}

// ---------------- conv0: imgs -> X_s2d ----------------
__global__ void conv0_s2d_kernel(const void* __restrict__ imgs, const float* __restrict__ w,
                                 const float* __restrict__ bias, unsigned short* __restrict__ xs,
                                 const int* __restrict__ flg) {
    bool f32 = flg[0] != 0;
    int b = blockIdx.z;
    int tile = blockIdx.x;
    int Y0 = (tile >> 2) * 16, X0 = (tile & 3) * 16;
    __shared__ float vin[3 * 34 * 35];
    __shared__ float wl[64 * 49];
    for (int i = threadIdx.x; i < 3 * 34 * 34; i += 256) {
        int c = i % 34; int t = i / 34; int r = t % 34; int ic = t / 34;
        int iy = 2 * Y0 - 1 + r, ix = 2 * X0 - 1 + c;
        float v = 0.f;
        if (((unsigned)iy < 128u) & ((unsigned)ix < 128u))
            v = loadIn(imgs, ((size_t)(b * 3 + ic) * 128 + iy) * 128 + ix, f32);
        vin[(ic * 34 + r) * 35 + c] = v;
    }
    for (int i = threadIdx.x; i < 3072; i += 256) {
        int oc = i / 48, idx = i % 48;
        wl[oc * 49 + idx] = w[i];
    }
    __syncthreads();
    int q = threadIdx.x >> 2;
    int ocq = threadIdx.x & 3;
    int qy = q >> 3, qx = q & 7;
    float acc[4][16];
#pragma unroll
    for (int p = 0; p < 4; ++p)
#pragma unroll
        for (int o = 0; o < 16; ++o) acc[p][o] = 0.f;
    for (int ic = 0; ic < 3; ++ic) {
        float v[6][6];
#pragma unroll
        for (int r = 0; r < 6; ++r)
#pragma unroll
            for (int c = 0; c < 6; ++c)
                v[r][c] = vin[(ic * 34 + 4 * qy + r) * 35 + 4 * qx + c];
#pragma unroll
        for (int o = 0; o < 16; ++o) {
            const float* wo = wl + (ocq * 16 + o) * 49 + ic * 16;
#pragma unroll
            for (int ky = 0; ky < 4; ++ky)
#pragma unroll
                for (int kx = 0; kx < 4; ++kx) {
                    float wv = wo[ky * 4 + kx];
                    acc[0][o] = fmaf(v[ky][kx], wv, acc[0][o]);
                    acc[1][o] = fmaf(v[ky][kx + 2], wv, acc[1][o]);
                    acc[2][o] = fmaf(v[ky + 2][kx], wv, acc[2][o]);
                    acc[3][o] = fmaf(v[ky + 2][kx + 2], wv, acc[3][o]);
                }
        }
    }
    int j = (Y0 >> 1) + qy, i2 = (X0 >> 1) + qx;
#pragma unroll
    for (int p = 0; p < 4; ++p) {
        int dy = p >> 1, dx = p & 1;
        unsigned short tmp[16];
#pragma unroll
        for (int o = 0; o < 16; ++o) tmp[o] = f2bf(acc[p][o] + bias[ocq * 16 + o]);
        unsigned short* dst = xs + (((size_t)((b * 2 + dy) * 2 + dx) * 32 + j) * 32 + i2) * 64 + ocq * 16;
        *(uint4*)(dst) = *(const uint4*)(tmp);
        *(uint4*)(dst + 8) = *(const uint4*)(tmp + 8);
    }
}

// ---------------- conv1 (MFMA, fused L0 BN on load, fused L1 stats, atomic-free in-block reduce) ----------------
__global__ void conv1_mfma_kernel(const unsigned short* __restrict__ xs,
                                  const unsigned short* __restrict__ wp,
                                  const float* __restrict__ bias,
                                  const float* __restrict__ sc, const float* __restrict__ sh,
                                  float* __restrict__ gsum, float* __restrict__ gsq,
                                  unsigned short* __restrict__ ys) {
    constexpr int STR = 72;
    __shared__ unsigned short lds[4 * 3 * 17 * STR];   // 29.4 KB
    __shared__ float ws[4][64], wq[4][64];
    int bid = blockIdx.x;
    int slot = (bid & (NREP - 1)) * 576;
    int xt = bid & 1;
    int qp = (bid >> 1) & 15;
    int b = bid >> 5;
    int oy0 = qp * 2, x0 = xt * 16;
    for (int i = threadIdx.x; i < 1632; i += 256) {
        int icc = i & 7; int t = i >> 3;
        int col = t % 17; int rc = t / 17;
        int row = rc % 3; int pl = rc / 3;
        int py = pl >> 1, px = pl & 1;
        int j = oy0 - py + row;
        int ci = x0 - px + col;
        uint4 v = {0u, 0u, 0u, 0u};
        if (((unsigned)j < 32u) & ((unsigned)ci < 32u)) {
            v = *(const uint4*)(xs + ((size_t)((b * 4 + pl) * 32 + j) * 32 + ci) * 64 + icc * 8);
            v = bn_fuse8(v, sc, sh, icc * 8, 0.2f);
        }
        *(uint4*)(lds + ((pl * 3 + row) * 17 + col) * STR + icc * 8) = v;
    }
    __syncthreads();

    int wv = threadIdx.x >> 6, lane = threadIdx.x & 63;
    int r = wv >> 1, oct = wv & 1;
    int m = lane & 15, kq = lane >> 4;
    f32x4 acc[4];
#pragma unroll
    for (int j = 0; j < 4; ++j) acc[j] = (f32x4){0.f, 0.f, 0.f, 0.f};

#pragma unroll
    for (int ky = 0; ky < 4; ++ky) {
        int py = (ky & 1) ^ 1;
        int lrow = r + (ky >> 1);
#pragma unroll
        for (int kx = 0; kx < 4; ++kx) {
            int px = (kx & 1) ^ 1;
            int pl = py * 2 + px;
            int lcol = m + (kx >> 1);
            const unsigned short* lp = lds + ((pl * 3 + lrow) * 17 + lcol) * STR + kq * 8;
            int ktap = ky * 4 + kx;
            const unsigned short* bb = wp + (size_t)(ktap * 2 + oct) * 4096;
#pragma unroll
            for (int kc = 0; kc < 2; ++kc) {
                bf16x8 a = *(const bf16x8*)(lp + kc * 32);
                const unsigned short* bk = bb + kc * 2048 + lane * 8;
                bf16x8 b0 = *(const bf16x8*)(bk);
                bf16x8 b1 = *(const bf16x8*)(bk + 512);
                bf16x8 b2 = *(const bf16x8*)(bk + 1024);
                bf16x8 b3 = *(const bf16x8*)(bk + 1536);
                acc[0] = __builtin_amdgcn_mfma_f32_16x16x32_bf16(a, b0, acc[0], 0, 0, 0);
                acc[1] = __builtin_amdgcn_mfma_f32_16x16x32_bf16(a, b1, acc[1], 0, 0, 0);
                acc[2] = __builtin_amdgcn_mfma_f32_16x16x32_bf16(a, b2, acc[2], 0, 0, 0);
                acc[3] = __builtin_amdgcn_mfma_f32_16x16x32_bf16(a, b3, acc[3], 0, 0, 0);
            }
        }
    }
    int oy = oy0 + r;
    int pyo = oy & 1, jo = oy >> 1;
    int n = m;
    float bv0 = bias[oct * 64 + n], bv1 = bias[oct * 64 + 16 + n];
    float bv2 = bias[oct * 64 + 32 + n], bv3 = bias[oct * 64 + 48 + n];
    float s0 = 0, s1 = 0, s2 = 0, s3 = 0, q0 = 0, q1 = 0, q2 = 0, q3 = 0;
#pragma unroll
    for (int reg = 0; reg < 4; ++reg) {
        int mm = kq * 4 + reg;
        int ox = x0 + mm;
        int pxo = ox & 1, io = ox >> 1;
        size_t base = (((size_t)((b * 2 + pyo) * 2 + pxo) * 16 + jo) * 16 + io) * 128 + oct * 64 + n;
        float v0 = acc[0][reg] + bv0, v1 = acc[1][reg] + bv1;
        float v2 = acc[2][reg] + bv2, v3 = acc[3][reg] + bv3;
        s0 += v0; q0 += v0 * v0; s1 += v1; q1 += v1 * v1;
        s2 += v2; q2 += v2 * v2; s3 += v3; q3 += v3 * v3;
        ys[base]      = f2bf(v0);
        ys[base + 16] = f2bf(v1);
        ys[base + 32] = f2bf(v2);
        ys[base + 48] = f2bf(v3);
    }
    // wave-level kq reduction (no atomics)
    s0 = kq_reduce(s0); q0 = kq_reduce(q0);
    s1 = kq_reduce(s1); q1 = kq_reduce(q1);
    s2 = kq_reduce(s2); q2 = kq_reduce(q2);
    s3 = kq_reduce(s3); q3 = kq_reduce(q3);
    if (lane < 16) {
        ws[wv][0 * 16 + n] = s0; wq[wv][0 * 16 + n] = q0;
        ws[wv][1 * 16 + n] = s1; wq[wv][1 * 16 + n] = q1;
        ws[wv][2 * 16 + n] = s2; wq[wv][2 * 16 + n] = q2;
        ws[wv][3 * 16 + n] = s3; wq[wv][3 * 16 + n] = q3;
    }
    __syncthreads();
    if (threadIdx.x < 128) {
        int c = threadIdx.x;
        int o = c >> 6, rr = c & 63;          // waves {o, o+2} cover oct o
        float s = ws[o][rr] + ws[o + 2][rr];
        float q = wq[o][rr] + wq[o + 2][rr];
        atomicAdd(&gsum[slot + 64 + c], s);
        atomicAdd(&gsq[slot + 64 + c], q);
    }
}

// ---------------- conv2 (MFMA, fused L1 BN on load) + tanh: Y_s2d -> Z_t[0:64) ----------------
__global__ void conv2_mfma_kernel(const unsigned short* __restrict__ ys,
                                  const unsigned short* __restrict__ wp,
                                  const float* __restrict__ bias,
                                  const float* __restrict__ sc, const float* __restrict__ sh,
                                  unsigned short* __restrict__ zt) {
    constexpr int STR = 136;
    __shared__ unsigned short lds[4 * 3 * 17 * STR];   // 55.5 KB
    int bid = blockIdx.x;
    int qp = bid & 7;
    int b = bid >> 3;
    int oy0 = qp * 2;
    for (int i = threadIdx.x; i < 3264; i += 256) {
        int icc = i & 15; int t = i >> 4;
        int col = t % 17; int rc = t / 17;
        int row = rc % 3; int pl = rc / 3;
        int py = pl >> 1, px = pl & 1;
        int j = oy0 - py + row;
        int ci = col - px;
        uint4 v = {0u, 0u, 0u, 0u};
        if (((unsigned)j < 16u) & ((unsigned)ci < 16u)) {
            v = *(const uint4*)(ys + ((size_t)((b * 4 + pl) * 16 + j) * 16 + ci) * 128 + icc * 8);
            v = bn_fuse8(v, sc, sh, icc * 8, 0.2f);
        }
        *(uint4*)(lds + ((pl * 3 + row) * 17 + col) * STR + icc * 8) = v;
    }
    __syncthreads();

    int wv = threadIdx.x >> 6, lane = threadIdx.x & 63;
    int r = wv >> 1, jh = wv & 1;
    int m = lane & 15, kq = lane >> 4;
    f32x4 acc[2];
    acc[0] = (f32x4){0.f, 0.f, 0.f, 0.f};
    acc[1] = acc[0];
#pragma unroll
    for (int ky = 0; ky < 4; ++ky) {
        int py = (ky & 1) ^ 1;
        int lrow = r + (ky >> 1);
#pragma unroll
        for (int kx = 0; kx < 4; ++kx) {
            int px = (kx & 1) ^ 1;
            int pl = py * 2 + px;
            int lcol = m + (kx >> 1);
            const unsigned short* lp = lds + ((pl * 3 + lrow) * 17 + lcol) * STR + kq * 8;
            int ktap = ky * 4 + kx;
            const unsigned short* bb = wp + (size_t)ktap * 8192;
#pragma unroll
            for (int kc = 0; kc < 4; ++kc) {
                bf16x8 a = *(const bf16x8*)(lp + kc * 32);
                const unsigned short* bk = bb + kc * 2048 + (jh * 2) * 512 + lane * 8;
                bf16x8 b0 = *(const bf16x8*)(bk);
                bf16x8 b1 = *(const bf16x8*)(bk + 512);
                acc[0] = __builtin_amdgcn_mfma_f32_16x16x32_bf16(a, b0, acc[0], 0, 0, 0);
                acc[1] = __builtin_amdgcn_mfma_f32_16x16x32_bf16(a, b1, acc[1], 0, 0, 0);
            }
        }
    }
    int oy = oy0 + r;
    int n = m;
    float bv0 = bias[(jh * 2) * 16 + n], bv1 = bias[(jh * 2 + 1) * 16 + n];
#pragma unroll
    for (int reg = 0; reg < 4; ++reg) {
        int x = kq * 4 + reg;
        size_t base = ((size_t)(b * 16 + oy) * 16 + x) * 192 + (jh * 2) * 16 + n;
        zt[base]      = f2bf(tanhf(acc[0][reg] + bv0));
        zt[base + 16] = f2bf(tanhf(acc[1][reg] + bv1));
    }
}

// ---------------- assemble Z_t[...][64:192): Zl, Zg, wave, and pad channels ----------------
__global__ void assemble_z(const void* __restrict__ Zl, const void* __restrict__ Zg,
                           const void* __restrict__ phi, const float* __restrict__ K12,
                           unsigned short* __restrict__ zt, const int* __restrict__ flg) {
    bool f32 = flg[0] != 0;
    int i = blockIdx.x * 256 + threadIdx.x;
    const int TOT = 64 * 128 * 256;
    if (i >= TOT) return;
    int pos = i & 255;
    int t = i >> 8;
    int c128 = t % 128;
    int b = t / 128;
    float val;
    if (c128 < 32) {
        val = loadIn(Zl, ((size_t)(b * 32 + c128) << 8) + pos, f32);
    } else if (c128 < 96) {
        val = loadIn(Zg, ((size_t)(b * 64 + (c128 - 32)) << 8) + pos, f32);
    } else if (c128 < 104) {
        int p = c128 - 96;
        int y = pos >> 4, x = pos & 15;
        float k1 = K12[b * 16 + p];
        float k2 = K12[b * 16 + 8 + p];
        val = sinf(k1 * (float)y + k2 * (float)x + loadIn(phi, b * 8 + p, f32) * TWO_PI_F);
    } else {
        val = 0.f;      // pad channels 168..192 of Z_t
    }
    zt[((size_t)(b * 256 + pos)) * 192 + 64 + c128] = f2bf(val);
}

// ---------------- MFMA transposed-conv v10: QR=2, oct slowest, fused BN-in, optional stats ----------------
// Round-9 verdict: ST=true costs ~40 us structurally in deconv1 (extra live regs + LDS pushing
// 4-block residency over the 160 KiB edge + retire barrier). deconv1 runs ST=false; its stats
// come from a separate stat_reduce pass (67 MB read ~= 18 us < 40 us).
template <int ICP, int Q, int OC, int QR, bool BN, bool ST>
__global__ __launch_bounds__(256, 2)
void deconv_mfma2_kernel(const unsigned short* __restrict__ in_t,
                         const unsigned short* __restrict__ wp2,
                         const float* __restrict__ bias,
                         const float* __restrict__ sc, const float* __restrict__ sh,
                         float* __restrict__ gsum, float* __restrict__ gsq, int statoff,
                         unsigned short* __restrict__ out_t) {
    constexpr int NOCT = OC / 64;
    constexpr int NK = ICP / 32;
    constexpr int XT = Q / 16;
    constexpr int NQB = Q / QR;
    constexpr int ROWS = QR + 2;
    constexpr int STRIDE = ICP + 8;
    constexpr int NTILES = XT * NQB * 64;
    __shared__ unsigned short lds[ROWS * 18 * STRIDE];
    __shared__ float ws[ST ? 4 : 1][64], wq[ST ? 4 : 1][64];

    int bid = blockIdx.x;
    int slot = (bid & (NREP - 1)) * 576;
    int oct = bid / NTILES;          // slowest dim
    bid -= oct * NTILES;
    int xt = bid % XT;
    int t2 = bid / XT;
    int qp = t2 % NQB;
    int b = t2 / NQB;
    int qy0 = qp * QR;
    int x0 = xt * 16;

    constexpr int P8 = ICP / 8;
    constexpr int E8 = ROWS * 18 * P8;
    for (int i = threadIdx.x; i < E8; i += 256) {
        int icc = i % P8;
        int rc = i / P8;
        int row = rc / 18, col = rc % 18;
        int y = qy0 - 1 + row, x = x0 - 1 + col;
        uint4 val = {0u, 0u, 0u, 0u};
        if (((unsigned)y < (unsigned)Q) & ((unsigned)x < (unsigned)Q)) {
            val = *(const uint4*)(in_t + (size_t)((b * Q + y) * Q + x) * ICP + icc * 8);
            if (BN) val = bn_fuse8(val, sc, sh, icc * 8, 0.f);
        }
        *(uint4*)(lds + rc * STRIDE + icc * 8) = val;
    }
    __syncthreads();

    int wv = threadIdx.x >> 6, lane = threadIdx.x & 63;
    int dy = wv >> 1, dx = wv & 1;
    int m = lane & 15, kq = lane >> 4;

    f32x4 acc[QR][4];
#pragma unroll
    for (int q = 0; q < QR; ++q)
#pragma unroll
        for (int j = 0; j < 4; ++j) acc[q][j] = (f32x4){0.f, 0.f, 0.f, 0.f};

#pragma unroll
    for (int t = 0; t < 4; ++t) {
        int rr = t >> 1, cc = t & 1;
        int ktap = ((3 - dy) - 2 * rr) * 4 + ((3 - dx) - 2 * cc);
        int col = m + dx + cc;
        int row0 = dy + rr;
        const unsigned short* bbase = wp2 + (size_t)((ktap * NOCT + oct) * NK) * 2048;
#pragma unroll
        for (int kc = 0; kc < NK; ++kc) {
            bf16x8 a[QR];
#pragma unroll
            for (int q = 0; q < QR; ++q)
                a[q] = *(const bf16x8*)(lds + ((row0 + q) * 18 + col) * STRIDE + kc * 32 + kq * 8);
            bf16x8 b0 = *(const bf16x8*)(bbase + (kc * 4 + 0) * 512 + lane * 8);
            bf16x8 b1 = *(const bf16x8*)(bbase + (kc * 4 + 1) * 512 + lane * 8);
            bf16x8 b2 = *(const bf16x8*)(bbase + (kc * 4 + 2) * 512 + lane * 8);
            bf16x8 b3 = *(const bf16x8*)(bbase + (kc * 4 + 3) * 512 + lane * 8);
#pragma unroll
            for (int q = 0; q < QR; ++q) {
                acc[q][0] = __builtin_amdgcn_mfma_f32_16x16x32_bf16(a[q], b0, acc[q][0], 0, 0, 0);
                acc[q][1] = __builtin_amdgcn_mfma_f32_16x16x32_bf16(a[q], b1, acc[q][1], 0, 0, 0);
                acc[q][2] = __builtin_amdgcn_mfma_f32_16x16x32_bf16(a[q], b2, acc[q][2], 0, 0, 0);
                acc[q][3] = __builtin_amdgcn_mfma_f32_16x16x32_bf16(a[q], b3, acc[q][3], 0, 0, 0);
            }
        }
    }
    // Epilogue: lane n holds channels oct*64 + 4n + j -> one contiguous ushort4 per (qyl,reg).
    int n = m;
    const float4 bv = *(const float4*)(bias + oct * 64 + 4 * n);
    float s0 = 0, s1 = 0, s2 = 0, s3 = 0, q0 = 0, q1 = 0, q2 = 0, q3 = 0;
#pragma unroll
    for (int qyl = 0; qyl < QR; ++qyl) {
        int oy = 2 * (qy0 + qyl) + dy;
#pragma unroll
        for (int reg = 0; reg < 4; ++reg) {
            int mm = kq * 4 + reg;
            int ox = 2 * (x0 + mm) + dx;
            size_t base = ((size_t)((b * 2 * Q + oy) * (2 * Q) + ox)) * OC + oct * 64 + 4 * n;
            float v0 = acc[qyl][0][reg] + bv.x;
            float v1 = acc[qyl][1][reg] + bv.y;
            float v2 = acc[qyl][2][reg] + bv.z;
            float v3 = acc[qyl][3][reg] + bv.w;
            if (ST) {
                s0 += v0; q0 += v0 * v0; s1 += v1; q1 += v1 * v1;
                s2 += v2; q2 += v2 * v2; s3 += v3; q3 += v3 * v3;
            }
            ushort4 tv;
            tv.x = f2bf(v0); tv.y = f2bf(v1); tv.z = f2bf(v2); tv.w = f2bf(v3);
            *(ushort4*)(out_t + base) = tv;
        }
    }
    if (ST) {
        // wave-level kq reduction (no LDS atomics)
        s0 = kq_reduce(s0); q0 = kq_reduce(q0);
        s1 = kq_reduce(s1); q1 = kq_reduce(q1);
        s2 = kq_reduce(s2); q2 = kq_reduce(q2);
        s3 = kq_reduce(s3); q3 = kq_reduce(q3);
        if (lane < 16) {
            ws[wv][4 * n + 0] = s0; wq[wv][4 * n + 0] = q0;
            ws[wv][4 * n + 1] = s1; wq[wv][4 * n + 1] = q1;
            ws[wv][4 * n + 2] = s2; wq[wv][4 * n + 2] = q2;
            ws[wv][4 * n + 3] = s3; wq[wv][4 * n + 3] = q3;
        }
        __syncthreads();
        if (threadIdx.x < 64) {
            int c = threadIdx.x;
            float s = ws[0][c] + ws[1][c] + ws[2][c] + ws[3][c];
            float q = wq[0][c] + wq[1][c] + wq[2][c] + wq[3][c];
            atomicAdd(&gsum[slot + statoff + oct * 64 + c], s);
            atomicAdd(&gsq[slot + statoff + oct * 64 + c], q);
        }
    }
}

// ---------------- deconv2 (MFMA, fused G1 BN+relu on load, OC=3 pad 16) + tanh -> fp32 NCHW ----------------
__global__ void deconv2_mfma_kernel(const unsigned short* __restrict__ yt,
                                    const unsigned short* __restrict__ wp,
                                    const float* __restrict__ bias,
                                    const float* __restrict__ sc, const float* __restrict__ sh,
                                    float* __restrict__ outp) {
    constexpr int Q = 64, ICP = 128, NK = 4, STRIDE = 136;
    __shared__ unsigned short lds[4 * 18 * STRIDE];   // 19.6 KB
    int bid = blockIdx.x;
    int xt = bid & 3;
    int t2 = bid >> 2;
    int qp = t2 & 31;
    int b = t2 >> 5;
    int qy0 = qp * 2, x0 = xt * 16;

    for (int i = threadIdx.x; i < 4 * 18 * 16; i += 256) {
        int icc = i & 15;
        int rc = i >> 4;
        int row = rc / 18, col = rc % 18;
        int y = qy0 - 1 + row, x = x0 - 1 + col;
        uint4 v = {0u, 0u, 0u, 0u};
        if (((unsigned)y < (unsigned)Q) & ((unsigned)x < (unsigned)Q)) {
            v = *(const uint4*)(yt + (size_t)((b * Q + y) * Q + x) * ICP + icc * 8);
            v = bn_fuse8(v, sc, sh, icc * 8, 0.f);
        }
        *(uint4*)(lds + rc * STRIDE + icc * 8) = v;
    }
    __syncthreads();

    int wv = threadIdx.x >> 6, lane = threadIdx.x & 63;
    int dy = wv >> 1, dx = wv & 1;
    int m = lane & 15, kq = lane >> 4;
    f32x4 acc0 = {0.f, 0.f, 0.f, 0.f}, acc1 = acc0;

#pragma unroll
    for (int t = 0; t < 4; ++t) {
        int rr = t >> 1, cc = t & 1;
        int ktap = ((3 - dy) - 2 * rr) * 4 + ((3 - dx) - 2 * cc);
        int col = m + dx + cc;
        int row0 = dy + rr;
        const unsigned short* bb = wp + (size_t)(ktap * NK) * 512;
#pragma unroll
        for (int kc = 0; kc < NK; ++kc) {
            bf16x8 a0 = *(const bf16x8*)(lds + (row0 * 18 + col) * STRIDE + kc * 32 + kq * 8);
            bf16x8 a1 = *(const bf16x8*)(lds + ((row0 + 1) * 18 + col) * STRIDE + kc * 32 + kq * 8);
            bf16x8 b0 = *(const bf16x8*)(bb + kc * 512 + lane * 8);
            acc0 = __builtin_amdgcn_mfma_f32_16x16x32_bf16(a0, b0, acc0, 0, 0, 0);
            acc1 = __builtin_amdgcn_mfma_f32_16x16x32_bf16(a1, b0, acc1, 0, 0, 0);
        }
    }
    int n = m;
    if (n < 3) {
        float bv = bias[n];
#pragma unroll
        for (int reg = 0; reg < 4; ++reg) {
            int mm = kq * 4 + reg;
            int ox = 2 * (x0 + mm) + dx;
            int oy0_ = 2 * qy0 + dy;
            size_t ob = (size_t)(b * 3 + n) * 16384;
            outp[ob + (size_t)oy0_ * 128 + ox]       = tanhf(acc0[reg] + bv);
            outp[ob + (size_t)(oy0_ + 2) * 128 + ox] = tanhf(acc1[reg] + bv);
        }
    }
}

// ---------------- channel-last BN stat reduction (conv0 output + deconv1 output) ----------------
template <int C>
__global__ void stat_reduce_t(const unsigned short* __restrict__ x, int total4,
                              float* __restrict__ ssum, float* __restrict__ ssq, int statoff) {
    __shared__ float ls[C], lq[C];
    for (int c = threadIdx.x; c < C; c += 256) { ls[c] = 0.f; lq[c] = 0.f; }
    __syncthreads();
    int i0 = blockIdx.x * 256 + threadIdx.x;
    int stride = gridDim.x * 256;
    int c0 = (i0 << 2) & (C - 1);
    float s0 = 0, s1 = 0, s2 = 0, s3 = 0, q0 = 0, q1 = 0, q2 = 0, q3 = 0;
    for (int i = i0; i < total4; i += stride) {
        ushort4 v = *(const ushort4*)(x + ((size_t)i << 2));
        float f0 = bf2f_raw(v.x), f1 = bf2f_raw(v.y), f2 = bf2f_raw(v.z), f3 = bf2f_raw(v.w);
        s0 += f0; s1 += f1; s2 += f2; s3 += f3;
        q0 += f0 * f0; q1 += f1 * f1; q2 += f2 * f2; q3 += f3 * f3;
    }
    atomicAdd(&ls[c0], s0); atomicAdd(&ls[c0 + 1], s1); atomicAdd(&ls[c0 + 2], s2); atomicAdd(&ls[c0 + 3], s3);
    atomicAdd(&lq[c0], q0); atomicAdd(&lq[c0 + 1], q1); atomicAdd(&lq[c0 + 2], q2); atomicAdd(&lq[c0 + 3], q3);
    __syncthreads();
    int slot = (blockIdx.x & (NREP - 1)) * 576;
    for (int c = threadIdx.x; c < C; c += 256) {
        atomicAdd(&ssum[slot + statoff + c], ls[c]);
        atomicAdd(&ssq[slot + statoff + c], lq[c]);
    }
}

// ---------------- BN finalize (sums NREP replicas) ----------------
__global__ void bn_fin_kernel(const float* __restrict__ ssum, const float* __restrict__ ssq,
                              const float* __restrict__ g, const float* __restrict__ be,
                              float* __restrict__ scale, float* __restrict__ shift,
                              int statoff, int C, float invN) {
    int c = threadIdx.x;
    if (c >= C) return;
    float s = 0.f, q = 0.f;
#pragma unroll
    for (int r = 0; r < NREP; ++r) {
        s += ssum[r * 576 + statoff + c];
        q += ssq[r * 576 + statoff + c];
    }
    float m = s * invN;
    float v = q * invN - m * m;
    v = fmaxf(v, 0.f);
    float sc = g[c] * rsqrtf(v + 1e-5f);
    scale[statoff + c] = sc;
    shift[statoff + c] = be[c] - m * sc;
}

extern "C" void kernel_launch(void* const* d_in, const int* in_sizes, int n_in,
                              void* d_out, int out_size, void* d_ws, size_t ws_size,
                              hipStream_t stream) {
    if (ws_size < WS_NEED_BYTES) {
        hipMemsetAsync(d_out, 0, (size_t)out_size * 4, stream);
        return;
    }

    float* W = (float*)d_ws;
    unsigned short* U = (unsigned short*)d_ws;
    int* FLG = (int*)(W + OFF_FLAG);

    detect_kernel<<<1, 256, 0, stream>>>((const unsigned short*)d_in[2], FLG);

    CvtJobs J;
    const int srcIdx[16] = {10, 28, 11, 12, 13, 15, 16, 17, 19, 21, 22, 23, 25, 26, 27, 29};
    const int cnt[16]    = {3072, 6144, 64, 64, 64, 128, 128, 128, 64, 256, 256, 256, 128, 128, 128, 3};
    float* dsts[16] = {W + OFF_WC0, W + OFF_WG2,
                       W + OFF_CB0, W + OFF_CG0, W + OFF_CBE0, W + OFF_CB1, W + OFF_CG1, W + OFF_CBE1,
                       W + OFF_CB2, W + OFF_GB0, W + OFF_GG0, W + OFF_GBE0, W + OFF_GB1, W + OFF_GG1,
                       W + OFF_GBE1, W + OFF_GB2};
    int off = 0;
    for (int k = 0; k < 16; ++k) {
        J.src[k] = d_in[srcIdx[k]];
        J.dst[k] = dsts[k];
        J.off[k] = off;
        off += cnt[k];
    }
    J.off[16] = off;
    cvt_all_kernel<<<(off + 255) / 256, 256, 0, stream>>>(J, off, FLG);

    zero_kernel<<<(2 * NREP * 576 + 255) / 256, 256, 0, stream>>>(W + OFF_SSUM, 2 * NREP * 576);

    // weight packs
    pack_w2_kernel<<<3072, 256, 0, stream>>>(d_in[20], U + UW0, 168, 192, 256, FLG);
    pack_w2_kernel<<<2048, 256, 0, stream>>>(d_in[24], U + UW1, 256, 256, 128, FLG);
    pack_wc_kernel<<<512, 256, 0, stream>>>(d_in[14], U + UWC1, 64, 128, FLG);
    pack_wc_kernel<<<512, 256, 0, stream>>>(d_in[18], U + UWC2, 128, 64, FLG);
    pack_w2s_kernel<<<128, 256, 0, stream>>>(d_in[28], U + UW2, 128, 3, FLG);

    mlp_kernel<<<64, 64, 0, stream>>>(d_in[1], d_in[4], d_in[5], d_in[6], d_in[7],
                                      d_in[8], d_in[9], W + OFF_K12, FLG);

    // ---- conv0 -> X_s2d (raw) ----
    conv0_s2d_kernel<<<dim3(16, 1, 64), 256, 0, stream>>>(d_in[2], W + OFF_WC0, W + OFF_CB0,
                                                          U + UXT, FLG);
    stat_reduce_t<64><<<1024, 256, 0, stream>>>(U + UXT, 4194304, W + OFF_SSUM, W + OFF_SSQ, 0);
    bn_fin_kernel<<<1, 256, 0, stream>>>(W + OFF_SSUM, W + OFF_SSQ, W + OFF_CG0, W + OFF_CBE0,
                                         W + OFF_SCALE, W + OFF_SHIFT, 0, 64, 1.f / 262144.f);

    // ---- conv1 (MFMA, fused L0 BN, fused L1 stats) -> Y_s2d ----
    conv1_mfma_kernel<<<2048, 256, 0, stream>>>(U + UXT, U + UWC1, W + OFF_CB1,
                                                W + OFF_SCALE + 0, W + OFF_SHIFT + 0,
                                                W + OFF_SSUM, W + OFF_SSQ, U + UYT);
    bn_fin_kernel<<<1, 256, 0, stream>>>(W + OFF_SSUM, W + OFF_SSQ, W + OFF_CG1, W + OFF_CBE1,
                                         W + OFF_SCALE, W + OFF_SHIFT, 64, 128, 1.f / 65536.f);

    // ---- conv2 (MFMA, fused L1 BN) + tanh -> Z_t[0:64) ----
    conv2_mfma_kernel<<<512, 256, 0, stream>>>(U + UYT, U + UWC2, W + OFF_CB2,
                                               W + OFF_SCALE + 64, W + OFF_SHIFT + 64, U + UZT);

    // ---- Z_t[64:192) incl. pad zeroing ----
    assemble_z<<<8192, 256, 0, stream>>>(d_in[0], d_in[1], d_in[3], W + OFF_K12, U + UZT, FLG);

    // ---- gen deconv0 (MFMA, fused G0 stats): Z_t -> X_t(32,32,256) ----
    deconv_mfma2_kernel<192, 16, 256, 2, false, true><<<2048, 256, 0, stream>>>(
        U + UZT, U + UW0, W + OFF_GB0, nullptr, nullptr,
        W + OFF_SSUM, W + OFF_SSQ, 192, U + UXT);
    bn_fin_kernel<<<1, 256, 0, stream>>>(W + OFF_SSUM, W + OFF_SSQ, W + OFF_GG0, W + OFF_GBE0,
                                         W + OFF_SCALE, W + OFF_SHIFT, 192, 256, 1.f / 65536.f);

    // ---- gen deconv1 (MFMA, fused G0 BN, NO fused stats): X_t -> Y_t(64,64,128) ----
    deconv_mfma2_kernel<256, 32, 128, 2, true, false><<<4096, 256, 0, stream>>>(
        U + UXT, U + UW1, W + OFF_GB1, W + OFF_SCALE + 192, W + OFF_SHIFT + 192,
        nullptr, nullptr, 0, U + UYT);
    // G1 stats via separate pass over Y_t (67 MB read)
    stat_reduce_t<128><<<1024, 256, 0, stream>>>(U + UYT, 8388608, W + OFF_SSUM, W + OFF_SSQ, 448);
    bn_fin_kernel<<<1, 256, 0, stream>>>(W + OFF_SSUM, W + OFF_SSQ, W + OFF_GG1, W + OFF_GBE1,
                                         W + OFF_SCALE, W + OFF_SHIFT, 448, 128, 1.f / 262144.f);

    // ---- gen deconv2 (MFMA, fused G1 BN) + tanh -> d_out fp32 ----
    deconv2_mfma_kernel<<<8192, 256, 0, stream>>>(U + UYT, U + UW2, W + OFF_GB2,
                                                  W + OFF_SCALE + 448, W + OFF_SHIFT + 448,
                                                  (float*)d_out);
}

// Round 11
// 589.164 us; speedup vs baseline: 1.2024x; 1.0224x over previous
//
#include <hip/hip_runtime.h>
#include <hip/hip_bf16.h>

#define TWO_PI_F 6.2831853071795864769f

typedef __attribute__((ext_vector_type(8))) __bf16 bf16x8;
typedef __attribute__((ext_vector_type(4))) float f32x4;

// 32-way replicated stat buffers: per-address global atomic chains drop 32x.
#define NREP 32

__device__ __forceinline__ float bf2f_raw(unsigned short u) {
    return __uint_as_float(((unsigned int)u) << 16);
}
__device__ __forceinline__ unsigned short f2bf(float f) {
    unsigned int u = __float_as_uint(f);
    unsigned int r = (u + 0x7FFFu + ((u >> 16) & 1u)) >> 16;   // RNE
    return (unsigned short)r;
}
__device__ __forceinline__ float loadIn(const void* p, size_t i, bool f32) {
    return f32 ? ((const float*)p)[i] : bf2f_raw(((const unsigned short*)p)[i]);
}

// Fused BN affine + (leaky)relu applied to 8 packed bf16 during staging.
__device__ __forceinline__ uint4 bn_fuse8(uint4 v, const float* __restrict__ sc,
                                          const float* __restrict__ sh, int c0, float slope) {
    unsigned short us[8];
    *(uint4*)us = v;
#pragma unroll
    for (int k = 0; k < 8; ++k) {
        float f = bf2f_raw(us[k]) * sc[c0 + k] + sh[c0 + k];
        f = f > 0.f ? f : slope * f;
        us[k] = f2bf(f);
    }
    return *(const uint4*)us;
}

// Reduce val across the 4 kq-groups of a wave (lanes differing in bits 4,5).
__device__ __forceinline__ float kq_reduce(float v) {
    v += __shfl_xor(v, 16, 64);
    v += __shfl_xor(v, 32, 64);
    return v;
}

// ---------------- ws layout ----------------
static constexpr size_t OFF_WC0 = 0;          // cod_w0 fp32 3072
static constexpr size_t OFF_WG2 = 3072;       // gen_w2 fp32 6144 (legacy, unused)
static constexpr size_t OFF_P   = 9216;
static constexpr size_t OFF_CB0 = OFF_P + 0;
static constexpr size_t OFF_CG0 = OFF_P + 64;
static constexpr size_t OFF_CBE0= OFF_P + 128;
static constexpr size_t OFF_CB1 = OFF_P + 192;
static constexpr size_t OFF_CG1 = OFF_P + 320;
static constexpr size_t OFF_CBE1= OFF_P + 448;
static constexpr size_t OFF_CB2 = OFF_P + 576;
static constexpr size_t OFF_GB0 = OFF_P + 640;
static constexpr size_t OFF_GG0 = OFF_P + 896;
static constexpr size_t OFF_GBE0= OFF_P + 1152;
static constexpr size_t OFF_GB1 = OFF_P + 1408;
static constexpr size_t OFF_GG1 = OFF_P + 1536;
static constexpr size_t OFF_GBE1= OFF_P + 1664;
static constexpr size_t OFF_GB2 = OFF_P + 1792;
static constexpr size_t OFF_SSUM  = OFF_P + 2048;              // NREP x 576
static constexpr size_t OFF_SSQ   = OFF_SSUM + NREP * 576;     // NREP x 576
static constexpr size_t OFF_SCALE = OFF_SSQ + NREP * 576;
static constexpr size_t OFF_SHIFT = OFF_SCALE + 576;
static constexpr size_t OFF_K12   = OFF_SHIFT + 576;
static constexpr size_t OFF_FLAG  = OFF_K12 + 1024;
static constexpr size_t FP32_END  = OFF_FLAG + 16;   // floats
// ushort regions:
static constexpr size_t UXT = 2 * FP32_END;            // X region: X_s2d (b,2,2,32,32,64) then X_t (b,32,32,256)
static constexpr size_t UYT = UXT + 16777216;          // Y region: Y_s2d head, then Y_t (b,64,64,128)
static constexpr size_t UZT = UYT + 8388608;           // Z_t (b,16,16,192)
static constexpr size_t UW0 = UYT + 33554432;          // deconv0 pack
static constexpr size_t UW1 = UW0 + 786432;            // deconv1 pack
static constexpr size_t UWC1 = UW1 + 524288;           // conv1 pack
static constexpr size_t UWC2 = UWC1 + 131072;          // conv2 pack
static constexpr size_t UW2 = UWC2 + 131072;           // deconv2 pack
static constexpr size_t WS_END_USHORT = UW2 + 32768;
static constexpr size_t WS_NEED_BYTES = WS_END_USHORT * 2;   // ~110 MB

// stat slots: L0:0(64) L1:64(128) G0:192(256) G1:448(128)

// ---------------- input dtype detection ----------------
__global__ void detect_kernel(const unsigned short* __restrict__ imgs, int* __restrict__ flag) {
    int t = threadIdx.x;  // 256
    unsigned short u = imgs[t];
    int e = (u >> 7) & 0xFF;
    unsigned long long b = __ballot(e >= 0xC0);
    __shared__ int cnt[4];
    if ((t & 63) == 0) cnt[t >> 6] = __popcll(b);
    __syncthreads();
    if (t == 0) flag[0] = (cnt[0] + cnt[1] + cnt[2] + cnt[3] >= 4) ? 1 : 0;
}

// ---------------- small param -> fp32 conversion ----------------
struct CvtJobs {
    const void* src[16];
    float* dst[16];
    int off[17];
};

__global__ void cvt_all_kernel(CvtJobs J, int total, const int* __restrict__ flg) {
    int i = blockIdx.x * 256 + threadIdx.x;
    if (i >= total) return;
    bool f32 = flg[0] != 0;
    int k = 0;
#pragma unroll
    for (int t = 0; t < 15; ++t) { if (i >= J.off[t + 1]) k = t + 1; }
    int r = i - J.off[k];
    J.dst[k][r] = loadIn(J.src[k], r, f32);
}

__global__ void zero_kernel(float* p, int n) {
    int i = blockIdx.x * 256 + threadIdx.x;
    if (i < n) p[i] = 0.f;
}

// ---------------- deconv weight packing ----------------
__global__ void pack_w2_kernel(const void* __restrict__ src, unsigned short* __restrict__ dst,
                               int ICreal, int ICP, int OC, const int* __restrict__ flg) {
    bool f32 = flg[0] != 0;
    int i = blockIdx.x * 256 + threadIdx.x;
    int total = 16 * OC * ICP;
    if (i >= total) return;
    int jj = i & 7;
    int lane = (i >> 3) & 63;
    int j = (i >> 9) & 3;
    int t3 = i >> 11;
    int NK = ICP / 32;
    int kc = t3 % NK;
    int t4 = t3 / NK;
    int NOCT = OC / 64;
    int oct = t4 % NOCT;
    int ktap = t4 / NOCT;
    int kq = lane >> 4, n = lane & 15;
    int ic = kc * 32 + kq * 8 + jj;
    int oc = oct * 64 + n * 4 + j;          // channel-interleaved
    unsigned short v = 0;
    if (ic < ICreal) v = f2bf(loadIn(src, ((size_t)(ic * OC + oc) << 4) + ktap, f32));
    dst[i] = v;
}

__global__ void pack_w2s_kernel(const void* __restrict__ src, unsigned short* __restrict__ dst,
                                int ICP, int OCreal, const int* __restrict__ flg) {
    bool f32 = flg[0] != 0;
    int i = blockIdx.x * 256 + threadIdx.x;
    int NK = ICP / 32;
    int total = 16 * NK * 512;
    if (i >= total) return;
    int jj = i & 7;
    int lane = (i >> 3) & 63;
    int t3 = i >> 9;
    int kc = t3 % NK;
    int ktap = t3 / NK;
    int kq = lane >> 4, n = lane & 15;
    int ic = kc * 32 + kq * 8 + jj;
    unsigned short v = 0;
    if (n < OCreal) v = f2bf(loadIn(src, ((size_t)(ic * OCreal + n) << 4) + ktap, f32));
    dst[i] = v;
}

__global__ void pack_wc_kernel(const void* __restrict__ src, unsigned short* __restrict__ dst,
                               int IC, int OC, const int* __restrict__ flg) {
    bool f32 = flg[0] != 0;
    int i = blockIdx.x * 256 + threadIdx.x;
    int total = 16 * OC * IC;
    if (i >= total) return;
    int jj = i & 7;
    int lane = (i >> 3) & 63;
    int j = (i >> 9) & 3;
    int t3 = i >> 11;
    int NK = IC / 32;
    int kc = t3 % NK;
    int t4 = t3 / NK;
    int NOCT = OC / 64;
    int oct = t4 % NOCT;
    int ktap = t4 / NOCT;
    int kq = lane >> 4, n = lane & 15;
    int ic = kc * 32 + kq * 8 + jj;
    int oc = oct * 64 + j * 16 + n;
    dst[i] = f2bf(loadIn(src, ((size_t)(oc * IC + ic) << 4) + ktap, f32));
}

// ---------------- tiny MLP ----------------
__global__ void mlp_kernel(const void* __restrict__ Zg,
                           const void* __restrict__ lW, const void* __restrict__ lb,
                           const void* __restrict__ l1W, const void* __restrict__ l1b,
                           const void* __restrict__ l2W, const void* __restrict__ l2b,
                           float* __restrict__ K12, const int* __restrict__ flg) {
    bool f32 = flg[0] != 0;
    int b = blockIdx.x;
    int t = threadIdx.x;  // 64
    __shared__ float xs[64];
    float acc = loadIn(lb, t, f32);
    for (int c = 0; c < 64; ++c)
        acc += loadIn(Zg, (size_t)(b * 64 + c) * 256, f32) * loadIn(lW, t * 64 + c, f32);
    xs[t] = fmaxf(acc, 0.f);
    __syncthreads();
    if (t < 16) {
        int p = t & 7;
        const void* Wp = (t < 8) ? l1W : l2W;
        const void* bp = (t < 8) ? l1b : l2b;
        float a = loadIn(bp, p, f32);
        for (int h = 0; h < 64; ++h) a += xs[h] * loadIn(Wp, p * 64 + h, f32);
        K12[b * 16 + t] = a;
    }
}

// ---------------- conv0: imgs -> X_s2d ----------------
__global__ void conv0_s2d_kernel(const void* __restrict__ imgs, const float* __restrict__ w,
                                 const float* __restrict__ bias, unsigned short* __restrict__ xs,
                                 const int* __restrict__ flg) {
    bool f32 = flg[0] != 0;
    int b = blockIdx.z;
    int tile = blockIdx.x;
    int Y0 = (tile >> 2) * 16, X0 = (tile & 3) * 16;
    __shared__ float vin[3 * 34 * 35];
    __shared__ float wl[64 * 49];
    for (int i = threadIdx.x; i < 3 * 34 * 34; i += 256) {
        int c = i % 34; int t = i / 34; int r = t % 34; int ic = t / 34;
        int iy = 2 * Y0 - 1 + r, ix = 2 * X0 - 1 + c;
        float v = 0.f;
        if (((unsigned)iy < 128u) & ((unsigned)ix < 128u))
            v = loadIn(imgs, ((size_t)(b * 3 + ic) * 128 + iy) * 128 + ix, f32);
        vin[(ic * 34 + r) * 35 + c] = v;
    }
    for (int i = threadIdx.x; i < 3072; i += 256) {
        int oc = i / 48, idx = i % 48;
        wl[oc * 49 + idx] = w[i];
    }
    __syncthreads();
    int q = threadIdx.x >> 2;
    int ocq = threadIdx.x & 3;
    int qy = q >> 3, qx = q & 7;
    float acc[4][16];
#pragma unroll
    for (int p = 0; p < 4; ++p)
#pragma unroll
        for (int o = 0; o < 16; ++o) acc[p][o] = 0.f;
    for (int ic = 0; ic < 3; ++ic) {
        float v[6][6];
#pragma unroll
        for (int r = 0; r < 6; ++r)
#pragma unroll
            for (int c = 0; c < 6; ++c)
                v[r][c] = vin[(ic * 34 + 4 * qy + r) * 35 + 4 * qx + c];
#pragma unroll
        for (int o = 0; o < 16; ++o) {
            const float* wo = wl + (ocq * 16 + o) * 49 + ic * 16;
#pragma unroll
            for (int ky = 0; ky < 4; ++ky)
#pragma unroll
                for (int kx = 0; kx < 4; ++kx) {
                    float wv = wo[ky * 4 + kx];
                    acc[0][o] = fmaf(v[ky][kx], wv, acc[0][o]);
                    acc[1][o] = fmaf(v[ky][kx + 2], wv, acc[1][o]);
                    acc[2][o] = fmaf(v[ky + 2][kx], wv, acc[2][o]);
                    acc[3][o] = fmaf(v[ky + 2][kx + 2], wv, acc[3][o]);
                }
        }
    }
    int j = (Y0 >> 1) + qy, i2 = (X0 >> 1) + qx;
#pragma unroll
    for (int p = 0; p < 4; ++p) {
        int dy = p >> 1, dx = p & 1;
        unsigned short tmp[16];
#pragma unroll
        for (int o = 0; o < 16; ++o) tmp[o] = f2bf(acc[p][o] + bias[ocq * 16 + o]);
        unsigned short* dst = xs + (((size_t)((b * 2 + dy) * 2 + dx) * 32 + j) * 32 + i2) * 64 + ocq * 16;
        *(uint4*)(dst) = *(const uint4*)(tmp);
        *(uint4*)(dst + 8) = *(const uint4*)(tmp + 8);
    }
}

// ---------------- conv1 (MFMA, fused L0 BN on load, fused L1 stats, atomic-free in-block reduce) ----------------
__global__ void conv1_mfma_kernel(const unsigned short* __restrict__ xs,
                                  const unsigned short* __restrict__ wp,
                                  const float* __restrict__ bias,
                                  const float* __restrict__ sc, const float* __restrict__ sh,
                                  float* __restrict__ gsum, float* __restrict__ gsq,
                                  unsigned short* __restrict__ ys) {
    constexpr int STR = 72;
    __shared__ unsigned short lds[4 * 3 * 17 * STR];   // 29.4 KB
    __shared__ float ws[4][64], wq[4][64];
    int bid = blockIdx.x;
    int slot = (bid & (NREP - 1)) * 576;
    int xt = bid & 1;
    int qp = (bid >> 1) & 15;
    int b = bid >> 5;
    int oy0 = qp * 2, x0 = xt * 16;
    for (int i = threadIdx.x; i < 1632; i += 256) {
        int icc = i & 7; int t = i >> 3;
        int col = t % 17; int rc = t / 17;
        int row = rc % 3; int pl = rc / 3;
        int py = pl >> 1, px = pl & 1;
        int j = oy0 - py + row;
        int ci = x0 - px + col;
        uint4 v = {0u, 0u, 0u, 0u};
        if (((unsigned)j < 32u) & ((unsigned)ci < 32u)) {
            v = *(const uint4*)(xs + ((size_t)((b * 4 + pl) * 32 + j) * 32 + ci) * 64 + icc * 8);
            v = bn_fuse8(v, sc, sh, icc * 8, 0.2f);
        }
        *(uint4*)(lds + ((pl * 3 + row) * 17 + col) * STR + icc * 8) = v;
    }
    __syncthreads();

    int wv = threadIdx.x >> 6, lane = threadIdx.x & 63;
    int r = wv >> 1, oct = wv & 1;
    int m = lane & 15, kq = lane >> 4;
    f32x4 acc[4];
#pragma unroll
    for (int j = 0; j < 4; ++j) acc[j] = (f32x4){0.f, 0.f, 0.f, 0.f};

#pragma unroll
    for (int ky = 0; ky < 4; ++ky) {
        int py = (ky & 1) ^ 1;
        int lrow = r + (ky >> 1);
#pragma unroll
        for (int kx = 0; kx < 4; ++kx) {
            int px = (kx & 1) ^ 1;
            int pl = py * 2 + px;
            int lcol = m + (kx >> 1);
            const unsigned short* lp = lds + ((pl * 3 + lrow) * 17 + lcol) * STR + kq * 8;
            int ktap = ky * 4 + kx;
            const unsigned short* bb = wp + (size_t)(ktap * 2 + oct) * 4096;
#pragma unroll
            for (int kc = 0; kc < 2; ++kc) {
                bf16x8 a = *(const bf16x8*)(lp + kc * 32);
                const unsigned short* bk = bb + kc * 2048 + lane * 8;
                bf16x8 b0 = *(const bf16x8*)(bk);
                bf16x8 b1 = *(const bf16x8*)(bk + 512);
                bf16x8 b2 = *(const bf16x8*)(bk + 1024);
                bf16x8 b3 = *(const bf16x8*)(bk + 1536);
                acc[0] = __builtin_amdgcn_mfma_f32_16x16x32_bf16(a, b0, acc[0], 0, 0, 0);
                acc[1] = __builtin_amdgcn_mfma_f32_16x16x32_bf16(a, b1, acc[1], 0, 0, 0);
                acc[2] = __builtin_amdgcn_mfma_f32_16x16x32_bf16(a, b2, acc[2], 0, 0, 0);
                acc[3] = __builtin_amdgcn_mfma_f32_16x16x32_bf16(a, b3, acc[3], 0, 0, 0);
            }
        }
    }
    int oy = oy0 + r;
    int pyo = oy & 1, jo = oy >> 1;
    int n = m;
    float bv0 = bias[oct * 64 + n], bv1 = bias[oct * 64 + 16 + n];
    float bv2 = bias[oct * 64 + 32 + n], bv3 = bias[oct * 64 + 48 + n];
    float s0 = 0, s1 = 0, s2 = 0, s3 = 0, q0 = 0, q1 = 0, q2 = 0, q3 = 0;
#pragma unroll
    for (int reg = 0; reg < 4; ++reg) {
        int mm = kq * 4 + reg;
        int ox = x0 + mm;
        int pxo = ox & 1, io = ox >> 1;
        size_t base = (((size_t)((b * 2 + pyo) * 2 + pxo) * 16 + jo) * 16 + io) * 128 + oct * 64 + n;
        float v0 = acc[0][reg] + bv0, v1 = acc[1][reg] + bv1;
        float v2 = acc[2][reg] + bv2, v3 = acc[3][reg] + bv3;
        s0 += v0; q0 += v0 * v0; s1 += v1; q1 += v1 * v1;
        s2 += v2; q2 += v2 * v2; s3 += v3; q3 += v3 * v3;
        ys[base]      = f2bf(v0);
        ys[base + 16] = f2bf(v1);
        ys[base + 32] = f2bf(v2);
        ys[base + 48] = f2bf(v3);
    }
    // wave-level kq reduction (no atomics)
    s0 = kq_reduce(s0); q0 = kq_reduce(q0);
    s1 = kq_reduce(s1); q1 = kq_reduce(q1);
    s2 = kq_reduce(s2); q2 = kq_reduce(q2);
    s3 = kq_reduce(s3); q3 = kq_reduce(q3);
    if (lane < 16) {
        ws[wv][0 * 16 + n] = s0; wq[wv][0 * 16 + n] = q0;
        ws[wv][1 * 16 + n] = s1; wq[wv][1 * 16 + n] = q1;
        ws[wv][2 * 16 + n] = s2; wq[wv][2 * 16 + n] = q2;
        ws[wv][3 * 16 + n] = s3; wq[wv][3 * 16 + n] = q3;
    }
    __syncthreads();
    if (threadIdx.x < 128) {
        int c = threadIdx.x;
        int o = c >> 6, rr = c & 63;          // waves {o, o+2} cover oct o
        float s = ws[o][rr] + ws[o + 2][rr];
        float q = wq[o][rr] + wq[o + 2][rr];
        atomicAdd(&gsum[slot + 64 + c], s);
        atomicAdd(&gsq[slot + 64 + c], q);
    }
}

// ---------------- conv2 (MFMA, fused L1 BN on load) + tanh: Y_s2d -> Z_t[0:64) ----------------
__global__ void conv2_mfma_kernel(const unsigned short* __restrict__ ys,
                                  const unsigned short* __restrict__ wp,
                                  const float* __restrict__ bias,
                                  const float* __restrict__ sc, const float* __restrict__ sh,
                                  unsigned short* __restrict__ zt) {
    constexpr int STR = 136;
    __shared__ unsigned short lds[4 * 3 * 17 * STR];   // 55.5 KB
    int bid = blockIdx.x;
    int qp = bid & 7;
    int b = bid >> 3;
    int oy0 = qp * 2;
    for (int i = threadIdx.x; i < 3264; i += 256) {
        int icc = i & 15; int t = i >> 4;
        int col = t % 17; int rc = t / 17;
        int row = rc % 3; int pl = rc / 3;
        int py = pl >> 1, px = pl & 1;
        int j = oy0 - py + row;
        int ci = col - px;
        uint4 v = {0u, 0u, 0u, 0u};
        if (((unsigned)j < 16u) & ((unsigned)ci < 16u)) {
            v = *(const uint4*)(ys + ((size_t)((b * 4 + pl) * 16 + j) * 16 + ci) * 128 + icc * 8);
            v = bn_fuse8(v, sc, sh, icc * 8, 0.2f);
        }
        *(uint4*)(lds + ((pl * 3 + row) * 17 + col) * STR + icc * 8) = v;
    }
    __syncthreads();

    int wv = threadIdx.x >> 6, lane = threadIdx.x & 63;
    int r = wv >> 1, jh = wv & 1;
    int m = lane & 15, kq = lane >> 4;
    f32x4 acc[2];
    acc[0] = (f32x4){0.f, 0.f, 0.f, 0.f};
    acc[1] = acc[0];
#pragma unroll
    for (int ky = 0; ky < 4; ++ky) {
        int py = (ky & 1) ^ 1;
        int lrow = r + (ky >> 1);
#pragma unroll
        for (int kx = 0; kx < 4; ++kx) {
            int px = (kx & 1) ^ 1;
            int pl = py * 2 + px;
            int lcol = m + (kx >> 1);
            const unsigned short* lp = lds + ((pl * 3 + lrow) * 17 + lcol) * STR + kq * 8;
            int ktap = ky * 4 + kx;
            const unsigned short* bb = wp + (size_t)ktap * 8192;
#pragma unroll
            for (int kc = 0; kc < 4; ++kc) {
                bf16x8 a = *(const bf16x8*)(lp + kc * 32);
                const unsigned short* bk = bb + kc * 2048 + (jh * 2) * 512 + lane * 8;
                bf16x8 b0 = *(const bf16x8*)(bk);
                bf16x8 b1 = *(const bf16x8*)(bk + 512);
                acc[0] = __builtin_amdgcn_mfma_f32_16x16x32_bf16(a, b0, acc[0], 0, 0, 0);
                acc[1] = __builtin_amdgcn_mfma_f32_16x16x32_bf16(a, b1, acc[1], 0, 0, 0);
            }
        }
    }
    int oy = oy0 + r;
    int n = m;
    float bv0 = bias[(jh * 2) * 16 + n], bv1 = bias[(jh * 2 + 1) * 16 + n];
#pragma unroll
    for (int reg = 0; reg < 4; ++reg) {
        int x = kq * 4 + reg;
        size_t base = ((size_t)(b * 16 + oy) * 16 + x) * 192 + (jh * 2) * 16 + n;
        zt[base]      = f2bf(tanhf(acc[0][reg] + bv0));
        zt[base + 16] = f2bf(tanhf(acc[1][reg] + bv1));
    }
}

// ---------------- assemble Z_t[...][64:192): Zl, Zg, wave, and pad channels ----------------
__global__ void assemble_z(const void* __restrict__ Zl, const void* __restrict__ Zg,
                           const void* __restrict__ phi, const float* __restrict__ K12,
                           unsigned short* __restrict__ zt, const int* __restrict__ flg) {
    bool f32 = flg[0] != 0;
    int i = blockIdx.x * 256 + threadIdx.x;
    const int TOT = 64 * 128 * 256;
    if (i >= TOT) return;
    int pos = i & 255;
    int t = i >> 8;
    int c128 = t % 128;
    int b = t / 128;
    float val;
    if (c128 < 32) {
        val = loadIn(Zl, ((size_t)(b * 32 + c128) << 8) + pos, f32);
    } else if (c128 < 96) {
        val = loadIn(Zg, ((size_t)(b * 64 + (c128 - 32)) << 8) + pos, f32);
    } else if (c128 < 104) {
        int p = c128 - 96;
        int y = pos >> 4, x = pos & 15;
        float k1 = K12[b * 16 + p];
        float k2 = K12[b * 16 + 8 + p];
        val = sinf(k1 * (float)y + k2 * (float)x + loadIn(phi, b * 8 + p, f32) * TWO_PI_F);
    } else {
        val = 0.f;      // pad channels 168..192 of Z_t
    }
    zt[((size_t)(b * 256 + pos)) * 192 + 64 + c128] = f2bf(val);
}

// ---------------- MFMA transposed-conv v11: QR rows/block, oct slowest, fused BN-in, optional stats ----------------
// QR=4 for deconv1 (BN-fuse VALU amortization: 1.5 halo-rows/output vs 2.0 at QR=2; r4 measured 118.7us).
template <int ICP, int Q, int OC, int QR, bool BN, bool ST>
__global__ __launch_bounds__(256, 2)
void deconv_mfma2_kernel(const unsigned short* __restrict__ in_t,
                         const unsigned short* __restrict__ wp2,
                         const float* __restrict__ bias,
                         const float* __restrict__ sc, const float* __restrict__ sh,
                         float* __restrict__ gsum, float* __restrict__ gsq, int statoff,
                         unsigned short* __restrict__ out_t) {
    constexpr int NOCT = OC / 64;
    constexpr int NK = ICP / 32;
    constexpr int XT = Q / 16;
    constexpr int NQB = Q / QR;
    constexpr int ROWS = QR + 2;
    constexpr int STRIDE = ICP + 8;
    constexpr int NTILES = XT * NQB * 64;
    __shared__ unsigned short lds[ROWS * 18 * STRIDE];
    __shared__ float ws[ST ? 4 : 1][64], wq[ST ? 4 : 1][64];

    int bid = blockIdx.x;
    int slot = (bid & (NREP - 1)) * 576;
    int oct = bid / NTILES;          // slowest dim
    bid -= oct * NTILES;
    int xt = bid % XT;
    int t2 = bid / XT;
    int qp = t2 % NQB;
    int b = t2 / NQB;
    int qy0 = qp * QR;
    int x0 = xt * 16;

    constexpr int P8 = ICP / 8;
    constexpr int E8 = ROWS * 18 * P8;
    for (int i = threadIdx.x; i < E8; i += 256) {
        int icc = i % P8;
        int rc = i / P8;
        int row = rc / 18, col = rc % 18;
        int y = qy0 - 1 + row, x = x0 - 1 + col;
        uint4 val = {0u, 0u, 0u, 0u};
        if (((unsigned)y < (unsigned)Q) & ((unsigned)x < (unsigned)Q)) {
            val = *(const uint4*)(in_t + (size_t)((b * Q + y) * Q + x) * ICP + icc * 8);
            if (BN) val = bn_fuse8(val, sc, sh, icc * 8, 0.f);
        }
        *(uint4*)(lds + rc * STRIDE + icc * 8) = val;
    }
    __syncthreads();

    int wv = threadIdx.x >> 6, lane = threadIdx.x & 63;
    int dy = wv >> 1, dx = wv & 1;
    int m = lane & 15, kq = lane >> 4;

    f32x4 acc[QR][4];
#pragma unroll
    for (int q = 0; q < QR; ++q)
#pragma unroll
        for (int j = 0; j < 4; ++j) acc[q][j] = (f32x4){0.f, 0.f, 0.f, 0.f};

#pragma unroll
    for (int t = 0; t < 4; ++t) {
        int rr = t >> 1, cc = t & 1;
        int ktap = ((3 - dy) - 2 * rr) * 4 + ((3 - dx) - 2 * cc);
        int col = m + dx + cc;
        int row0 = dy + rr;
        const unsigned short* bbase = wp2 + (size_t)((ktap * NOCT + oct) * NK) * 2048;
#pragma unroll
        for (int kc = 0; kc < NK; ++kc) {
            bf16x8 a[QR];
#pragma unroll
            for (int q = 0; q < QR; ++q)
                a[q] = *(const bf16x8*)(lds + ((row0 + q) * 18 + col) * STRIDE + kc * 32 + kq * 8);
            bf16x8 b0 = *(const bf16x8*)(bbase + (kc * 4 + 0) * 512 + lane * 8);
            bf16x8 b1 = *(const bf16x8*)(bbase + (kc * 4 + 1) * 512 + lane * 8);
            bf16x8 b2 = *(const bf16x8*)(bbase + (kc * 4 + 2) * 512 + lane * 8);
            bf16x8 b3 = *(const bf16x8*)(bbase + (kc * 4 + 3) * 512 + lane * 8);
#pragma unroll
            for (int q = 0; q < QR; ++q) {
                acc[q][0] = __builtin_amdgcn_mfma_f32_16x16x32_bf16(a[q], b0, acc[q][0], 0, 0, 0);
                acc[q][1] = __builtin_amdgcn_mfma_f32_16x16x32_bf16(a[q], b1, acc[q][1], 0, 0, 0);
                acc[q][2] = __builtin_amdgcn_mfma_f32_16x16x32_bf16(a[q], b2, acc[q][2], 0, 0, 0);
                acc[q][3] = __builtin_amdgcn_mfma_f32_16x16x32_bf16(a[q], b3, acc[q][3], 0, 0, 0);
            }
        }
    }
    // Epilogue: lane n holds channels oct*64 + 4n + j -> one contiguous ushort4 per (qyl,reg).
    int n = m;
    const float4 bv = *(const float4*)(bias + oct * 64 + 4 * n);
    float s0 = 0, s1 = 0, s2 = 0, s3 = 0, q0 = 0, q1 = 0, q2 = 0, q3 = 0;
#pragma unroll
    for (int qyl = 0; qyl < QR; ++qyl) {
        int oy = 2 * (qy0 + qyl) + dy;
#pragma unroll
        for (int reg = 0; reg < 4; ++reg) {
            int mm = kq * 4 + reg;
            int ox = 2 * (x0 + mm) + dx;
            size_t base = ((size_t)((b * 2 * Q + oy) * (2 * Q) + ox)) * OC + oct * 64 + 4 * n;
            float v0 = acc[qyl][0][reg] + bv.x;
            float v1 = acc[qyl][1][reg] + bv.y;
            float v2 = acc[qyl][2][reg] + bv.z;
            float v3 = acc[qyl][3][reg] + bv.w;
            if (ST) {
                s0 += v0; q0 += v0 * v0; s1 += v1; q1 += v1 * v1;
                s2 += v2; q2 += v2 * v2; s3 += v3; q3 += v3 * v3;
            }
            ushort4 tv;
            tv.x = f2bf(v0); tv.y = f2bf(v1); tv.z = f2bf(v2); tv.w = f2bf(v3);
            *(ushort4*)(out_t + base) = tv;
        }
    }
    if (ST) {
        // wave-level kq reduction (no LDS atomics)
        s0 = kq_reduce(s0); q0 = kq_reduce(q0);
        s1 = kq_reduce(s1); q1 = kq_reduce(q1);
        s2 = kq_reduce(s2); q2 = kq_reduce(q2);
        s3 = kq_reduce(s3); q3 = kq_reduce(q3);
        if (lane < 16) {
            ws[wv][4 * n + 0] = s0; wq[wv][4 * n + 0] = q0;
            ws[wv][4 * n + 1] = s1; wq[wv][4 * n + 1] = q1;
            ws[wv][4 * n + 2] = s2; wq[wv][4 * n + 2] = q2;
            ws[wv][4 * n + 3] = s3; wq[wv][4 * n + 3] = q3;
        }
        __syncthreads();
        if (threadIdx.x < 64) {
            int c = threadIdx.x;
            float s = ws[0][c] + ws[1][c] + ws[2][c] + ws[3][c];
            float q = wq[0][c] + wq[1][c] + wq[2][c] + wq[3][c];
            atomicAdd(&gsum[slot + statoff + oct * 64 + c], s);
            atomicAdd(&gsq[slot + statoff + oct * 64 + c], q);
        }
    }
}

// ---------------- deconv2 v2 (MFMA, QR=4, fused G1 BN+relu on load, OC=3 pad 16) + tanh -> fp32 NCHW ----------------
// QR 2->4: staged halo rows per output q-row 2.0x -> 1.5x (Y_t is 134 MB; cuts ~90 MB of L2/HBM reads
// and 25% of the BN-fuse VALU), grid 8192 -> 4096.
__global__ void deconv2_mfma_kernel(const unsigned short* __restrict__ yt,
                                    const unsigned short* __restrict__ wp,
                                    const float* __restrict__ bias,
                                    const float* __restrict__ sc, const float* __restrict__ sh,
                                    float* __restrict__ outp) {
    constexpr int Q = 64, ICP = 128, NK = 4, STRIDE = 136, QR = 4, ROWS = 6;
    __shared__ unsigned short lds[ROWS * 18 * STRIDE];   // 29.4 KB
    int bid = blockIdx.x;
    int xt = bid & 3;
    int t2 = bid >> 2;
    int qp = t2 & 15;
    int b = t2 >> 4;
    int qy0 = qp * QR, x0 = xt * 16;

    for (int i = threadIdx.x; i < ROWS * 18 * 16; i += 256) {
        int icc = i & 15;
        int rc = i >> 4;
        int row = rc / 18, col = rc % 18;
        int y = qy0 - 1 + row, x = x0 - 1 + col;
        uint4 v = {0u, 0u, 0u, 0u};
        if (((unsigned)y < (unsigned)Q) & ((unsigned)x < (unsigned)Q)) {
            v = *(const uint4*)(yt + (size_t)((b * Q + y) * Q + x) * ICP + icc * 8);
            v = bn_fuse8(v, sc, sh, icc * 8, 0.f);
        }
        *(uint4*)(lds + rc * STRIDE + icc * 8) = v;
    }
    __syncthreads();

    int wv = threadIdx.x >> 6, lane = threadIdx.x & 63;
    int dy = wv >> 1, dx = wv & 1;
    int m = lane & 15, kq = lane >> 4;
    f32x4 acc[QR];
#pragma unroll
    for (int q = 0; q < QR; ++q) acc[q] = (f32x4){0.f, 0.f, 0.f, 0.f};

#pragma unroll
    for (int t = 0; t < 4; ++t) {
        int rr = t >> 1, cc = t & 1;
        int ktap = ((3 - dy) - 2 * rr) * 4 + ((3 - dx) - 2 * cc);
        int col = m + dx + cc;
        int row0 = dy + rr;
        const unsigned short* bb = wp + (size_t)(ktap * NK) * 512;
#pragma unroll
        for (int kc = 0; kc < NK; ++kc) {
            bf16x8 a[QR];
#pragma unroll
            for (int q = 0; q < QR; ++q)
                a[q] = *(const bf16x8*)(lds + ((row0 + q) * 18 + col) * STRIDE + kc * 32 + kq * 8);
            bf16x8 b0 = *(const bf16x8*)(bb + kc * 512 + lane * 8);
#pragma unroll
            for (int q = 0; q < QR; ++q)
                acc[q] = __builtin_amdgcn_mfma_f32_16x16x32_bf16(a[q], b0, acc[q], 0, 0, 0);
        }
    }
    int n = m;
    if (n < 3) {
        float bv = bias[n];
#pragma unroll
        for (int qyl = 0; qyl < QR; ++qyl) {
            int oy = 2 * (qy0 + qyl) + dy;
#pragma unroll
            for (int reg = 0; reg < 4; ++reg) {
                int mm = kq * 4 + reg;
                int ox = 2 * (x0 + mm) + dx;
                size_t ob = (size_t)(b * 3 + n) * 16384;
                outp[ob + (size_t)oy * 128 + ox] = tanhf(acc[qyl][reg] + bv);
            }
        }
    }
}

// ---------------- channel-last BN stat reduction (conv0 output + deconv1 output) ----------------
template <int C>
__global__ void stat_reduce_t(const unsigned short* __restrict__ x, int total4,
                              float* __restrict__ ssum, float* __restrict__ ssq, int statoff) {
    __shared__ float ls[C], lq[C];
    for (int c = threadIdx.x; c < C; c += 256) { ls[c] = 0.f; lq[c] = 0.f; }
    __syncthreads();
    int i0 = blockIdx.x * 256 + threadIdx.x;
    int stride = gridDim.x * 256;
    int c0 = (i0 << 2) & (C - 1);
    float s0 = 0, s1 = 0, s2 = 0, s3 = 0, q0 = 0, q1 = 0, q2 = 0, q3 = 0;
    for (int i = i0; i < total4; i += stride) {
        ushort4 v = *(const ushort4*)(x + ((size_t)i << 2));
        float f0 = bf2f_raw(v.x), f1 = bf2f_raw(v.y), f2 = bf2f_raw(v.z), f3 = bf2f_raw(v.w);
        s0 += f0; s1 += f1; s2 += f2; s3 += f3;
        q0 += f0 * f0; q1 += f1 * f1; q2 += f2 * f2; q3 += f3 * f3;
    }
    atomicAdd(&ls[c0], s0); atomicAdd(&ls[c0 + 1], s1); atomicAdd(&ls[c0 + 2], s2); atomicAdd(&ls[c0 + 3], s3);
    atomicAdd(&lq[c0], q0); atomicAdd(&lq[c0 + 1], q1); atomicAdd(&lq[c0 + 2], q2); atomicAdd(&lq[c0 + 3], q3);
    __syncthreads();
    int slot = (blockIdx.x & (NREP - 1)) * 576;
    for (int c = threadIdx.x; c < C; c += 256) {
        atomicAdd(&ssum[slot + statoff + c], ls[c]);
        atomicAdd(&ssq[slot + statoff + c], lq[c]);
    }
}

// ---------------- BN finalize (sums NREP replicas) ----------------
__global__ void bn_fin_kernel(const float* __restrict__ ssum, const float* __restrict__ ssq,
                              const float* __restrict__ g, const float* __restrict__ be,
                              float* __restrict__ scale, float* __restrict__ shift,
                              int statoff, int C, float invN) {
    int c = threadIdx.x;
    if (c >= C) return;
    float s = 0.f, q = 0.f;
#pragma unroll
    for (int r = 0; r < NREP; ++r) {
        s += ssum[r * 576 + statoff + c];
        q += ssq[r * 576 + statoff + c];
    }
    float m = s * invN;
    float v = q * invN - m * m;
    v = fmaxf(v, 0.f);
    float sc = g[c] * rsqrtf(v + 1e-5f);
    scale[statoff + c] = sc;
    shift[statoff + c] = be[c] - m * sc;
}

extern "C" void kernel_launch(void* const* d_in, const int* in_sizes, int n_in,
                              void* d_out, int out_size, void* d_ws, size_t ws_size,
                              hipStream_t stream) {
    if (ws_size < WS_NEED_BYTES) {
        hipMemsetAsync(d_out, 0, (size_t)out_size * 4, stream);
        return;
    }

    float* W = (float*)d_ws;
    unsigned short* U = (unsigned short*)d_ws;
    int* FLG = (int*)(W + OFF_FLAG);

    detect_kernel<<<1, 256, 0, stream>>>((const unsigned short*)d_in[2], FLG);

    CvtJobs J;
    const int srcIdx[16] = {10, 28, 11, 12, 13, 15, 16, 17, 19, 21, 22, 23, 25, 26, 27, 29};
    const int cnt[16]    = {3072, 6144, 64, 64, 64, 128, 128, 128, 64, 256, 256, 256, 128, 128, 128, 3};
    float* dsts[16] = {W + OFF_WC0, W + OFF_WG2,
                       W + OFF_CB0, W + OFF_CG0, W + OFF_CBE0, W + OFF_CB1, W + OFF_CG1, W + OFF_CBE1,
                       W + OFF_CB2, W + OFF_GB0, W + OFF_GG0, W + OFF_GBE0, W + OFF_GB1, W + OFF_GG1,
                       W + OFF_GBE1, W + OFF_GB2};
    int off = 0;
    for (int k = 0; k < 16; ++k) {
        J.src[k] = d_in[srcIdx[k]];
        J.dst[k] = dsts[k];
        J.off[k] = off;
        off += cnt[k];
    }
    J.off[16] = off;
    cvt_all_kernel<<<(off + 255) / 256, 256, 0, stream>>>(J, off, FLG);

    zero_kernel<<<(2 * NREP * 576 + 255) / 256, 256, 0, stream>>>(W + OFF_SSUM, 2 * NREP * 576);

    // weight packs
    pack_w2_kernel<<<3072, 256, 0, stream>>>(d_in[20], U + UW0, 168, 192, 256, FLG);
    pack_w2_kernel<<<2048, 256, 0, stream>>>(d_in[24], U + UW1, 256, 256, 128, FLG);
    pack_wc_kernel<<<512, 256, 0, stream>>>(d_in[14], U + UWC1, 64, 128, FLG);
    pack_wc_kernel<<<512, 256, 0, stream>>>(d_in[18], U + UWC2, 128, 64, FLG);
    pack_w2s_kernel<<<128, 256, 0, stream>>>(d_in[28], U + UW2, 128, 3, FLG);

    mlp_kernel<<<64, 64, 0, stream>>>(d_in[1], d_in[4], d_in[5], d_in[6], d_in[7],
                                      d_in[8], d_in[9], W + OFF_K12, FLG);

    // ---- conv0 -> X_s2d (raw) ----
    conv0_s2d_kernel<<<dim3(16, 1, 64), 256, 0, stream>>>(d_in[2], W + OFF_WC0, W + OFF_CB0,
                                                          U + UXT, FLG);
    stat_reduce_t<64><<<1024, 256, 0, stream>>>(U + UXT, 4194304, W + OFF_SSUM, W + OFF_SSQ, 0);
    bn_fin_kernel<<<1, 256, 0, stream>>>(W + OFF_SSUM, W + OFF_SSQ, W + OFF_CG0, W + OFF_CBE0,
                                         W + OFF_SCALE, W + OFF_SHIFT, 0, 64, 1.f / 262144.f);

    // ---- conv1 (MFMA, fused L0 BN, fused L1 stats) -> Y_s2d ----
    conv1_mfma_kernel<<<2048, 256, 0, stream>>>(U + UXT, U + UWC1, W + OFF_CB1,
                                                W + OFF_SCALE + 0, W + OFF_SHIFT + 0,
                                                W + OFF_SSUM, W + OFF_SSQ, U + UYT);
    bn_fin_kernel<<<1, 256, 0, stream>>>(W + OFF_SSUM, W + OFF_SSQ, W + OFF_CG1, W + OFF_CBE1,
                                         W + OFF_SCALE, W + OFF_SHIFT, 64, 128, 1.f / 65536.f);

    // ---- conv2 (MFMA, fused L1 BN) + tanh -> Z_t[0:64) ----
    conv2_mfma_kernel<<<512, 256, 0, stream>>>(U + UYT, U + UWC2, W + OFF_CB2,
                                               W + OFF_SCALE + 64, W + OFF_SHIFT + 64, U + UZT);

    // ---- Z_t[64:192) incl. pad zeroing ----
    assemble_z<<<8192, 256, 0, stream>>>(d_in[0], d_in[1], d_in[3], W + OFF_K12, U + UZT, FLG);

    // ---- gen deconv0 (MFMA, fused G0 stats): Z_t -> X_t(32,32,256) ----
    deconv_mfma2_kernel<192, 16, 256, 2, false, true><<<2048, 256, 0, stream>>>(
        U + UZT, U + UW0, W + OFF_GB0, nullptr, nullptr,
        W + OFF_SSUM, W + OFF_SSQ, 192, U + UXT);
    bn_fin_kernel<<<1, 256, 0, stream>>>(W + OFF_SSUM, W + OFF_SSQ, W + OFF_GG0, W + OFF_GBE0,
                                         W + OFF_SCALE, W + OFF_SHIFT, 192, 256, 1.f / 65536.f);

    // ---- gen deconv1 (MFMA, QR=4, fused G0 BN, NO fused stats): X_t -> Y_t(64,64,128) ----
    // grid = NOCT(2) * XT(2) * NQB(8) * 64 = 2048
    deconv_mfma2_kernel<256, 32, 128, 4, true, false><<<2048, 256, 0, stream>>>(
        U + UXT, U + UW1, W + OFF_GB1, W + OFF_SCALE + 192, W + OFF_SHIFT + 192,
        nullptr, nullptr, 0, U + UYT);
    // G1 stats via separate pass over Y_t (67 MB read)
    stat_reduce_t<128><<<1024, 256, 0, stream>>>(U + UYT, 8388608, W + OFF_SSUM, W + OFF_SSQ, 448);
    bn_fin_kernel<<<1, 256, 0, stream>>>(W + OFF_SSUM, W + OFF_SSQ, W + OFF_GG1, W + OFF_GBE1,
                                         W + OFF_SCALE, W + OFF_SHIFT, 448, 128, 1.f / 262144.f);

    // ---- gen deconv2 (MFMA, QR=4, fused G1 BN) + tanh -> d_out fp32 ----  grid = 64*16*4 = 4096
    deconv2_mfma_kernel<<<4096, 256, 0, stream>>>(U + UYT, U + UW2, W + OFF_GB2,
                                                  W + OFF_SCALE + 448, W + OFF_SHIFT + 448,
                                                  (float*)d_out);
}

// Round 12
// 561.578 us; speedup vs baseline: 1.2615x; 1.0491x over previous
//
#include <hip/hip_runtime.h>
#include <hip/hip_bf16.h>

#define TWO_PI_F 6.2831853071795864769f

typedef __attribute__((ext_vector_type(8))) __bf16 bf16x8;
typedef __attribute__((ext_vector_type(4))) float f32x4;

// 32-way replicated stat buffers: per-address global atomic chains drop 32x.
#define NREP 32

__device__ __forceinline__ float bf2f_raw(unsigned short u) {
    return __uint_as_float(((unsigned int)u) << 16);
}
__device__ __forceinline__ unsigned short f2bf(float f) {
    unsigned int u = __float_as_uint(f);
    unsigned int r = (u + 0x7FFFu + ((u >> 16) & 1u)) >> 16;   // RNE
    return (unsigned short)r;
}
__device__ __forceinline__ float loadIn(const void* p, size_t i, bool f32) {
    return f32 ? ((const float*)p)[i] : bf2f_raw(((const unsigned short*)p)[i]);
}

// Fused BN affine + (leaky)relu applied to 8 packed bf16 during staging.
__device__ __forceinline__ uint4 bn_fuse8(uint4 v, const float* __restrict__ sc,
                                          const float* __restrict__ sh, int c0, float slope) {
    unsigned short us[8];
    *(uint4*)us = v;
#pragma unroll
    for (int k = 0; k < 8; ++k) {
        float f = bf2f_raw(us[k]) * sc[c0 + k] + sh[c0 + k];
        f = f > 0.f ? f : slope * f;
        us[k] = f2bf(f);
    }
    return *(const uint4*)us;
}

// Reduce val across the 4 kq-groups of a wave (lanes differing in bits 4,5).
__device__ __forceinline__ float kq_reduce(float v) {
    v += __shfl_xor(v, 16, 64);
    v += __shfl_xor(v, 32, 64);
    return v;
}

// ---------------- ws layout ----------------
static constexpr size_t OFF_WC0 = 0;          // cod_w0 fp32 3072
static constexpr size_t OFF_WG2 = 3072;       // gen_w2 fp32 6144 (legacy, unused)
static constexpr size_t OFF_P   = 9216;
static constexpr size_t OFF_CB0 = OFF_P + 0;
static constexpr size_t OFF_CG0 = OFF_P + 64;
static constexpr size_t OFF_CBE0= OFF_P + 128;
static constexpr size_t OFF_CB1 = OFF_P + 192;
static constexpr size_t OFF_CG1 = OFF_P + 320;
static constexpr size_t OFF_CBE1= OFF_P + 448;
static constexpr size_t OFF_CB2 = OFF_P + 576;
static constexpr size_t OFF_GB0 = OFF_P + 640;
static constexpr size_t OFF_GG0 = OFF_P + 896;
static constexpr size_t OFF_GBE0= OFF_P + 1152;
static constexpr size_t OFF_GB1 = OFF_P + 1408;
static constexpr size_t OFF_GG1 = OFF_P + 1536;
static constexpr size_t OFF_GBE1= OFF_P + 1664;
static constexpr size_t OFF_GB2 = OFF_P + 1792;
static constexpr size_t OFF_SSUM  = OFF_P + 2048;              // NREP x 576
static constexpr size_t OFF_SSQ   = OFF_SSUM + NREP * 576;     // NREP x 576
static constexpr size_t OFF_SCALE = OFF_SSQ + NREP * 576;
static constexpr size_t OFF_SHIFT = OFF_SCALE + 576;
static constexpr size_t OFF_K12   = OFF_SHIFT + 576;
static constexpr size_t OFF_FLAG  = OFF_K12 + 1024;
static constexpr size_t FP32_END  = OFF_FLAG + 16;   // floats
// ushort regions:
static constexpr size_t UXT = 2 * FP32_END;            // X region: X_s2d (b,2,2,32,32,64) then X_t (b,32,32,256)
static constexpr size_t UYT = UXT + 16777216;          // Y region: Y_s2d head, then Y_t (b,64,64,128)
static constexpr size_t UZT = UYT + 8388608;           // Z_t (b,16,16,192)
static constexpr size_t UW0 = UYT + 33554432;          // deconv0 pack
static constexpr size_t UW1 = UW0 + 786432;            // deconv1 pack
static constexpr size_t UWC1 = UW1 + 524288;           // conv1 pack
static constexpr size_t UWC2 = UWC1 + 131072;          // conv2 pack
static constexpr size_t UW2 = UWC2 + 131072;           // deconv2 pack
static constexpr size_t WS_END_USHORT = UW2 + 32768;
static constexpr size_t WS_NEED_BYTES = WS_END_USHORT * 2;   // ~110 MB

// stat slots: L0:0(64) L1:64(128) G0:192(256) G1:448(128)

// ---------------- input dtype detection ----------------
__global__ void detect_kernel(const unsigned short* __restrict__ imgs, int* __restrict__ flag) {
    int t = threadIdx.x;  // 256
    unsigned short u = imgs[t];
    int e = (u >> 7) & 0xFF;
    unsigned long long b = __ballot(e >= 0xC0);
    __shared__ int cnt[4];
    if ((t & 63) == 0) cnt[t >> 6] = __popcll(b);
    __syncthreads();
    if (t == 0) flag[0] = (cnt[0] + cnt[1] + cnt[2] + cnt[3] >= 4) ? 1 : 0;
}

// ---------------- small param -> fp32 conversion ----------------
struct CvtJobs {
    const void* src[16];
    float* dst[16];
    int off[17];
};

__global__ void cvt_all_kernel(CvtJobs J, int total, const int* __restrict__ flg) {
    int i = blockIdx.x * 256 + threadIdx.x;
    if (i >= total) return;
    bool f32 = flg[0] != 0;
    int k = 0;
#pragma unroll
    for (int t = 0; t < 15; ++t) { if (i >= J.off[t + 1]) k = t + 1; }
    int r = i - J.off[k];
    J.dst[k][r] = loadIn(J.src[k], r, f32);
}

__global__ void zero_kernel(float* p, int n) {
    int i = blockIdx.x * 256 + threadIdx.x;
    if (i < n) p[i] = 0.f;
}

// ---------------- deconv weight packing ----------------
__global__ void pack_w2_kernel(const void* __restrict__ src, unsigned short* __restrict__ dst,
                               int ICreal, int ICP, int OC, const int* __restrict__ flg) {
    bool f32 = flg[0] != 0;
    int i = blockIdx.x * 256 + threadIdx.x;
    int total = 16 * OC * ICP;
    if (i >= total) return;
    int jj = i & 7;
    int lane = (i >> 3) & 63;
    int j = (i >> 9) & 3;
    int t3 = i >> 11;
    int NK = ICP / 32;
    int kc = t3 % NK;
    int t4 = t3 / NK;
    int NOCT = OC / 64;
    int oct = t4 % NOCT;
    int ktap = t4 / NOCT;
    int kq = lane >> 4, n = lane & 15;
    int ic = kc * 32 + kq * 8 + jj;
    int oc = oct * 64 + n * 4 + j;          // channel-interleaved
    unsigned short v = 0;
    if (ic < ICreal) v = f2bf(loadIn(src, ((size_t)(ic * OC + oc) << 4) + ktap, f32));
    dst[i] = v;
}

__global__ void pack_w2s_kernel(const void* __restrict__ src, unsigned short* __restrict__ dst,
                                int ICP, int OCreal, const int* __restrict__ flg) {
    bool f32 = flg[0] != 0;
    int i = blockIdx.x * 256 + threadIdx.x;
    int NK = ICP / 32;
    int total = 16 * NK * 512;
    if (i >= total) return;
    int jj = i & 7;
    int lane = (i >> 3) & 63;
    int t3 = i >> 9;
    int kc = t3 % NK;
    int ktap = t3 / NK;
    int kq = lane >> 4, n = lane & 15;
    int ic = kc * 32 + kq * 8 + jj;
    unsigned short v = 0;
    if (n < OCreal) v = f2bf(loadIn(src, ((size_t)(ic * OCreal + n) << 4) + ktap, f32));
    dst[i] = v;
}

__global__ void pack_wc_kernel(const void* __restrict__ src, unsigned short* __restrict__ dst,
                               int IC, int OC, const int* __restrict__ flg) {
    bool f32 = flg[0] != 0;
    int i = blockIdx.x * 256 + threadIdx.x;
    int total = 16 * OC * IC;
    if (i >= total) return;
    int jj = i & 7;
    int lane = (i >> 3) & 63;
    int j = (i >> 9) & 3;
    int t3 = i >> 11;
    int NK = IC / 32;
    int kc = t3 % NK;
    int t4 = t3 / NK;
    int NOCT = OC / 64;
    int oct = t4 % NOCT;
    int ktap = t4 / NOCT;
    int kq = lane >> 4, n = lane & 15;
    int ic = kc * 32 + kq * 8 + jj;
    int oc = oct * 64 + j * 16 + n;
    dst[i] = f2bf(loadIn(src, ((size_t)(oc * IC + ic) << 4) + ktap, f32));
}

// ---------------- tiny MLP ----------------
__global__ void mlp_kernel(const void* __restrict__ Zg,
                           const void* __restrict__ lW, const void* __restrict__ lb,
                           const void* __restrict__ l1W, const void* __restrict__ l1b,
                           const void* __restrict__ l2W, const void* __restrict__ l2b,
                           float* __restrict__ K12, const int* __restrict__ flg) {
    bool f32 = flg[0] != 0;
    int b = blockIdx.x;
    int t = threadIdx.x;  // 64
    __shared__ float xs[64];
    float acc = loadIn(lb, t, f32);
    for (int c = 0; c < 64; ++c)
        acc += loadIn(Zg, (size_t)(b * 64 + c) * 256, f32) * loadIn(lW, t * 64 + c, f32);
    xs[t] = fmaxf(acc, 0.f);
    __syncthreads();
    if (t < 16) {
        int p = t & 7;
        const void* Wp = (t < 8) ? l1W : l2W;
        const void* bp = (t < 8) ? l1b : l2b;
        float a = loadIn(bp, p, f32);
        for (int h = 0; h < 64; ++h) a += xs[h] * loadIn(Wp, p * 64 + h, f32);
        K12[b * 16 + t] = a;
    }
}

// ---------------- conv0: imgs -> X_s2d ----------------
__global__ void conv0_s2d_kernel(const void* __restrict__ imgs, const float* __restrict__ w,
                                 const float* __restrict__ bias, unsigned short* __restrict__ xs,
                                 const int* __restrict__ flg) {
    bool f32 = flg[0] != 0;
    int b = blockIdx.z;
    int tile = blockIdx.x;
    int Y0 = (tile >> 2) * 16, X0 = (tile & 3) * 16;
    __shared__ float vin[3 * 34 * 35];
    __shared__ float wl[64 * 49];
    for (int i = threadIdx.x; i < 3 * 34 * 34; i += 256) {
        int c = i % 34; int t = i / 34; int r = t % 34; int ic = t / 34;
        int iy = 2 * Y0 - 1 + r, ix = 2 * X0 - 1 + c;
        float v = 0.f;
        if (((unsigned)iy < 128u) & ((unsigned)ix < 128u))
            v = loadIn(imgs, ((size_t)(b * 3 + ic) * 128 + iy) * 128 + ix, f32);
        vin[(ic * 34 + r) * 35 + c] = v;
    }
    for (int i = threadIdx.x; i < 3072; i += 256) {
        int oc = i / 48, idx = i % 48;
        wl[oc * 49 + idx] = w[i];
    }
    __syncthreads();
    int q = threadIdx.x >> 2;
    int ocq = threadIdx.x & 3;
    int qy = q >> 3, qx = q & 7;
    float acc[4][16];
#pragma unroll
    for (int p = 0; p < 4; ++p)
#pragma unroll
        for (int o = 0; o < 16; ++o) acc[p][o] = 0.f;
    for (int ic = 0; ic < 3; ++ic) {
        float v[6][6];
#pragma unroll
        for (int r = 0; r < 6; ++r)
#pragma unroll
            for (int c = 0; c < 6; ++c)
                v[r][c] = vin[(ic * 34 + 4 * qy + r) * 35 + 4 * qx + c];
#pragma unroll
        for (int o = 0; o < 16; ++o) {
            const float* wo = wl + (ocq * 16 + o) * 49 + ic * 16;
#pragma unroll
            for (int ky = 0; ky < 4; ++ky)
#pragma unroll
                for (int kx = 0; kx < 4; ++kx) {
                    float wv = wo[ky * 4 + kx];
                    acc[0][o] = fmaf(v[ky][kx], wv, acc[0][o]);
                    acc[1][o] = fmaf(v[ky][kx + 2], wv, acc[1][o]);
                    acc[2][o] = fmaf(v[ky + 2][kx], wv, acc[2][o]);
                    acc[3][o] = fmaf(v[ky + 2][kx + 2], wv, acc[3][o]);
                }
        }
    }
    int j = (Y0 >> 1) + qy, i2 = (X0 >> 1) + qx;
#pragma unroll
    for (int p = 0; p < 4; ++p) {
        int dy = p >> 1, dx = p & 1;
        unsigned short tmp[16];
#pragma unroll
        for (int o = 0; o < 16; ++o) tmp[o] = f2bf(acc[p][o] + bias[ocq * 16 + o]);
        unsigned short* dst = xs + (((size_t)((b * 2 + dy) * 2 + dx) * 32 + j) * 32 + i2) * 64 + ocq * 16;
        *(uint4*)(dst) = *(const uint4*)(tmp);
        *(uint4*)(dst + 8) = *(const uint4*)(tmp + 8);
    }
}

// ---------------- conv1 (MFMA, fused L0 BN on load, fused L1 stats, atomic-free in-block reduce) ----------------
__global__ void conv1_mfma_kernel(const unsigned short* __restrict__ xs,
                                  const unsigned short* __restrict__ wp,
                                  const float* __restrict__ bias,
                                  const float* __restrict__ sc, const float* __restrict__ sh,
                                  float* __restrict__ gsum, float* __restrict__ gsq,
                                  unsigned short* __restrict__ ys) {
    constexpr int STR = 72;
    __shared__ unsigned short lds[4 * 3 * 17 * STR];   // 29.4 KB
    __shared__ float ws[4][64], wq[4][64];
    int bid = blockIdx.x;
    int slot = (bid & (NREP - 1)) * 576;
    int xt = bid & 1;
    int qp = (bid >> 1) & 15;
    int b = bid >> 5;
    int oy0 = qp * 2, x0 = xt * 16;
    for (int i = threadIdx.x; i < 1632; i += 256) {
        int icc = i & 7; int t = i >> 3;
        int col = t % 17; int rc = t / 17;
        int row = rc % 3; int pl = rc / 3;
        int py = pl >> 1, px = pl & 1;
        int j = oy0 - py + row;
        int ci = x0 - px + col;
        uint4 v = {0u, 0u, 0u, 0u};
        if (((unsigned)j < 32u) & ((unsigned)ci < 32u)) {
            v = *(const uint4*)(xs + ((size_t)((b * 4 + pl) * 32 + j) * 32 + ci) * 64 + icc * 8);
            v = bn_fuse8(v, sc, sh, icc * 8, 0.2f);
        }
        *(uint4*)(lds + ((pl * 3 + row) * 17 + col) * STR + icc * 8) = v;
    }
    __syncthreads();

    int wv = threadIdx.x >> 6, lane = threadIdx.x & 63;
    int r = wv >> 1, oct = wv & 1;
    int m = lane & 15, kq = lane >> 4;
    f32x4 acc[4];
#pragma unroll
    for (int j = 0; j < 4; ++j) acc[j] = (f32x4){0.f, 0.f, 0.f, 0.f};

#pragma unroll
    for (int ky = 0; ky < 4; ++ky) {
        int py = (ky & 1) ^ 1;
        int lrow = r + (ky >> 1);
#pragma unroll
        for (int kx = 0; kx < 4; ++kx) {
            int px = (kx & 1) ^ 1;
            int pl = py * 2 + px;
            int lcol = m + (kx >> 1);
            const unsigned short* lp = lds + ((pl * 3 + lrow) * 17 + lcol) * STR + kq * 8;
            int ktap = ky * 4 + kx;
            const unsigned short* bb = wp + (size_t)(ktap * 2 + oct) * 4096;
#pragma unroll
            for (int kc = 0; kc < 2; ++kc) {
                bf16x8 a = *(const bf16x8*)(lp + kc * 32);
                const unsigned short* bk = bb + kc * 2048 + lane * 8;
                bf16x8 b0 = *(const bf16x8*)(bk);
                bf16x8 b1 = *(const bf16x8*)(bk + 512);
                bf16x8 b2 = *(const bf16x8*)(bk + 1024);
                bf16x8 b3 = *(const bf16x8*)(bk + 1536);
                acc[0] = __builtin_amdgcn_mfma_f32_16x16x32_bf16(a, b0, acc[0], 0, 0, 0);
                acc[1] = __builtin_amdgcn_mfma_f32_16x16x32_bf16(a, b1, acc[1], 0, 0, 0);
                acc[2] = __builtin_amdgcn_mfma_f32_16x16x32_bf16(a, b2, acc[2], 0, 0, 0);
                acc[3] = __builtin_amdgcn_mfma_f32_16x16x32_bf16(a, b3, acc[3], 0, 0, 0);
            }
        }
    }
    int oy = oy0 + r;
    int pyo = oy & 1, jo = oy >> 1;
    int n = m;
    float bv0 = bias[oct * 64 + n], bv1 = bias[oct * 64 + 16 + n];
    float bv2 = bias[oct * 64 + 32 + n], bv3 = bias[oct * 64 + 48 + n];
    float s0 = 0, s1 = 0, s2 = 0, s3 = 0, q0 = 0, q1 = 0, q2 = 0, q3 = 0;
#pragma unroll
    for (int reg = 0; reg < 4; ++reg) {
        int mm = kq * 4 + reg;
        int ox = x0 + mm;
        int pxo = ox & 1, io = ox >> 1;
        size_t base = (((size_t)((b * 2 + pyo) * 2 + pxo) * 16 + jo) * 16 + io) * 128 + oct * 64 + n;
        float v0 = acc[0][reg] + bv0, v1 = acc[1][reg] + bv1;
        float v2 = acc[2][reg] + bv2, v3 = acc[3][reg] + bv3;
        s0 += v0; q0 += v0 * v0; s1 += v1; q1 += v1 * v1;
        s2 += v2; q2 += v2 * v2; s3 += v3; q3 += v3 * v3;
        ys[base]      = f2bf(v0);
        ys[base + 16] = f2bf(v1);
        ys[base + 32] = f2bf(v2);
        ys[base + 48] = f2bf(v3);
    }
    // wave-level kq reduction (no atomics)
    s0 = kq_reduce(s0); q0 = kq_reduce(q0);
    s1 = kq_reduce(s1); q1 = kq_reduce(q1);
    s2 = kq_reduce(s2); q2 = kq_reduce(q2);
    s3 = kq_reduce(s3); q3 = kq_reduce(q3);
    if (lane < 16) {
        ws[wv][0 * 16 + n] = s0; wq[wv][0 * 16 + n] = q0;
        ws[wv][1 * 16 + n] = s1; wq[wv][1 * 16 + n] = q1;
        ws[wv][2 * 16 + n] = s2; wq[wv][2 * 16 + n] = q2;
        ws[wv][3 * 16 + n] = s3; wq[wv][3 * 16 + n] = q3;
    }
    __syncthreads();
    if (threadIdx.x < 128) {
        int c = threadIdx.x;
        int o = c >> 6, rr = c & 63;          // waves {o, o+2} cover oct o
        float s = ws[o][rr] + ws[o + 2][rr];
        float q = wq[o][rr] + wq[o + 2][rr];
        atomicAdd(&gsum[slot + 64 + c], s);
        atomicAdd(&gsq[slot + 64 + c], q);
    }
}

// ---------------- conv2 (MFMA, fused L1 BN on load) + tanh: Y_s2d -> Z_t[0:64) ----------------
__global__ void conv2_mfma_kernel(const unsigned short* __restrict__ ys,
                                  const unsigned short* __restrict__ wp,
                                  const float* __restrict__ bias,
                                  const float* __restrict__ sc, const float* __restrict__ sh,
                                  unsigned short* __restrict__ zt) {
    constexpr int STR = 136;
    __shared__ unsigned short lds[4 * 3 * 17 * STR];   // 55.5 KB
    int bid = blockIdx.x;
    int qp = bid & 7;
    int b = bid >> 3;
    int oy0 = qp * 2;
    for (int i = threadIdx.x; i < 3264; i += 256) {
        int icc = i & 15; int t = i >> 4;
        int col = t % 17; int rc = t / 17;
        int row = rc % 3; int pl = rc / 3;
        int py = pl >> 1, px = pl & 1;
        int j = oy0 - py + row;
        int ci = col - px;
        uint4 v = {0u, 0u, 0u, 0u};
        if (((unsigned)j < 16u) & ((unsigned)ci < 16u)) {
            v = *(const uint4*)(ys + ((size_t)((b * 4 + pl) * 16 + j) * 16 + ci) * 128 + icc * 8);
            v = bn_fuse8(v, sc, sh, icc * 8, 0.2f);
        }
        *(uint4*)(lds + ((pl * 3 + row) * 17 + col) * STR + icc * 8) = v;
    }
    __syncthreads();

    int wv = threadIdx.x >> 6, lane = threadIdx.x & 63;
    int r = wv >> 1, jh = wv & 1;
    int m = lane & 15, kq = lane >> 4;
    f32x4 acc[2];
    acc[0] = (f32x4){0.f, 0.f, 0.f, 0.f};
    acc[1] = acc[0];
#pragma unroll
    for (int ky = 0; ky < 4; ++ky) {
        int py = (ky & 1) ^ 1;
        int lrow = r + (ky >> 1);
#pragma unroll
        for (int kx = 0; kx < 4; ++kx) {
            int px = (kx & 1) ^ 1;
            int pl = py * 2 + px;
            int lcol = m + (kx >> 1);
            const unsigned short* lp = lds + ((pl * 3 + lrow) * 17 + lcol) * STR + kq * 8;
            int ktap = ky * 4 + kx;
            const unsigned short* bb = wp + (size_t)ktap * 8192;
#pragma unroll
            for (int kc = 0; kc < 4; ++kc) {
                bf16x8 a = *(const bf16x8*)(lp + kc * 32);
                const unsigned short* bk = bb + kc * 2048 + (jh * 2) * 512 + lane * 8;
                bf16x8 b0 = *(const bf16x8*)(bk);
                bf16x8 b1 = *(const bf16x8*)(bk + 512);
                acc[0] = __builtin_amdgcn_mfma_f32_16x16x32_bf16(a, b0, acc[0], 0, 0, 0);
                acc[1] = __builtin_amdgcn_mfma_f32_16x16x32_bf16(a, b1, acc[1], 0, 0, 0);
            }
        }
    }
    int oy = oy0 + r;
    int n = m;
    float bv0 = bias[(jh * 2) * 16 + n], bv1 = bias[(jh * 2 + 1) * 16 + n];
#pragma unroll
    for (int reg = 0; reg < 4; ++reg) {
        int x = kq * 4 + reg;
        size_t base = ((size_t)(b * 16 + oy) * 16 + x) * 192 + (jh * 2) * 16 + n;
        zt[base]      = f2bf(tanhf(acc[0][reg] + bv0));
        zt[base + 16] = f2bf(tanhf(acc[1][reg] + bv1));
    }
}

// ---------------- assemble Z_t[...][64:192): Zl, Zg, wave, and pad channels ----------------
__global__ void assemble_z(const void* __restrict__ Zl, const void* __restrict__ Zg,
                           const void* __restrict__ phi, const float* __restrict__ K12,
                           unsigned short* __restrict__ zt, const int* __restrict__ flg) {
    bool f32 = flg[0] != 0;
    int i = blockIdx.x * 256 + threadIdx.x;
    const int TOT = 64 * 128 * 256;
    if (i >= TOT) return;
    int pos = i & 255;
    int t = i >> 8;
    int c128 = t % 128;
    int b = t / 128;
    float val;
    if (c128 < 32) {
        val = loadIn(Zl, ((size_t)(b * 32 + c128) << 8) + pos, f32);
    } else if (c128 < 96) {
        val = loadIn(Zg, ((size_t)(b * 64 + (c128 - 32)) << 8) + pos, f32);
    } else if (c128 < 104) {
        int p = c128 - 96;
        int y = pos >> 4, x = pos & 15;
        float k1 = K12[b * 16 + p];
        float k2 = K12[b * 16 + 8 + p];
        val = sinf(k1 * (float)y + k2 * (float)x + loadIn(phi, b * 8 + p, f32) * TWO_PI_F);
    } else {
        val = 0.f;      // pad channels 168..192 of Z_t
    }
    zt[((size_t)(b * 256 + pos)) * 192 + 64 + c128] = f2bf(val);
}

// ---------------- MFMA transposed-conv v12: QR rows/block, oct slowest, fused BN-in,
// optional stats, K-phase split (KPH) to shrink LDS and raise occupancy ----------------
// KPH=2 for deconv1: stage 128 of 256 channels at a time into a 29.4 KB buffer (was 57.3 KB)
// -> 4 blocks/CU instead of 2 (VGPR-limited at 128), doubling latency-hiding waves.
// acc persists across phases; staged bytes unchanged; +3 barriers/block.
template <int ICP, int Q, int OC, int QR, bool BN, bool ST, int KPH>
__global__ __launch_bounds__(256, 2)
void deconv_mfma2_kernel(const unsigned short* __restrict__ in_t,
                         const unsigned short* __restrict__ wp2,
                         const float* __restrict__ bias,
                         const float* __restrict__ sc, const float* __restrict__ sh,
                         float* __restrict__ gsum, float* __restrict__ gsq, int statoff,
                         unsigned short* __restrict__ out_t) {
    constexpr int NOCT = OC / 64;
    constexpr int NK = ICP / 32;         // total 32-channel chunks
    constexpr int ICPP = ICP / KPH;      // channels per phase
    constexpr int NKL = NK / KPH;        // chunks per phase
    constexpr int XT = Q / 16;
    constexpr int NQB = Q / QR;
    constexpr int ROWS = QR + 2;
    constexpr int STRIDE = ICPP + 8;
    constexpr int NTILES = XT * NQB * 64;
    __shared__ unsigned short lds[ROWS * 18 * STRIDE];
    __shared__ float ws[ST ? 4 : 1][64], wq[ST ? 4 : 1][64];

    int bid = blockIdx.x;
    int slot = (bid & (NREP - 1)) * 576;
    int oct = bid / NTILES;          // slowest dim
    bid -= oct * NTILES;
    int xt = bid % XT;
    int t2 = bid / XT;
    int qp = t2 % NQB;
    int b = t2 / NQB;
    int qy0 = qp * QR;
    int x0 = xt * 16;

    int wv = threadIdx.x >> 6, lane = threadIdx.x & 63;
    int dy = wv >> 1, dx = wv & 1;
    int m = lane & 15, kq = lane >> 4;

    f32x4 acc[QR][4];
#pragma unroll
    for (int q = 0; q < QR; ++q)
#pragma unroll
        for (int j = 0; j < 4; ++j) acc[q][j] = (f32x4){0.f, 0.f, 0.f, 0.f};

    constexpr int P8 = ICPP / 8;
    constexpr int E8 = ROWS * 18 * P8;
#pragma unroll
    for (int ph = 0; ph < KPH; ++ph) {
        if (ph) __syncthreads();     // all waves done reading previous phase
        for (int i = threadIdx.x; i < E8; i += 256) {
            int icc = i % P8;
            int rc = i / P8;
            int row = rc / 18, col = rc % 18;
            int y = qy0 - 1 + row, x = x0 - 1 + col;
            uint4 val = {0u, 0u, 0u, 0u};
            if (((unsigned)y < (unsigned)Q) & ((unsigned)x < (unsigned)Q)) {
                val = *(const uint4*)(in_t + (size_t)((b * Q + y) * Q + x) * ICP + ph * ICPP + icc * 8);
                if (BN) val = bn_fuse8(val, sc, sh, ph * ICPP + icc * 8, 0.f);
            }
            *(uint4*)(lds + rc * STRIDE + icc * 8) = val;
        }
        __syncthreads();

#pragma unroll
        for (int t = 0; t < 4; ++t) {
            int rr = t >> 1, cc = t & 1;
            int ktap = ((3 - dy) - 2 * rr) * 4 + ((3 - dx) - 2 * cc);
            int col = m + dx + cc;
            int row0 = dy + rr;
            const unsigned short* bbase = wp2 + (size_t)((ktap * NOCT + oct) * NK) * 2048;
#pragma unroll
            for (int kc = 0; kc < NKL; ++kc) {
                int kcg = ph * NKL + kc;
                bf16x8 a[QR];
#pragma unroll
                for (int q = 0; q < QR; ++q)
                    a[q] = *(const bf16x8*)(lds + ((row0 + q) * 18 + col) * STRIDE + kc * 32 + kq * 8);
                bf16x8 b0 = *(const bf16x8*)(bbase + (kcg * 4 + 0) * 512 + lane * 8);
                bf16x8 b1 = *(const bf16x8*)(bbase + (kcg * 4 + 1) * 512 + lane * 8);
                bf16x8 b2 = *(const bf16x8*)(bbase + (kcg * 4 + 2) * 512 + lane * 8);
                bf16x8 b3 = *(const bf16x8*)(bbase + (kcg * 4 + 3) * 512 + lane * 8);
#pragma unroll
                for (int q = 0; q < QR; ++q) {
                    acc[q][0] = __builtin_amdgcn_mfma_f32_16x16x32_bf16(a[q], b0, acc[q][0], 0, 0, 0);
                    acc[q][1] = __builtin_amdgcn_mfma_f32_16x16x32_bf16(a[q], b1, acc[q][1], 0, 0, 0);
                    acc[q][2] = __builtin_amdgcn_mfma_f32_16x16x32_bf16(a[q], b2, acc[q][2], 0, 0, 0);
                    acc[q][3] = __builtin_amdgcn_mfma_f32_16x16x32_bf16(a[q], b3, acc[q][3], 0, 0, 0);
                }
            }
        }
    }
    // Epilogue: lane n holds channels oct*64 + 4n + j -> one contiguous ushort4 per (qyl,reg).
    int n = m;
    const float4 bv = *(const float4*)(bias + oct * 64 + 4 * n);
    float s0 = 0, s1 = 0, s2 = 0, s3 = 0, q0 = 0, q1 = 0, q2 = 0, q3 = 0;
#pragma unroll
    for (int qyl = 0; qyl < QR; ++qyl) {
        int oy = 2 * (qy0 + qyl) + dy;
#pragma unroll
        for (int reg = 0; reg < 4; ++reg) {
            int mm = kq * 4 + reg;
            int ox = 2 * (x0 + mm) + dx;
            size_t base = ((size_t)((b * 2 * Q + oy) * (2 * Q) + ox)) * OC + oct * 64 + 4 * n;
            float v0 = acc[qyl][0][reg] + bv.x;
            float v1 = acc[qyl][1][reg] + bv.y;
            float v2 = acc[qyl][2][reg] + bv.z;
            float v3 = acc[qyl][3][reg] + bv.w;
            if (ST) {
                s0 += v0; q0 += v0 * v0; s1 += v1; q1 += v1 * v1;
                s2 += v2; q2 += v2 * v2; s3 += v3; q3 += v3 * v3;
            }
            ushort4 tv;
            tv.x = f2bf(v0); tv.y = f2bf(v1); tv.z = f2bf(v2); tv.w = f2bf(v3);
            *(ushort4*)(out_t + base) = tv;
        }
    }
    if (ST) {
        // wave-level kq reduction (no LDS atomics)
        s0 = kq_reduce(s0); q0 = kq_reduce(q0);
        s1 = kq_reduce(s1); q1 = kq_reduce(q1);
        s2 = kq_reduce(s2); q2 = kq_reduce(q2);
        s3 = kq_reduce(s3); q3 = kq_reduce(q3);
        if (lane < 16) {
            ws[wv][4 * n + 0] = s0; wq[wv][4 * n + 0] = q0;
            ws[wv][4 * n + 1] = s1; wq[wv][4 * n + 1] = q1;
            ws[wv][4 * n + 2] = s2; wq[wv][4 * n + 2] = q2;
            ws[wv][4 * n + 3] = s3; wq[wv][4 * n + 3] = q3;
        }
        __syncthreads();
        if (threadIdx.x < 64) {
            int c = threadIdx.x;
            float s = ws[0][c] + ws[1][c] + ws[2][c] + ws[3][c];
            float q = wq[0][c] + wq[1][c] + wq[2][c] + wq[3][c];
            atomicAdd(&gsum[slot + statoff + oct * 64 + c], s);
            atomicAdd(&gsq[slot + statoff + oct * 64 + c], q);
        }
    }
}

// ---------------- deconv2 v2 (MFMA, QR=4, fused G1 BN+relu on load, OC=3 pad 16) + tanh -> fp32 NCHW ----------------
__global__ void deconv2_mfma_kernel(const unsigned short* __restrict__ yt,
                                    const unsigned short* __restrict__ wp,
                                    const float* __restrict__ bias,
                                    const float* __restrict__ sc, const float* __restrict__ sh,
                                    float* __restrict__ outp) {
    constexpr int Q = 64, ICP = 128, NK = 4, STRIDE = 136, QR = 4, ROWS = 6;
    __shared__ unsigned short lds[ROWS * 18 * STRIDE];   // 29.4 KB
    int bid = blockIdx.x;
    int xt = bid & 3;
    int t2 = bid >> 2;
    int qp = t2 & 15;
    int b = t2 >> 4;
    int qy0 = qp * QR, x0 = xt * 16;

    for (int i = threadIdx.x; i < ROWS * 18 * 16; i += 256) {
        int icc = i & 15;
        int rc = i >> 4;
        int row = rc / 18, col = rc % 18;
        int y = qy0 - 1 + row, x = x0 - 1 + col;
        uint4 v = {0u, 0u, 0u, 0u};
        if (((unsigned)y < (unsigned)Q) & ((unsigned)x < (unsigned)Q)) {
            v = *(const uint4*)(yt + (size_t)((b * Q + y) * Q + x) * ICP + icc * 8);
            v = bn_fuse8(v, sc, sh, icc * 8, 0.f);
        }
        *(uint4*)(lds + rc * STRIDE + icc * 8) = v;
    }
    __syncthreads();

    int wv = threadIdx.x >> 6, lane = threadIdx.x & 63;
    int dy = wv >> 1, dx = wv & 1;
    int m = lane & 15, kq = lane >> 4;
    f32x4 acc[QR];
#pragma unroll
    for (int q = 0; q < QR; ++q) acc[q] = (f32x4){0.f, 0.f, 0.f, 0.f};

#pragma unroll
    for (int t = 0; t < 4; ++t) {
        int rr = t >> 1, cc = t & 1;
        int ktap = ((3 - dy) - 2 * rr) * 4 + ((3 - dx) - 2 * cc);
        int col = m + dx + cc;
        int row0 = dy + rr;
        const unsigned short* bb = wp + (size_t)(ktap * NK) * 512;
#pragma unroll
        for (int kc = 0; kc < NK; ++kc) {
            bf16x8 a[QR];
#pragma unroll
            for (int q = 0; q < QR; ++q)
                a[q] = *(const bf16x8*)(lds + ((row0 + q) * 18 + col) * STRIDE + kc * 32 + kq * 8);
            bf16x8 b0 = *(const bf16x8*)(bb + kc * 512 + lane * 8);
#pragma unroll
            for (int q = 0; q < QR; ++q)
                acc[q] = __builtin_amdgcn_mfma_f32_16x16x32_bf16(a[q], b0, acc[q], 0, 0, 0);
        }
    }
    int n = m;
    if (n < 3) {
        float bv = bias[n];
#pragma unroll
        for (int qyl = 0; qyl < QR; ++qyl) {
            int oy = 2 * (qy0 + qyl) + dy;
#pragma unroll
            for (int reg = 0; reg < 4; ++reg) {
                int mm = kq * 4 + reg;
                int ox = 2 * (x0 + mm) + dx;
                size_t ob = (size_t)(b * 3 + n) * 16384;
                outp[ob + (size_t)oy * 128 + ox] = tanhf(acc[qyl][reg] + bv);
            }
        }
    }
}

// ---------------- channel-last BN stat reduction (conv0 output + deconv1 output) ----------------
template <int C>
__global__ void stat_reduce_t(const unsigned short* __restrict__ x, int total4,
                              float* __restrict__ ssum, float* __restrict__ ssq, int statoff) {
    __shared__ float ls[C], lq[C];
    for (int c = threadIdx.x; c < C; c += 256) { ls[c] = 0.f; lq[c] = 0.f; }
    __syncthreads();
    int i0 = blockIdx.x * 256 + threadIdx.x;
    int stride = gridDim.x * 256;
    int c0 = (i0 << 2) & (C - 1);
    float s0 = 0, s1 = 0, s2 = 0, s3 = 0, q0 = 0, q1 = 0, q2 = 0, q3 = 0;
    for (int i = i0; i < total4; i += stride) {
        ushort4 v = *(const ushort4*)(x + ((size_t)i << 2));
        float f0 = bf2f_raw(v.x), f1 = bf2f_raw(v.y), f2 = bf2f_raw(v.z), f3 = bf2f_raw(v.w);
        s0 += f0; s1 += f1; s2 += f2; s3 += f3;
        q0 += f0 * f0; q1 += f1 * f1; q2 += f2 * f2; q3 += f3 * f3;
    }
    atomicAdd(&ls[c0], s0); atomicAdd(&ls[c0 + 1], s1); atomicAdd(&ls[c0 + 2], s2); atomicAdd(&ls[c0 + 3], s3);
    atomicAdd(&lq[c0], q0); atomicAdd(&lq[c0 + 1], q1); atomicAdd(&lq[c0 + 2], q2); atomicAdd(&lq[c0 + 3], q3);
    __syncthreads();
    int slot = (blockIdx.x & (NREP - 1)) * 576;
    for (int c = threadIdx.x; c < C; c += 256) {
        atomicAdd(&ssum[slot + statoff + c], ls[c]);
        atomicAdd(&ssq[slot + statoff + c], lq[c]);
    }
}

// ---------------- BN finalize (sums NREP replicas) ----------------
__global__ void bn_fin_kernel(const float* __restrict__ ssum, const float* __restrict__ ssq,
                              const float* __restrict__ g, const float* __restrict__ be,
                              float* __restrict__ scale, float* __restrict__ shift,
                              int statoff, int C, float invN) {
    int c = threadIdx.x;
    if (c >= C) return;
    float s = 0.f, q = 0.f;
#pragma unroll
    for (int r = 0; r < NREP; ++r) {
        s += ssum[r * 576 + statoff + c];
        q += ssq[r * 576 + statoff + c];
    }
    float m = s * invN;
    float v = q * invN - m * m;
    v = fmaxf(v, 0.f);
    float sc = g[c] * rsqrtf(v + 1e-5f);
    scale[statoff + c] = sc;
    shift[statoff + c] = be[c] - m * sc;
}

extern "C" void kernel_launch(void* const* d_in, const int* in_sizes, int n_in,
                              void* d_out, int out_size, void* d_ws, size_t ws_size,
                              hipStream_t stream) {
    if (ws_size < WS_NEED_BYTES) {
        hipMemsetAsync(d_out, 0, (size_t)out_size * 4, stream);
        return;
    }

    float* W = (float*)d_ws;
    unsigned short* U = (unsigned short*)d_ws;
    int* FLG = (int*)(W + OFF_FLAG);

    detect_kernel<<<1, 256, 0, stream>>>((const unsigned short*)d_in[2], FLG);

    CvtJobs J;
    const int srcIdx[16] = {10, 28, 11, 12, 13, 15, 16, 17, 19, 21, 22, 23, 25, 26, 27, 29};
    const int cnt[16]    = {3072, 6144, 64, 64, 64, 128, 128, 128, 64, 256, 256, 256, 128, 128, 128, 3};
    float* dsts[16] = {W + OFF_WC0, W + OFF_WG2,
                       W + OFF_CB0, W + OFF_CG0, W + OFF_CBE0, W + OFF_CB1, W + OFF_CG1, W + OFF_CBE1,
                       W + OFF_CB2, W + OFF_GB0, W + OFF_GG0, W + OFF_GBE0, W + OFF_GB1, W + OFF_GG1,
                       W + OFF_GBE1, W + OFF_GB2};
    int off = 0;
    for (int k = 0; k < 16; ++k) {
        J.src[k] = d_in[srcIdx[k]];
        J.dst[k] = dsts[k];
        J.off[k] = off;
        off += cnt[k];
    }
    J.off[16] = off;
    cvt_all_kernel<<<(off + 255) / 256, 256, 0, stream>>>(J, off, FLG);

    zero_kernel<<<(2 * NREP * 576 + 255) / 256, 256, 0, stream>>>(W + OFF_SSUM, 2 * NREP * 576);

    // weight packs
    pack_w2_kernel<<<3072, 256, 0, stream>>>(d_in[20], U + UW0, 168, 192, 256, FLG);
    pack_w2_kernel<<<2048, 256, 0, stream>>>(d_in[24], U + UW1, 256, 256, 128, FLG);
    pack_wc_kernel<<<512, 256, 0, stream>>>(d_in[14], U + UWC1, 64, 128, FLG);
    pack_wc_kernel<<<512, 256, 0, stream>>>(d_in[18], U + UWC2, 128, 64, FLG);
    pack_w2s_kernel<<<128, 256, 0, stream>>>(d_in[28], U + UW2, 128, 3, FLG);

    mlp_kernel<<<64, 64, 0, stream>>>(d_in[1], d_in[4], d_in[5], d_in[6], d_in[7],
                                      d_in[8], d_in[9], W + OFF_K12, FLG);

    // ---- conv0 -> X_s2d (raw) ----
    conv0_s2d_kernel<<<dim3(16, 1, 64), 256, 0, stream>>>(d_in[2], W + OFF_WC0, W + OFF_CB0,
                                                          U + UXT, FLG);
    stat_reduce_t<64><<<1024, 256, 0, stream>>>(U + UXT, 4194304, W + OFF_SSUM, W + OFF_SSQ, 0);
    bn_fin_kernel<<<1, 256, 0, stream>>>(W + OFF_SSUM, W + OFF_SSQ, W + OFF_CG0, W + OFF_CBE0,
                                         W + OFF_SCALE, W + OFF_SHIFT, 0, 64, 1.f / 262144.f);

    // ---- conv1 (MFMA, fused L0 BN, fused L1 stats) -> Y_s2d ----
    conv1_mfma_kernel<<<2048, 256, 0, stream>>>(U + UXT, U + UWC1, W + OFF_CB1,
                                                W + OFF_SCALE + 0, W + OFF_SHIFT + 0,
                                                W + OFF_SSUM, W + OFF_SSQ, U + UYT);
    bn_fin_kernel<<<1, 256, 0, stream>>>(W + OFF_SSUM, W + OFF_SSQ, W + OFF_CG1, W + OFF_CBE1,
                                         W + OFF_SCALE, W + OFF_SHIFT, 64, 128, 1.f / 65536.f);

    // ---- conv2 (MFMA, fused L1 BN) + tanh -> Z_t[0:64) ----
    conv2_mfma_kernel<<<512, 256, 0, stream>>>(U + UYT, U + UWC2, W + OFF_CB2,
                                               W + OFF_SCALE + 64, W + OFF_SHIFT + 64, U + UZT);

    // ---- Z_t[64:192) incl. pad zeroing ----
    assemble_z<<<8192, 256, 0, stream>>>(d_in[0], d_in[1], d_in[3], W + OFF_K12, U + UZT, FLG);

    // ---- gen deconv0 (MFMA, QR=2, fused G0 stats, KPH=1): Z_t -> X_t(32,32,256) ----
    deconv_mfma2_kernel<192, 16, 256, 2, false, true, 1><<<2048, 256, 0, stream>>>(
        U + UZT, U + UW0, W + OFF_GB0, nullptr, nullptr,
        W + OFF_SSUM, W + OFF_SSQ, 192, U + UXT);
    bn_fin_kernel<<<1, 256, 0, stream>>>(W + OFF_SSUM, W + OFF_SSQ, W + OFF_GG0, W + OFF_GBE0,
                                         W + OFF_SCALE, W + OFF_SHIFT, 192, 256, 1.f / 65536.f);

    // ---- gen deconv1 (MFMA, QR=4, fused G0 BN, KPH=2 K-split): X_t -> Y_t(64,64,128) ----
    // grid = NOCT(2) * XT(2) * NQB(8) * 64 = 2048; LDS 29.4 KB -> 4 blocks/CU
    deconv_mfma2_kernel<256, 32, 128, 4, true, false, 2><<<2048, 256, 0, stream>>>(
        U + UXT, U + UW1, W + OFF_GB1, W + OFF_SCALE + 192, W + OFF_SHIFT + 192,
        nullptr, nullptr, 0, U + UYT);
    // G1 stats via separate pass over Y_t (67 MB read)
    stat_reduce_t<128><<<1024, 256, 0, stream>>>(U + UYT, 8388608, W + OFF_SSUM, W + OFF_SSQ, 448);
    bn_fin_kernel<<<1, 256, 0, stream>>>(W + OFF_SSUM, W + OFF_SSQ, W + OFF_GG1, W + OFF_GBE1,
                                         W + OFF_SCALE, W + OFF_SHIFT, 448, 128, 1.f / 262144.f);

    // ---- gen deconv2 (MFMA, QR=4, fused G1 BN) + tanh -> d_out fp32 ----  grid = 64*16*4 = 4096
    deconv2_mfma_kernel<<<4096, 256, 0, stream>>>(U + UYT, U + UW2, W + OFF_GB2,
                                                  W + OFF_SCALE + 448, W + OFF_SHIFT + 448,
                                                  (float*)d_out);
}

// Round 13
// 555.771 us; speedup vs baseline: 1.2747x; 1.0104x over previous
//
#include <hip/hip_runtime.h>
#include <hip/hip_bf16.h>

#define TWO_PI_F 6.2831853071795864769f

typedef __attribute__((ext_vector_type(8))) __bf16 bf16x8;
typedef __attribute__((ext_vector_type(4))) float f32x4;

// 32-way replicated stat buffers: per-address global atomic chains drop 32x.
#define NREP 32

__device__ __forceinline__ float bf2f_raw(unsigned short u) {
    return __uint_as_float(((unsigned int)u) << 16);
}
__device__ __forceinline__ unsigned short f2bf(float f) {
    unsigned int u = __float_as_uint(f);
    unsigned int r = (u + 0x7FFFu + ((u >> 16) & 1u)) >> 16;   // RNE
    return (unsigned short)r;
}
__device__ __forceinline__ float loadIn(const void* p, size_t i, bool f32) {
    return f32 ? ((const float*)p)[i] : bf2f_raw(((const unsigned short*)p)[i]);
}

// Fused BN affine + (leaky)relu applied to 8 packed bf16 during staging.
__device__ __forceinline__ uint4 bn_fuse8(uint4 v, const float* __restrict__ sc,
                                          const float* __restrict__ sh, int c0, float slope) {
    unsigned short us[8];
    *(uint4*)us = v;
#pragma unroll
    for (int k = 0; k < 8; ++k) {
        float f = bf2f_raw(us[k]) * sc[c0 + k] + sh[c0 + k];
        f = f > 0.f ? f : slope * f;
        us[k] = f2bf(f);
    }
    return *(const uint4*)us;
}

// Reduce val across the 4 kq-groups of a wave (lanes differing in bits 4,5).
__device__ __forceinline__ float kq_reduce(float v) {
    v += __shfl_xor(v, 16, 64);
    v += __shfl_xor(v, 32, 64);
    return v;
}

// ---------------- ws layout ----------------
static constexpr size_t OFF_WC0 = 0;          // cod_w0 fp32 3072
static constexpr size_t OFF_WG2 = 3072;       // gen_w2 fp32 6144 (legacy, unused)
static constexpr size_t OFF_P   = 9216;
static constexpr size_t OFF_CB0 = OFF_P + 0;
static constexpr size_t OFF_CG0 = OFF_P + 64;
static constexpr size_t OFF_CBE0= OFF_P + 128;
static constexpr size_t OFF_CB1 = OFF_P + 192;
static constexpr size_t OFF_CG1 = OFF_P + 320;
static constexpr size_t OFF_CBE1= OFF_P + 448;
static constexpr size_t OFF_CB2 = OFF_P + 576;
static constexpr size_t OFF_GB0 = OFF_P + 640;
static constexpr size_t OFF_GG0 = OFF_P + 896;
static constexpr size_t OFF_GBE0= OFF_P + 1152;
static constexpr size_t OFF_GB1 = OFF_P + 1408;
static constexpr size_t OFF_GG1 = OFF_P + 1536;
static constexpr size_t OFF_GBE1= OFF_P + 1664;
static constexpr size_t OFF_GB2 = OFF_P + 1792;
static constexpr size_t OFF_SSUM  = OFF_P + 2048;              // NREP x 576
static constexpr size_t OFF_SSQ   = OFF_SSUM + NREP * 576;     // NREP x 576
static constexpr size_t OFF_SCALE = OFF_SSQ + NREP * 576;
static constexpr size_t OFF_SHIFT = OFF_SCALE + 576;
static constexpr size_t OFF_K12   = OFF_SHIFT + 576;
static constexpr size_t OFF_FLAG  = OFF_K12 + 1024;
static constexpr size_t FP32_END  = OFF_FLAG + 16;   // floats
// ushort regions:
static constexpr size_t UXT = 2 * FP32_END;            // X region: X_s2d (b,2,2,32,32,64) then X_t (b,32,32,256)
static constexpr size_t UYT = UXT + 16777216;          // Y region: Y_s2d head, then Y_t (b,64,64,128)
static constexpr size_t UZT = UYT + 8388608;           // Z_t (b,16,16,192)
static constexpr size_t UW0 = UYT + 33554432;          // deconv0 pack
static constexpr size_t UW1 = UW0 + 786432;            // deconv1 pack
static constexpr size_t UWC1 = UW1 + 524288;           // conv1 pack
static constexpr size_t UWC2 = UWC1 + 131072;          // conv2 pack
static constexpr size_t UW2 = UWC2 + 131072;           // deconv2 pack
static constexpr size_t WS_END_USHORT = UW2 + 32768;
static constexpr size_t WS_NEED_BYTES = WS_END_USHORT * 2;   // ~110 MB

// stat slots: L0:0(64) L1:64(128) G0:192(256) G1:448(128)

// ---------------- input dtype detection ----------------
__global__ void detect_kernel(const unsigned short* __restrict__ imgs, int* __restrict__ flag) {
    int t = threadIdx.x;  // 256
    unsigned short u = imgs[t];
    int e = (u >> 7) & 0xFF;
    unsigned long long b = __ballot(e >= 0xC0);
    __shared__ int cnt[4];
    if ((t & 63) == 0) cnt[t >> 6] = __popcll(b);
    __syncthreads();
    if (t == 0) flag[0] = (cnt[0] + cnt[1] + cnt[2] + cnt[3] >= 4) ? 1 : 0;
}

// ---------------- small param -> fp32 conversion ----------------
struct CvtJobs {
    const void* src[16];
    float* dst[16];
    int off[17];
};

__global__ void cvt_all_kernel(CvtJobs J, int total, const int* __restrict__ flg) {
    int i = blockIdx.x * 256 + threadIdx.x;
    if (i >= total) return;
    bool f32 = flg[0] != 0;
    int k = 0;
#pragma unroll
    for (int t = 0; t < 15; ++t) { if (i >= J.off[t + 1]) k = t + 1; }
    int r = i - J.off[k];
    J.dst[k][r] = loadIn(J.src[k], r, f32);
}

__global__ void zero_kernel(float* p, int n) {
    int i = blockIdx.x * 256 + threadIdx.x;
    if (i < n) p[i] = 0.f;
}

// ---------------- deconv weight packing ----------------
__global__ void pack_w2_kernel(const void* __restrict__ src, unsigned short* __restrict__ dst,
                               int ICreal, int ICP, int OC, const int* __restrict__ flg) {
    bool f32 = flg[0] != 0;
    int i = blockIdx.x * 256 + threadIdx.x;
    int total = 16 * OC * ICP;
    if (i >= total) return;
    int jj = i & 7;
    int lane = (i >> 3) & 63;
    int j = (i >> 9) & 3;
    int t3 = i >> 11;
    int NK = ICP / 32;
    int kc = t3 % NK;
    int t4 = t3 / NK;
    int NOCT = OC / 64;
    int oct = t4 % NOCT;
    int ktap = t4 / NOCT;
    int kq = lane >> 4, n = lane & 15;
    int ic = kc * 32 + kq * 8 + jj;
    int oc = oct * 64 + n * 4 + j;          // channel-interleaved
    unsigned short v = 0;
    if (ic < ICreal) v = f2bf(loadIn(src, ((size_t)(ic * OC + oc) << 4) + ktap, f32));
    dst[i] = v;
}

__global__ void pack_w2s_kernel(const void* __restrict__ src, unsigned short* __restrict__ dst,
                                int ICP, int OCreal, const int* __restrict__ flg) {
    bool f32 = flg[0] != 0;
    int i = blockIdx.x * 256 + threadIdx.x;
    int NK = ICP / 32;
    int total = 16 * NK * 512;
    if (i >= total) return;
    int jj = i & 7;
    int lane = (i >> 3) & 63;
    int t3 = i >> 9;
    int kc = t3 % NK;
    int ktap = t3 / NK;
    int kq = lane >> 4, n = lane & 15;
    int ic = kc * 32 + kq * 8 + jj;
    unsigned short v = 0;
    if (n < OCreal) v = f2bf(loadIn(src, ((size_t)(ic * OCreal + n) << 4) + ktap, f32));
    dst[i] = v;
}

__global__ void pack_wc_kernel(const void* __restrict__ src, unsigned short* __restrict__ dst,
                               int IC, int OC, const int* __restrict__ flg) {
    bool f32 = flg[0] != 0;
    int i = blockIdx.x * 256 + threadIdx.x;
    int total = 16 * OC * IC;
    if (i >= total) return;
    int jj = i & 7;
    int lane = (i >> 3) & 63;
    int j = (i >> 9) & 3;
    int t3 = i >> 11;
    int NK = IC / 32;
    int kc = t3 % NK;
    int t4 = t3 / NK;
    int NOCT = OC / 64;
    int oct = t4 % NOCT;
    int ktap = t4 / NOCT;
    int kq = lane >> 4, n = lane & 15;
    int ic = kc * 32 + kq * 8 + jj;
    int oc = oct * 64 + j * 16 + n;
    dst[i] = f2bf(loadIn(src, ((size_t)(oc * IC + ic) << 4) + ktap, f32));
}

// ---------------- tiny MLP ----------------
__global__ void mlp_kernel(const void* __restrict__ Zg,
                           const void* __restrict__ lW, const void* __restrict__ lb,
                           const void* __restrict__ l1W, const void* __restrict__ l1b,
                           const void* __restrict__ l2W, const void* __restrict__ l2b,
                           float* __restrict__ K12, const int* __restrict__ flg) {
    bool f32 = flg[0] != 0;
    int b = blockIdx.x;
    int t = threadIdx.x;  // 64
    __shared__ float xs[64];
    float acc = loadIn(lb, t, f32);
    for (int c = 0; c < 64; ++c)
        acc += loadIn(Zg, (size_t)(b * 64 + c) * 256, f32) * loadIn(lW, t * 64 + c, f32);
    xs[t] = fmaxf(acc, 0.f);
    __syncthreads();
    if (t < 16) {
        int p = t & 7;
        const void* Wp = (t < 8) ? l1W : l2W;
        const void* bp = (t < 8) ? l1b : l2b;
        float a = loadIn(bp, p, f32);
        for (int h = 0; h < 64; ++h) a += xs[h] * loadIn(Wp, p * 64 + h, f32);
        K12[b * 16 + t] = a;
    }
}

// ---------------- conv0: imgs -> X_s2d ----------------
__global__ void conv0_s2d_kernel(const void* __restrict__ imgs, const float* __restrict__ w,
                                 const float* __restrict__ bias, unsigned short* __restrict__ xs,
                                 const int* __restrict__ flg) {
    bool f32 = flg[0] != 0;
    int b = blockIdx.z;
    int tile = blockIdx.x;
    int Y0 = (tile >> 2) * 16, X0 = (tile & 3) * 16;
    __shared__ float vin[3 * 34 * 35];
    __shared__ float wl[64 * 49];
    for (int i = threadIdx.x; i < 3 * 34 * 34; i += 256) {
        int c = i % 34; int t = i / 34; int r = t % 34; int ic = t / 34;
        int iy = 2 * Y0 - 1 + r, ix = 2 * X0 - 1 + c;
        float v = 0.f;
        if (((unsigned)iy < 128u) & ((unsigned)ix < 128u))
            v = loadIn(imgs, ((size_t)(b * 3 + ic) * 128 + iy) * 128 + ix, f32);
        vin[(ic * 34 + r) * 35 + c] = v;
    }
    for (int i = threadIdx.x; i < 3072; i += 256) {
        int oc = i / 48, idx = i % 48;
        wl[oc * 49 + idx] = w[i];
    }
    __syncthreads();
    int q = threadIdx.x >> 2;
    int ocq = threadIdx.x & 3;
    int qy = q >> 3, qx = q & 7;
    float acc[4][16];
#pragma unroll
    for (int p = 0; p < 4; ++p)
#pragma unroll
        for (int o = 0; o < 16; ++o) acc[p][o] = 0.f;
    for (int ic = 0; ic < 3; ++ic) {
        float v[6][6];
#pragma unroll
        for (int r = 0; r < 6; ++r)
#pragma unroll
            for (int c = 0; c < 6; ++c)
                v[r][c] = vin[(ic * 34 + 4 * qy + r) * 35 + 4 * qx + c];
#pragma unroll
        for (int o = 0; o < 16; ++o) {
            const float* wo = wl + (ocq * 16 + o) * 49 + ic * 16;
#pragma unroll
            for (int ky = 0; ky < 4; ++ky)
#pragma unroll
                for (int kx = 0; kx < 4; ++kx) {
                    float wv = wo[ky * 4 + kx];
                    acc[0][o] = fmaf(v[ky][kx], wv, acc[0][o]);
                    acc[1][o] = fmaf(v[ky][kx + 2], wv, acc[1][o]);
                    acc[2][o] = fmaf(v[ky + 2][kx], wv, acc[2][o]);
                    acc[3][o] = fmaf(v[ky + 2][kx + 2], wv, acc[3][o]);
                }
        }
    }
    int j = (Y0 >> 1) + qy, i2 = (X0 >> 1) + qx;
#pragma unroll
    for (int p = 0; p < 4; ++p) {
        int dy = p >> 1, dx = p & 1;
        unsigned short tmp[16];
#pragma unroll
        for (int o = 0; o < 16; ++o) tmp[o] = f2bf(acc[p][o] + bias[ocq * 16 + o]);
        unsigned short* dst = xs + (((size_t)((b * 2 + dy) * 2 + dx) * 32 + j) * 32 + i2) * 64 + ocq * 16;
        *(uint4*)(dst) = *(const uint4*)(tmp);
        *(uint4*)(dst + 8) = *(const uint4*)(tmp + 8);
    }
}

// ---------------- conv1 (MFMA, fused L0 BN on load, fused L1 stats, atomic-free in-block reduce) ----------------
__global__ void conv1_mfma_kernel(const unsigned short* __restrict__ xs,
                                  const unsigned short* __restrict__ wp,
                                  const float* __restrict__ bias,
                                  const float* __restrict__ sc, const float* __restrict__ sh,
                                  float* __restrict__ gsum, float* __restrict__ gsq,
                                  unsigned short* __restrict__ ys) {
    constexpr int STR = 72;
    __shared__ unsigned short lds[4 * 3 * 17 * STR];   // 29.4 KB
    __shared__ float ws[4][64], wq[4][64];
    int bid = blockIdx.x;
    int slot = (bid & (NREP - 1)) * 576;
    int xt = bid & 1;
    int qp = (bid >> 1) & 15;
    int b = bid >> 5;
    int oy0 = qp * 2, x0 = xt * 16;
    for (int i = threadIdx.x; i < 1632; i += 256) {
        int icc = i & 7; int t = i >> 3;
        int col = t % 17; int rc = t / 17;
        int row = rc % 3; int pl = rc / 3;
        int py = pl >> 1, px = pl & 1;
        int j = oy0 - py + row;
        int ci = x0 - px + col;
        uint4 v = {0u, 0u, 0u, 0u};
        if (((unsigned)j < 32u) & ((unsigned)ci < 32u)) {
            v = *(const uint4*)(xs + ((size_t)((b * 4 + pl) * 32 + j) * 32 + ci) * 64 + icc * 8);
            v = bn_fuse8(v, sc, sh, icc * 8, 0.2f);
        }
        *(uint4*)(lds + ((pl * 3 + row) * 17 + col) * STR + icc * 8) = v;
    }
    __syncthreads();

    int wv = threadIdx.x >> 6, lane = threadIdx.x & 63;
    int r = wv >> 1, oct = wv & 1;
    int m = lane & 15, kq = lane >> 4;
    f32x4 acc[4];
#pragma unroll
    for (int j = 0; j < 4; ++j) acc[j] = (f32x4){0.f, 0.f, 0.f, 0.f};

#pragma unroll
    for (int ky = 0; ky < 4; ++ky) {
        int py = (ky & 1) ^ 1;
        int lrow = r + (ky >> 1);
#pragma unroll
        for (int kx = 0; kx < 4; ++kx) {
            int px = (kx & 1) ^ 1;
            int pl = py * 2 + px;
            int lcol = m + (kx >> 1);
            const unsigned short* lp = lds + ((pl * 3 + lrow) * 17 + lcol) * STR + kq * 8;
            int ktap = ky * 4 + kx;
            const unsigned short* bb = wp + (size_t)(ktap * 2 + oct) * 4096;
#pragma unroll
            for (int kc = 0; kc < 2; ++kc) {
                bf16x8 a = *(const bf16x8*)(lp + kc * 32);
                const unsigned short* bk = bb + kc * 2048 + lane * 8;
                bf16x8 b0 = *(const bf16x8*)(bk);
                bf16x8 b1 = *(const bf16x8*)(bk + 512);
                bf16x8 b2 = *(const bf16x8*)(bk + 1024);
                bf16x8 b3 = *(const bf16x8*)(bk + 1536);
                acc[0] = __builtin_amdgcn_mfma_f32_16x16x32_bf16(a, b0, acc[0], 0, 0, 0);
                acc[1] = __builtin_amdgcn_mfma_f32_16x16x32_bf16(a, b1, acc[1], 0, 0, 0);
                acc[2] = __builtin_amdgcn_mfma_f32_16x16x32_bf16(a, b2, acc[2], 0, 0, 0);
                acc[3] = __builtin_amdgcn_mfma_f32_16x16x32_bf16(a, b3, acc[3], 0, 0, 0);
            }
        }
    }
    int oy = oy0 + r;
    int pyo = oy & 1, jo = oy >> 1;
    int n = m;
    float bv0 = bias[oct * 64 + n], bv1 = bias[oct * 64 + 16 + n];
    float bv2 = bias[oct * 64 + 32 + n], bv3 = bias[oct * 64 + 48 + n];
    float s0 = 0, s1 = 0, s2 = 0, s3 = 0, q0 = 0, q1 = 0, q2 = 0, q3 = 0;
#pragma unroll
    for (int reg = 0; reg < 4; ++reg) {
        int mm = kq * 4 + reg;
        int ox = x0 + mm;
        int pxo = ox & 1, io = ox >> 1;
        size_t base = (((size_t)((b * 2 + pyo) * 2 + pxo) * 16 + jo) * 16 + io) * 128 + oct * 64 + n;
        float v0 = acc[0][reg] + bv0, v1 = acc[1][reg] + bv1;
        float v2 = acc[2][reg] + bv2, v3 = acc[3][reg] + bv3;
        s0 += v0; q0 += v0 * v0; s1 += v1; q1 += v1 * v1;
        s2 += v2; q2 += v2 * v2; s3 += v3; q3 += v3 * v3;
        ys[base]      = f2bf(v0);
        ys[base + 16] = f2bf(v1);
        ys[base + 32] = f2bf(v2);
        ys[base + 48] = f2bf(v3);
    }
    // wave-level kq reduction (no atomics)
    s0 = kq_reduce(s0); q0 = kq_reduce(q0);
    s1 = kq_reduce(s1); q1 = kq_reduce(q1);
    s2 = kq_reduce(s2); q2 = kq_reduce(q2);
    s3 = kq_reduce(s3); q3 = kq_reduce(q3);
    if (lane < 16) {
        ws[wv][0 * 16 + n] = s0; wq[wv][0 * 16 + n] = q0;
        ws[wv][1 * 16 + n] = s1; wq[wv][1 * 16 + n] = q1;
        ws[wv][2 * 16 + n] = s2; wq[wv][2 * 16 + n] = q2;
        ws[wv][3 * 16 + n] = s3; wq[wv][3 * 16 + n] = q3;
    }
    __syncthreads();
    if (threadIdx.x < 128) {
        int c = threadIdx.x;
        int o = c >> 6, rr = c & 63;          // waves {o, o+2} cover oct o
        float s = ws[o][rr] + ws[o + 2][rr];
        float q = wq[o][rr] + wq[o + 2][rr];
        atomicAdd(&gsum[slot + 64 + c], s);
        atomicAdd(&gsq[slot + 64 + c], q);
    }
}

// ---------------- conv2 (MFMA, fused L1 BN on load) + tanh: Y_s2d -> Z_t[0:64) ----------------
__global__ void conv2_mfma_kernel(const unsigned short* __restrict__ ys,
                                  const unsigned short* __restrict__ wp,
                                  const float* __restrict__ bias,
                                  const float* __restrict__ sc, const float* __restrict__ sh,
                                  unsigned short* __restrict__ zt) {
    constexpr int STR = 136;
    __shared__ unsigned short lds[4 * 3 * 17 * STR];   // 55.5 KB
    int bid = blockIdx.x;
    int qp = bid & 7;
    int b = bid >> 3;
    int oy0 = qp * 2;
    for (int i = threadIdx.x; i < 3264; i += 256) {
        int icc = i & 15; int t = i >> 4;
        int col = t % 17; int rc = t / 17;
        int row = rc % 3; int pl = rc / 3;
        int py = pl >> 1, px = pl & 1;
        int j = oy0 - py + row;
        int ci = col - px;
        uint4 v = {0u, 0u, 0u, 0u};
        if (((unsigned)j < 16u) & ((unsigned)ci < 16u)) {
            v = *(const uint4*)(ys + ((size_t)((b * 4 + pl) * 16 + j) * 16 + ci) * 128 + icc * 8);
            v = bn_fuse8(v, sc, sh, icc * 8, 0.2f);
        }
        *(uint4*)(lds + ((pl * 3 + row) * 17 + col) * STR + icc * 8) = v;
    }
    __syncthreads();

    int wv = threadIdx.x >> 6, lane = threadIdx.x & 63;
    int r = wv >> 1, jh = wv & 1;
    int m = lane & 15, kq = lane >> 4;
    f32x4 acc[2];
    acc[0] = (f32x4){0.f, 0.f, 0.f, 0.f};
    acc[1] = acc[0];
#pragma unroll
    for (int ky = 0; ky < 4; ++ky) {
        int py = (ky & 1) ^ 1;
        int lrow = r + (ky >> 1);
#pragma unroll
        for (int kx = 0; kx < 4; ++kx) {
            int px = (kx & 1) ^ 1;
            int pl = py * 2 + px;
            int lcol = m + (kx >> 1);
            const unsigned short* lp = lds + ((pl * 3 + lrow) * 17 + lcol) * STR + kq * 8;
            int ktap = ky * 4 + kx;
            const unsigned short* bb = wp + (size_t)ktap * 8192;
#pragma unroll
            for (int kc = 0; kc < 4; ++kc) {
                bf16x8 a = *(const bf16x8*)(lp + kc * 32);
                const unsigned short* bk = bb + kc * 2048 + (jh * 2) * 512 + lane * 8;
                bf16x8 b0 = *(const bf16x8*)(bk);
                bf16x8 b1 = *(const bf16x8*)(bk + 512);
                acc[0] = __builtin_amdgcn_mfma_f32_16x16x32_bf16(a, b0, acc[0], 0, 0, 0);
                acc[1] = __builtin_amdgcn_mfma_f32_16x16x32_bf16(a, b1, acc[1], 0, 0, 0);
            }
        }
    }
    int oy = oy0 + r;
    int n = m;
    float bv0 = bias[(jh * 2) * 16 + n], bv1 = bias[(jh * 2 + 1) * 16 + n];
#pragma unroll
    for (int reg = 0; reg < 4; ++reg) {
        int x = kq * 4 + reg;
        size_t base = ((size_t)(b * 16 + oy) * 16 + x) * 192 + (jh * 2) * 16 + n;
        zt[base]      = f2bf(tanhf(acc[0][reg] + bv0));
        zt[base + 16] = f2bf(tanhf(acc[1][reg] + bv1));
    }
}

// ---------------- assemble Z_t[...][64:192): Zl, Zg, wave, and pad channels ----------------
__global__ void assemble_z(const void* __restrict__ Zl, const void* __restrict__ Zg,
                           const void* __restrict__ phi, const float* __restrict__ K12,
                           unsigned short* __restrict__ zt, const int* __restrict__ flg) {
    bool f32 = flg[0] != 0;
    int i = blockIdx.x * 256 + threadIdx.x;
    const int TOT = 64 * 128 * 256;
    if (i >= TOT) return;
    int pos = i & 255;
    int t = i >> 8;
    int c128 = t % 128;
    int b = t / 128;
    float val;
    if (c128 < 32) {
        val = loadIn(Zl, ((size_t)(b * 32 + c128) << 8) + pos, f32);
    } else if (c128 < 96) {
        val = loadIn(Zg, ((size_t)(b * 64 + (c128 - 32)) << 8) + pos, f32);
    } else if (c128 < 104) {
        int p = c128 - 96;
        int y = pos >> 4, x = pos & 15;
        float k1 = K12[b * 16 + p];
        float k2 = K12[b * 16 + 8 + p];
        val = sinf(k1 * (float)y + k2 * (float)x + loadIn(phi, b * 8 + p, f32) * TWO_PI_F);
    } else {
        val = 0.f;      // pad channels 168..192 of Z_t
    }
    zt[((size_t)(b * 256 + pos)) * 192 + 64 + c128] = f2bf(val);
}

// ---------------- MFMA transposed-conv v13: QR rows/block, oct slowest, fused BN-in,
// optional stats, K-phase split (KPH) to shrink LDS and raise occupancy ----------------
template <int ICP, int Q, int OC, int QR, bool BN, bool ST, int KPH>
__global__ __launch_bounds__(256, 2)
void deconv_mfma2_kernel(const unsigned short* __restrict__ in_t,
                         const unsigned short* __restrict__ wp2,
                         const float* __restrict__ bias,
                         const float* __restrict__ sc, const float* __restrict__ sh,
                         float* __restrict__ gsum, float* __restrict__ gsq, int statoff,
                         unsigned short* __restrict__ out_t) {
    constexpr int NOCT = OC / 64;
    constexpr int NK = ICP / 32;         // total 32-channel chunks
    constexpr int ICPP = ICP / KPH;      // channels per phase
    constexpr int NKL = NK / KPH;        // chunks per phase
    constexpr int XT = Q / 16;
    constexpr int NQB = Q / QR;
    constexpr int ROWS = QR + 2;
    constexpr int STRIDE = ICPP + 8;
    constexpr int NTILES = XT * NQB * 64;
    __shared__ unsigned short lds[ROWS * 18 * STRIDE];
    __shared__ float ws[ST ? 4 : 1][64], wq[ST ? 4 : 1][64];

    int bid = blockIdx.x;
    int slot = (bid & (NREP - 1)) * 576;
    int oct = bid / NTILES;          // slowest dim
    bid -= oct * NTILES;
    int xt = bid % XT;
    int t2 = bid / XT;
    int qp = t2 % NQB;
    int b = t2 / NQB;
    int qy0 = qp * QR;
    int x0 = xt * 16;

    int wv = threadIdx.x >> 6, lane = threadIdx.x & 63;
    int dy = wv >> 1, dx = wv & 1;
    int m = lane & 15, kq = lane >> 4;

    f32x4 acc[QR][4];
#pragma unroll
    for (int q = 0; q < QR; ++q)
#pragma unroll
        for (int j = 0; j < 4; ++j) acc[q][j] = (f32x4){0.f, 0.f, 0.f, 0.f};

    constexpr int P8 = ICPP / 8;
    constexpr int E8 = ROWS * 18 * P8;
#pragma unroll
    for (int ph = 0; ph < KPH; ++ph) {
        if (ph) __syncthreads();     // all waves done reading previous phase
        for (int i = threadIdx.x; i < E8; i += 256) {
            int icc = i % P8;
            int rc = i / P8;
            int row = rc / 18, col = rc % 18;
            int y = qy0 - 1 + row, x = x0 - 1 + col;
            uint4 val = {0u, 0u, 0u, 0u};
            if (((unsigned)y < (unsigned)Q) & ((unsigned)x < (unsigned)Q)) {
                val = *(const uint4*)(in_t + (size_t)((b * Q + y) * Q + x) * ICP + ph * ICPP + icc * 8);
                if (BN) val = bn_fuse8(val, sc, sh, ph * ICPP + icc * 8, 0.f);
            }
            *(uint4*)(lds + rc * STRIDE + icc * 8) = val;
        }
        __syncthreads();

#pragma unroll
        for (int t = 0; t < 4; ++t) {
            int rr = t >> 1, cc = t & 1;
            int ktap = ((3 - dy) - 2 * rr) * 4 + ((3 - dx) - 2 * cc);
            int col = m + dx + cc;
            int row0 = dy + rr;
            const unsigned short* bbase = wp2 + (size_t)((ktap * NOCT + oct) * NK) * 2048;
#pragma unroll
            for (int kc = 0; kc < NKL; ++kc) {
                int kcg = ph * NKL + kc;
                bf16x8 a[QR];
#pragma unroll
                for (int q = 0; q < QR; ++q)
                    a[q] = *(const bf16x8*)(lds + ((row0 + q) * 18 + col) * STRIDE + kc * 32 + kq * 8);
                bf16x8 b0 = *(const bf16x8*)(bbase + (kcg * 4 + 0) * 512 + lane * 8);
                bf16x8 b1 = *(const bf16x8*)(bbase + (kcg * 4 + 1) * 512 + lane * 8);
                bf16x8 b2 = *(const bf16x8*)(bbase + (kcg * 4 + 2) * 512 + lane * 8);
                bf16x8 b3 = *(const bf16x8*)(bbase + (kcg * 4 + 3) * 512 + lane * 8);
#pragma unroll
                for (int q = 0; q < QR; ++q) {
                    acc[q][0] = __builtin_amdgcn_mfma_f32_16x16x32_bf16(a[q], b0, acc[q][0], 0, 0, 0);
                    acc[q][1] = __builtin_amdgcn_mfma_f32_16x16x32_bf16(a[q], b1, acc[q][1], 0, 0, 0);
                    acc[q][2] = __builtin_amdgcn_mfma_f32_16x16x32_bf16(a[q], b2, acc[q][2], 0, 0, 0);
                    acc[q][3] = __builtin_amdgcn_mfma_f32_16x16x32_bf16(a[q], b3, acc[q][3], 0, 0, 0);
                }
            }
        }
    }
    // Epilogue: lane n holds channels oct*64 + 4n + j -> one contiguous ushort4 per (qyl,reg).
    int n = m;
    const float4 bv = *(const float4*)(bias + oct * 64 + 4 * n);
    float s0 = 0, s1 = 0, s2 = 0, s3 = 0, q0 = 0, q1 = 0, q2 = 0, q3 = 0;
#pragma unroll
    for (int qyl = 0; qyl < QR; ++qyl) {
        int oy = 2 * (qy0 + qyl) + dy;
#pragma unroll
        for (int reg = 0; reg < 4; ++reg) {
            int mm = kq * 4 + reg;
            int ox = 2 * (x0 + mm) + dx;
            size_t base = ((size_t)((b * 2 * Q + oy) * (2 * Q) + ox)) * OC + oct * 64 + 4 * n;
            float v0 = acc[qyl][0][reg] + bv.x;
            float v1 = acc[qyl][1][reg] + bv.y;
            float v2 = acc[qyl][2][reg] + bv.z;
            float v3 = acc[qyl][3][reg] + bv.w;
            if (ST) {
                s0 += v0; q0 += v0 * v0; s1 += v1; q1 += v1 * v1;
                s2 += v2; q2 += v2 * v2; s3 += v3; q3 += v3 * v3;
            }
            ushort4 tv;
            tv.x = f2bf(v0); tv.y = f2bf(v1); tv.z = f2bf(v2); tv.w = f2bf(v3);
            *(ushort4*)(out_t + base) = tv;
        }
    }
    if (ST) {
        // wave-level kq reduction (no LDS atomics)
        s0 = kq_reduce(s0); q0 = kq_reduce(q0);
        s1 = kq_reduce(s1); q1 = kq_reduce(q1);
        s2 = kq_reduce(s2); q2 = kq_reduce(q2);
        s3 = kq_reduce(s3); q3 = kq_reduce(q3);
        if (lane < 16) {
            ws[wv][4 * n + 0] = s0; wq[wv][4 * n + 0] = q0;
            ws[wv][4 * n + 1] = s1; wq[wv][4 * n + 1] = q1;
            ws[wv][4 * n + 2] = s2; wq[wv][4 * n + 2] = q2;
            ws[wv][4 * n + 3] = s3; wq[wv][4 * n + 3] = q3;
        }
        __syncthreads();
        if (threadIdx.x < 64) {
            int c = threadIdx.x;
            float s = ws[0][c] + ws[1][c] + ws[2][c] + ws[3][c];
            float q = wq[0][c] + wq[1][c] + wq[2][c] + wq[3][c];
            atomicAdd(&gsum[slot + statoff + oct * 64 + c], s);
            atomicAdd(&gsq[slot + statoff + oct * 64 + c], q);
        }
    }
}

// ---------------- deconv2 v3 (MFMA, QR=4, KPH=2, fused G1 BN+relu on load, OC=3 pad 16) + tanh ----------------
// KPH=2: stage 64 of 128 channels per phase; LDS 29.4 -> 15.6 KB for more resident blocks.
__global__ void deconv2_mfma_kernel(const unsigned short* __restrict__ yt,
                                    const unsigned short* __restrict__ wp,
                                    const float* __restrict__ bias,
                                    const float* __restrict__ sc, const float* __restrict__ sh,
                                    float* __restrict__ outp) {
    constexpr int Q = 64, ICP = 128, NK = 4, QR = 4, ROWS = 6, KPH = 2;
    constexpr int ICPP = ICP / KPH;      // 64
    constexpr int NKL = NK / KPH;        // 2
    constexpr int STRIDE = ICPP + 8;     // 72
    __shared__ unsigned short lds[ROWS * 18 * STRIDE];   // 15.6 KB
    int bid = blockIdx.x;
    int xt = bid & 3;
    int t2 = bid >> 2;
    int qp = t2 & 15;
    int b = t2 >> 4;
    int qy0 = qp * QR, x0 = xt * 16;

    int wv = threadIdx.x >> 6, lane = threadIdx.x & 63;
    int dy = wv >> 1, dx = wv & 1;
    int m = lane & 15, kq = lane >> 4;
    f32x4 acc[QR];
#pragma unroll
    for (int q = 0; q < QR; ++q) acc[q] = (f32x4){0.f, 0.f, 0.f, 0.f};

    constexpr int P8 = ICPP / 8;         // 8
    constexpr int E8 = ROWS * 18 * P8;   // 864
#pragma unroll
    for (int ph = 0; ph < KPH; ++ph) {
        if (ph) __syncthreads();
        for (int i = threadIdx.x; i < E8; i += 256) {
            int icc = i % P8;
            int rc = i / P8;
            int row = rc / 18, col = rc % 18;
            int y = qy0 - 1 + row, x = x0 - 1 + col;
            uint4 v = {0u, 0u, 0u, 0u};
            if (((unsigned)y < (unsigned)Q) & ((unsigned)x < (unsigned)Q)) {
                v = *(const uint4*)(yt + (size_t)((b * Q + y) * Q + x) * ICP + ph * ICPP + icc * 8);
                v = bn_fuse8(v, sc, sh, ph * ICPP + icc * 8, 0.f);
            }
            *(uint4*)(lds + rc * STRIDE + icc * 8) = v;
        }
        __syncthreads();

#pragma unroll
        for (int t = 0; t < 4; ++t) {
            int rr = t >> 1, cc = t & 1;
            int ktap = ((3 - dy) - 2 * rr) * 4 + ((3 - dx) - 2 * cc);
            int col = m + dx + cc;
            int row0 = dy + rr;
            const unsigned short* bb = wp + (size_t)(ktap * NK) * 512;
#pragma unroll
            for (int kc = 0; kc < NKL; ++kc) {
                int kcg = ph * NKL + kc;
                bf16x8 a[QR];
#pragma unroll
                for (int q = 0; q < QR; ++q)
                    a[q] = *(const bf16x8*)(lds + ((row0 + q) * 18 + col) * STRIDE + kc * 32 + kq * 8);
                bf16x8 b0 = *(const bf16x8*)(bb + kcg * 512 + lane * 8);
#pragma unroll
                for (int q = 0; q < QR; ++q)
                    acc[q] = __builtin_amdgcn_mfma_f32_16x16x32_bf16(a[q], b0, acc[q], 0, 0, 0);
            }
        }
    }
    int n = m;
    if (n < 3) {
        float bv = bias[n];
#pragma unroll
        for (int qyl = 0; qyl < QR; ++qyl) {
            int oy = 2 * (qy0 + qyl) + dy;
#pragma unroll
            for (int reg = 0; reg < 4; ++reg) {
                int mm = kq * 4 + reg;
                int ox = 2 * (x0 + mm) + dx;
                size_t ob = (size_t)(b * 3 + n) * 16384;
                outp[ob + (size_t)oy * 128 + ox] = tanhf(acc[qyl][reg] + bv);
            }
        }
    }
}

// ---------------- channel-last BN stat reduction (conv0 output + deconv1 output) ----------------
template <int C>
__global__ void stat_reduce_t(const unsigned short* __restrict__ x, int total4,
                              float* __restrict__ ssum, float* __restrict__ ssq, int statoff) {
    __shared__ float ls[C], lq[C];
    for (int c = threadIdx.x; c < C; c += 256) { ls[c] = 0.f; lq[c] = 0.f; }
    __syncthreads();
    int i0 = blockIdx.x * 256 + threadIdx.x;
    int stride = gridDim.x * 256;
    int c0 = (i0 << 2) & (C - 1);
    float s0 = 0, s1 = 0, s2 = 0, s3 = 0, q0 = 0, q1 = 0, q2 = 0, q3 = 0;
    for (int i = i0; i < total4; i += stride) {
        ushort4 v = *(const ushort4*)(x + ((size_t)i << 2));
        float f0 = bf2f_raw(v.x), f1 = bf2f_raw(v.y), f2 = bf2f_raw(v.z), f3 = bf2f_raw(v.w);
        s0 += f0; s1 += f1; s2 += f2; s3 += f3;
        q0 += f0 * f0; q1 += f1 * f1; q2 += f2 * f2; q3 += f3 * f3;
    }
    atomicAdd(&ls[c0], s0); atomicAdd(&ls[c0 + 1], s1); atomicAdd(&ls[c0 + 2], s2); atomicAdd(&ls[c0 + 3], s3);
    atomicAdd(&lq[c0], q0); atomicAdd(&lq[c0 + 1], q1); atomicAdd(&lq[c0 + 2], q2); atomicAdd(&lq[c0 + 3], q3);
    __syncthreads();
    int slot = (blockIdx.x & (NREP - 1)) * 576;
    for (int c = threadIdx.x; c < C; c += 256) {
        atomicAdd(&ssum[slot + statoff + c], ls[c]);
        atomicAdd(&ssq[slot + statoff + c], lq[c]);
    }
}

// ---------------- BN finalize (sums NREP replicas) ----------------
__global__ void bn_fin_kernel(const float* __restrict__ ssum, const float* __restrict__ ssq,
                              const float* __restrict__ g, const float* __restrict__ be,
                              float* __restrict__ scale, float* __restrict__ shift,
                              int statoff, int C, float invN) {
    int c = threadIdx.x;
    if (c >= C) return;
    float s = 0.f, q = 0.f;
#pragma unroll
    for (int r = 0; r < NREP; ++r) {
        s += ssum[r * 576 + statoff + c];
        q += ssq[r * 576 + statoff + c];
    }
    float m = s * invN;
    float v = q * invN - m * m;
    v = fmaxf(v, 0.f);
    float sc = g[c] * rsqrtf(v + 1e-5f);
    scale[statoff + c] = sc;
    shift[statoff + c] = be[c] - m * sc;
}

extern "C" void kernel_launch(void* const* d_in, const int* in_sizes, int n_in,
                              void* d_out, int out_size, void* d_ws, size_t ws_size,
                              hipStream_t stream) {
    if (ws_size < WS_NEED_BYTES) {
        hipMemsetAsync(d_out, 0, (size_t)out_size * 4, stream);
        return;
    }

    float* W = (float*)d_ws;
    unsigned short* U = (unsigned short*)d_ws;
    int* FLG = (int*)(W + OFF_FLAG);

    detect_kernel<<<1, 256, 0, stream>>>((const unsigned short*)d_in[2], FLG);

    CvtJobs J;
    const int srcIdx[16] = {10, 28, 11, 12, 13, 15, 16, 17, 19, 21, 22, 23, 25, 26, 27, 29};
    const int cnt[16]    = {3072, 6144, 64, 64, 64, 128, 128, 128, 64, 256, 256, 256, 128, 128, 128, 3};
    float* dsts[16] = {W + OFF_WC0, W + OFF_WG2,
                       W + OFF_CB0, W + OFF_CG0, W + OFF_CBE0, W + OFF_CB1, W + OFF_CG1, W + OFF_CBE1,
                       W + OFF_CB2, W + OFF_GB0, W + OFF_GG0, W + OFF_GBE0, W + OFF_GB1, W + OFF_GG1,
                       W + OFF_GBE1, W + OFF_GB2};
    int off = 0;
    for (int k = 0; k < 16; ++k) {
        J.src[k] = d_in[srcIdx[k]];
        J.dst[k] = dsts[k];
        J.off[k] = off;
        off += cnt[k];
    }
    J.off[16] = off;
    cvt_all_kernel<<<(off + 255) / 256, 256, 0, stream>>>(J, off, FLG);

    zero_kernel<<<(2 * NREP * 576 + 255) / 256, 256, 0, stream>>>(W + OFF_SSUM, 2 * NREP * 576);

    // weight packs
    pack_w2_kernel<<<3072, 256, 0, stream>>>(d_in[20], U + UW0, 168, 192, 256, FLG);
    pack_w2_kernel<<<2048, 256, 0, stream>>>(d_in[24], U + UW1, 256, 256, 128, FLG);
    pack_wc_kernel<<<512, 256, 0, stream>>>(d_in[14], U + UWC1, 64, 128, FLG);
    pack_wc_kernel<<<512, 256, 0, stream>>>(d_in[18], U + UWC2, 128, 64, FLG);
    pack_w2s_kernel<<<128, 256, 0, stream>>>(d_in[28], U + UW2, 128, 3, FLG);

    mlp_kernel<<<64, 64, 0, stream>>>(d_in[1], d_in[4], d_in[5], d_in[6], d_in[7],
                                      d_in[8], d_in[9], W + OFF_K12, FLG);

    // ---- conv0 -> X_s2d (raw) ----
    conv0_s2d_kernel<<<dim3(16, 1, 64), 256, 0, stream>>>(d_in[2], W + OFF_WC0, W + OFF_CB0,
                                                          U + UXT, FLG);
    stat_reduce_t<64><<<1024, 256, 0, stream>>>(U + UXT, 4194304, W + OFF_SSUM, W + OFF_SSQ, 0);
    bn_fin_kernel<<<1, 256, 0, stream>>>(W + OFF_SSUM, W + OFF_SSQ, W + OFF_CG0, W + OFF_CBE0,
                                         W + OFF_SCALE, W + OFF_SHIFT, 0, 64, 1.f / 262144.f);

    // ---- conv1 (MFMA, fused L0 BN, fused L1 stats) -> Y_s2d ----
    conv1_mfma_kernel<<<2048, 256, 0, stream>>>(U + UXT, U + UWC1, W + OFF_CB1,
                                                W + OFF_SCALE + 0, W + OFF_SHIFT + 0,
                                                W + OFF_SSUM, W + OFF_SSQ, U + UYT);
    bn_fin_kernel<<<1, 256, 0, stream>>>(W + OFF_SSUM, W + OFF_SSQ, W + OFF_CG1, W + OFF_CBE1,
                                         W + OFF_SCALE, W + OFF_SHIFT, 64, 128, 1.f / 65536.f);

    // ---- conv2 (MFMA, fused L1 BN) + tanh -> Z_t[0:64) ----
    conv2_mfma_kernel<<<512, 256, 0, stream>>>(U + UYT, U + UWC2, W + OFF_CB2,
                                               W + OFF_SCALE + 64, W + OFF_SHIFT + 64, U + UZT);

    // ---- Z_t[64:192) incl. pad zeroing ----
    assemble_z<<<8192, 256, 0, stream>>>(d_in[0], d_in[1], d_in[3], W + OFF_K12, U + UZT, FLG);

    // ---- gen deconv0 (MFMA, QR=2, fused G0 stats, KPH=2): Z_t -> X_t(32,32,256) ----
    // LDS 4*18*(96+8)*2 = 15.0 KB (was 30)
    deconv_mfma2_kernel<192, 16, 256, 2, false, true, 2><<<2048, 256, 0, stream>>>(
        U + UZT, U + UW0, W + OFF_GB0, nullptr, nullptr,
        W + OFF_SSUM, W + OFF_SSQ, 192, U + UXT);
    bn_fin_kernel<<<1, 256, 0, stream>>>(W + OFF_SSUM, W + OFF_SSQ, W + OFF_GG0, W + OFF_GBE0,
                                         W + OFF_SCALE, W + OFF_SHIFT, 192, 256, 1.f / 65536.f);

    // ---- gen deconv1 (MFMA, QR=4, fused G0 BN, KPH=2 K-split): X_t -> Y_t(64,64,128) ----
    deconv_mfma2_kernel<256, 32, 128, 4, true, false, 2><<<2048, 256, 0, stream>>>(
        U + UXT, U + UW1, W + OFF_GB1, W + OFF_SCALE + 192, W + OFF_SHIFT + 192,
        nullptr, nullptr, 0, U + UYT);
    // G1 stats via separate pass over Y_t (67 MB read)
    stat_reduce_t<128><<<1024, 256, 0, stream>>>(U + UYT, 8388608, W + OFF_SSUM, W + OFF_SSQ, 448);
    bn_fin_kernel<<<1, 256, 0, stream>>>(W + OFF_SSUM, W + OFF_SSQ, W + OFF_GG1, W + OFF_GBE1,
                                         W + OFF_SCALE, W + OFF_SHIFT, 448, 128, 1.f / 262144.f);

    // ---- gen deconv2 (MFMA, QR=4, KPH=2, fused G1 BN) + tanh -> d_out fp32 ----  grid = 4096
    deconv2_mfma_kernel<<<4096, 256, 0, stream>>>(U + UYT, U + UW2, W + OFF_GB2,
                                                  W + OFF_SCALE + 448, W + OFF_SHIFT + 448,
                                                  (float*)d_out);
}